// Round 1
// baseline (1677.263 us; speedup 1.0000x reference)
//
#include <hip/hip_runtime.h>
#include <hip/hip_bf16.h>
#include <math.h>

#define N_PTS 16384
#define NUM_G 64
#define GRP_K 32
#define EPSF 1e-5f

// ---------------- Phase A: farthest point sampling ----------------
// One block per batch. 1024 threads, 16 points/thread held in registers.
// Must match numpy fp32 exactly: no FMA contraction, argmax tie -> lowest idx.
__global__ __launch_bounds__(1024) void fps_kernel(const float* __restrict__ pcd,
                                                   int* __restrict__ cidx) {
    const int b = blockIdx.x;
    const int tid = threadIdx.x;
    const float* xb = pcd + (size_t)b * 6 * N_PTS;

    float px[16], py[16], pz[16], dist[16];
#pragma unroll
    for (int j = 0; j < 16; ++j) {
        int p = tid + 1024 * j;
        px[j] = xb[p];
        py[j] = xb[N_PTS + p];
        pz[j] = xb[2 * N_PTS + p];
        dist[j] = 1e10f;
    }

    __shared__ float red_v[16];
    __shared__ int red_i[16];
    __shared__ int far_sh;

    int far = 0;
    for (int it = 0; it < NUM_G; ++it) {
        if (tid == 0) cidx[b * NUM_G + it] = far;
        float cx = xb[far], cy = xb[N_PTS + far], cz = xb[2 * N_PTS + far];

        float bv = -1.0f;
        int bi = 0;
#pragma unroll
        for (int j = 0; j < 16; ++j) {
            float dx = __fsub_rn(px[j], cx);
            float dy = __fsub_rn(py[j], cy);
            float dz = __fsub_rn(pz[j], cz);
            float d = __fadd_rn(__fadd_rn(__fmul_rn(dx, dx), __fmul_rn(dy, dy)),
                                __fmul_rn(dz, dz));
            dist[j] = fminf(dist[j], d);
            // j ascending => point index ascending: strict > keeps earliest on tie
            if (dist[j] > bv) { bv = dist[j]; bi = tid + 1024 * j; }
        }
        // wave reduce (64 lanes), tie -> lower index
#pragma unroll
        for (int o = 32; o > 0; o >>= 1) {
            float ov = __shfl_down(bv, o);
            int oi = __shfl_down(bi, o);
            if (ov > bv || (ov == bv && oi < bi)) { bv = ov; bi = oi; }
        }
        int w = tid >> 6;
        if ((tid & 63) == 0) { red_v[w] = bv; red_i[w] = bi; }
        __syncthreads();
        if (tid == 0) {
            float v = red_v[0]; int i0 = red_i[0];
            for (int k = 1; k < 16; ++k)
                if (red_v[k] > v || (red_v[k] == v && red_i[k] < i0)) { v = red_v[k]; i0 = red_i[k]; }
            far_sh = i0;
        }
        __syncthreads();
        far = far_sh;
    }
}

// ---------------- Phase B: KNN (32 smallest by (d2, idx)) + gather ----------------
// One block per (b,g). 256 threads, 64 d2 values/thread in registers.
// 32 extraction rounds of block-wide (val,idx) min; removed set tracked via bitmask
// (avoids dynamic register-array indexing).
__global__ __launch_bounds__(256) void knn_kernel(const float* __restrict__ pcd,
                                                  const int* __restrict__ cidx,
                                                  float* __restrict__ xout) {
    const int bg = blockIdx.x;
    const int b = bg >> 6;
    const int tid = threadIdx.x;
    const float* xb = pcd + (size_t)b * 6 * N_PTS;

    const int ci = cidx[bg];
    const float cx = xb[ci], cy = xb[N_PTS + ci], cz = xb[2 * N_PTS + ci];

    float d2[64];
    float bv = 3.9e38f;
    int bi = 1 << 30;
#pragma unroll
    for (int j = 0; j < 64; ++j) {
        int p = tid + 256 * j;
        float dx = __fsub_rn(cx, xb[p]);
        float dy = __fsub_rn(cy, xb[N_PTS + p]);
        float dz = __fsub_rn(cz, xb[2 * N_PTS + p]);
        float d = __fadd_rn(__fadd_rn(__fmul_rn(dx, dx), __fmul_rn(dy, dy)),
                            __fmul_rn(dz, dz));
        d2[j] = d;
        if (d < bv) { bv = d; bi = p; }
    }

    __shared__ float rv[4];
    __shared__ int ri[4];
    __shared__ int knn[GRP_K];
    __shared__ int win_sh;

    unsigned long long removed = 0ull;

    for (int r = 0; r < GRP_K; ++r) {
        float v = bv; int i = bi;
#pragma unroll
        for (int o = 32; o > 0; o >>= 1) {
            float ov = __shfl_down(v, o);
            int oi = __shfl_down(i, o);
            if (ov < v || (ov == v && oi < i)) { v = ov; i = oi; }
        }
        int w = tid >> 6;
        if ((tid & 63) == 0) { rv[w] = v; ri[w] = i; }
        __syncthreads();
        if (tid == 0) {
            float vv = rv[0]; int ii = ri[0];
            for (int k = 1; k < 4; ++k)
                if (rv[k] < vv || (rv[k] == vv && ri[k] < ii)) { vv = rv[k]; ii = ri[k]; }
            knn[r] = ii;
            win_sh = ii;
        }
        __syncthreads();
        int win = win_sh;
        if ((win & 255) == tid) {
            removed |= 1ull << (win >> 8);
            bv = 3.9e38f; bi = 1 << 30;
#pragma unroll
            for (int j = 0; j < 64; ++j) {
                if (!((removed >> j) & 1ull) && d2[j] < bv) { bv = d2[j]; bi = tid + 256 * j; }
            }
        }
    }
    __syncthreads();

    // gather 32 x 6, subtract center from xyz channels
    if (tid < 192) {
        int k = tid / 6, c = tid % 6;
        int p = knn[k];
        float val = xb[c * N_PTS + p];
        if (c == 0) val = __fsub_rn(val, cx);
        else if (c == 1) val = __fsub_rn(val, cy);
        else if (c == 2) val = __fsub_rn(val, cz);
        xout[(size_t)bg * 192 + tid] = val;
    }
}

// ---------------- Phase C: fused MLP per group ----------------
// One block (512 thr) per (b,g). All intermediates in LDS (<52KB).
// fg@w3[:256] computed once per group (matvec), not per point.
// gemm3+gemm4 fused via 128-col chunks of f3 so f3 never fully materializes.
__global__ __launch_bounds__(512) void mlp_kernel(
    const float* __restrict__ xin,
    const float* __restrict__ w1, const float* __restrict__ b1,
    const float* __restrict__ g1, const float* __restrict__ be1,
    const float* __restrict__ m1, const float* __restrict__ v1,
    const float* __restrict__ w2, const float* __restrict__ b2,
    const float* __restrict__ w3, const float* __restrict__ b3,
    const float* __restrict__ g2, const float* __restrict__ be2,
    const float* __restrict__ m2, const float* __restrict__ v2,
    const float* __restrict__ w4, const float* __restrict__ b4,
    float* __restrict__ out) {
    const int bg = blockIdx.x;
    const int t = threadIdx.x;

    __shared__ float xs[32][6];     // input group
    __shared__ float f1s[32][128];  // after mlp1 (reused as f3 chunk later)
    __shared__ float f2s[32][256];  // after mlp2
    __shared__ float fgs[256];      // column max of f2
    __shared__ float hs[512];       // b3 + fg @ w3[:256]

    if (t < 192) xs[t / 6][t % 6] = xin[(size_t)bg * 192 + t];
    __syncthreads();

    // ---- gemm1 (6->128) + bn1 + relu ----
    {
        const int d = t & 127, k0 = t >> 7;  // k0 in 0..3
        float wv[6];
#pragma unroll
        for (int c = 0; c < 6; ++c) wv[c] = w1[c * 128 + d];
        const float bias = b1[d];
        const float sc = g1[d] / sqrtf(v1[d] + EPSF);
        const float sh = be1[d] - m1[d] * sc;
#pragma unroll
        for (int r = 0; r < 8; ++r) {
            int k = k0 + 4 * r;
            float s = bias;
#pragma unroll
            for (int c = 0; c < 6; ++c) s += xs[k][c] * wv[c];
            f1s[k][d] = fmaxf(s * sc + sh, 0.0f);
        }
    }
    __syncthreads();

    // ---- gemm2 (128->256), no activation ----
    {
        const int d = t & 255, kh = t >> 8;  // kh in 0..1 -> 16 rows each
        float acc[16];
        const float bias = b2[d];
#pragma unroll
        for (int k = 0; k < 16; ++k) acc[k] = bias;
        for (int c = 0; c < 128; ++c) {
            float wv = w2[c * 256 + d];
#pragma unroll
            for (int k = 0; k < 16; ++k) acc[k] += f1s[kh * 16 + k][c] * wv;
        }
#pragma unroll
        for (int k = 0; k < 16; ++k) f2s[kh * 16 + k][d] = acc[k];
    }
    __syncthreads();

    // ---- fg = column max over k ----
    if (t < 256) {
        float m = f2s[0][t];
#pragma unroll
        for (int k = 1; k < 32; ++k) m = fmaxf(m, f2s[k][t]);
        fgs[t] = m;
    }
    __syncthreads();

    // ---- h = b3 + fg @ w3[:256,:]  (shared across all 32 rows) ----
    {
        float s = b3[t];
        for (int c = 0; c < 256; ++c) s += fgs[c] * w3[c * 512 + t];
        hs[t] = s;
    }
    __syncthreads();

    // ---- fused gemm3(256->512)+bn2+relu -> gemm4(512->384) in 4 chunks ----
    float facc[32];
    {
        const float bias4 = (t < 384) ? b4[t] : 0.0f;
#pragma unroll
        for (int k = 0; k < 32; ++k) facc[k] = bias4;
    }
    float (*f3c)[128] = (float(*)[128])f1s;  // reuse f1s as 32x128 f3 chunk

    for (int cb = 0; cb < 4; ++cb) {
        // compute f3 chunk cols [cb*128, cb*128+128)
        {
            const int dd = t & 127, k0 = t >> 7;
            const int D = cb * 128 + dd;
            const float sc = g2[D] / sqrtf(v2[D] + EPSF);
            const float sh = be2[D] - m2[D] * sc;
            const float h = hs[D];
            float a8[8];
#pragma unroll
            for (int r = 0; r < 8; ++r) a8[r] = h;
            for (int c = 0; c < 256; ++c) {
                float wv = w3[(256 + c) * 512 + D];
#pragma unroll
                for (int r = 0; r < 8; ++r) a8[r] += f2s[k0 + 4 * r][c] * wv;
            }
#pragma unroll
            for (int r = 0; r < 8; ++r)
                f3c[k0 + 4 * r][dd] = fmaxf(a8[r] * sc + sh, 0.0f);
        }
        __syncthreads();
        // gemm4 partial over this chunk
        if (t < 384) {
            for (int c = 0; c < 128; ++c) {
                float wv = w4[(cb * 128 + c) * 384 + t];
#pragma unroll
                for (int k = 0; k < 32; ++k) facc[k] += f3c[k][c] * wv;
            }
        }
        __syncthreads();
    }

    // ---- max over k, write ----
    if (t < 384) {
        float m = facc[0];
#pragma unroll
        for (int k = 1; k < 32; ++k) m = fmaxf(m, facc[k]);
        out[(size_t)bg * 384 + t] = m;
    }
}

extern "C" void kernel_launch(void* const* d_in, const int* in_sizes, int n_in,
                              void* d_out, int out_size, void* d_ws, size_t ws_size,
                              hipStream_t stream) {
    const float* pcd = (const float*)d_in[0];
    // d_in[1] = pcd_mask (unused)
    const float* w1 = (const float*)d_in[2];
    const float* b1 = (const float*)d_in[3];
    const float* g1 = (const float*)d_in[4];
    const float* be1 = (const float*)d_in[5];
    const float* m1 = (const float*)d_in[6];
    const float* v1 = (const float*)d_in[7];
    const float* w2 = (const float*)d_in[8];
    const float* b2 = (const float*)d_in[9];
    const float* w3 = (const float*)d_in[10];
    const float* b3 = (const float*)d_in[11];
    const float* g2 = (const float*)d_in[12];
    const float* be2 = (const float*)d_in[13];
    const float* m2 = (const float*)d_in[14];
    const float* v2 = (const float*)d_in[15];
    const float* w4 = (const float*)d_in[16];
    const float* b4 = (const float*)d_in[17];
    float* out = (float*)d_out;

    int* cidx = (int*)d_ws;                                    // 2048 ints
    float* xg = (float*)((char*)d_ws + 2048 * sizeof(int));    // 2048*192 floats

    fps_kernel<<<32, 1024, 0, stream>>>(pcd, cidx);
    knn_kernel<<<2048, 256, 0, stream>>>(pcd, cidx, xg);
    mlp_kernel<<<2048, 512, 0, stream>>>(xg, w1, b1, g1, be1, m1, v1,
                                         w2, b2, w3, b3, g2, be2, m2, v2,
                                         w4, b4, out);
}

// Round 2
// 703.652 us; speedup vs baseline: 2.3837x; 2.3837x over previous
//
#include <hip/hip_runtime.h>
#include <hip/hip_bf16.h>
#include <math.h>

#define N_PTS 16384
#define NUM_G 64
#define GRP_K 32
#define EPSF 1e-5f

typedef short bf16x8 __attribute__((ext_vector_type(8)));
typedef short bf16x4 __attribute__((ext_vector_type(4)));
typedef float f32x4 __attribute__((ext_vector_type(4)));

__device__ __forceinline__ unsigned short f2bf(float x) {
    unsigned int u = __builtin_bit_cast(unsigned int, x);
    u = (u + 0x7FFFu + ((u >> 16) & 1u)) >> 16;
    return (unsigned short)u;
}
__device__ __forceinline__ float bf2f(unsigned short h) {
    unsigned int u = ((unsigned int)h) << 16;
    return __builtin_bit_cast(float, u);
}

// ---------------- Phase A: farthest point sampling (unchanged, fp32-exact) ----------------
__global__ __launch_bounds__(1024) void fps_kernel(const float* __restrict__ pcd,
                                                   int* __restrict__ cidx) {
    const int b = blockIdx.x;
    const int tid = threadIdx.x;
    const float* xb = pcd + (size_t)b * 6 * N_PTS;

    float px[16], py[16], pz[16], dist[16];
#pragma unroll
    for (int j = 0; j < 16; ++j) {
        int p = tid + 1024 * j;
        px[j] = xb[p];
        py[j] = xb[N_PTS + p];
        pz[j] = xb[2 * N_PTS + p];
        dist[j] = 1e10f;
    }

    __shared__ float red_v[16];
    __shared__ int red_i[16];
    __shared__ int far_sh;

    int far = 0;
    for (int it = 0; it < NUM_G; ++it) {
        if (tid == 0) cidx[b * NUM_G + it] = far;
        float cx = xb[far], cy = xb[N_PTS + far], cz = xb[2 * N_PTS + far];

        float bv = -1.0f;
        int bi = 0;
#pragma unroll
        for (int j = 0; j < 16; ++j) {
            float dx = __fsub_rn(px[j], cx);
            float dy = __fsub_rn(py[j], cy);
            float dz = __fsub_rn(pz[j], cz);
            float d = __fadd_rn(__fadd_rn(__fmul_rn(dx, dx), __fmul_rn(dy, dy)),
                                __fmul_rn(dz, dz));
            dist[j] = fminf(dist[j], d);
            if (dist[j] > bv) { bv = dist[j]; bi = tid + 1024 * j; }
        }
#pragma unroll
        for (int o = 32; o > 0; o >>= 1) {
            float ov = __shfl_down(bv, o);
            int oi = __shfl_down(bi, o);
            if (ov > bv || (ov == bv && oi < bi)) { bv = ov; bi = oi; }
        }
        int w = tid >> 6;
        if ((tid & 63) == 0) { red_v[w] = bv; red_i[w] = bi; }
        __syncthreads();
        if (tid == 0) {
            float v = red_v[0]; int i0 = red_i[0];
            for (int k = 1; k < 16; ++k)
                if (red_v[k] > v || (red_v[k] == v && red_i[k] < i0)) { v = red_v[k]; i0 = red_i[k]; }
            far_sh = i0;
        }
        __syncthreads();
        far = far_sh;
    }
}

// ---------------- Phase B: KNN + gather (unchanged) ----------------
__global__ __launch_bounds__(256) void knn_kernel(const float* __restrict__ pcd,
                                                  const int* __restrict__ cidx,
                                                  float* __restrict__ xout) {
    const int bg = blockIdx.x;
    const int b = bg >> 6;
    const int tid = threadIdx.x;
    const float* xb = pcd + (size_t)b * 6 * N_PTS;

    const int ci = cidx[bg];
    const float cx = xb[ci], cy = xb[N_PTS + ci], cz = xb[2 * N_PTS + ci];

    float d2[64];
    float bv = 3.9e38f;
    int bi = 1 << 30;
#pragma unroll
    for (int j = 0; j < 64; ++j) {
        int p = tid + 256 * j;
        float dx = __fsub_rn(cx, xb[p]);
        float dy = __fsub_rn(cy, xb[N_PTS + p]);
        float dz = __fsub_rn(cz, xb[2 * N_PTS + p]);
        float d = __fadd_rn(__fadd_rn(__fmul_rn(dx, dx), __fmul_rn(dy, dy)),
                            __fmul_rn(dz, dz));
        d2[j] = d;
        if (d < bv) { bv = d; bi = p; }
    }

    __shared__ float rv[4];
    __shared__ int ri[4];
    __shared__ int knn[GRP_K];
    __shared__ int win_sh;

    unsigned long long removed = 0ull;

    for (int r = 0; r < GRP_K; ++r) {
        float v = bv; int i = bi;
#pragma unroll
        for (int o = 32; o > 0; o >>= 1) {
            float ov = __shfl_down(v, o);
            int oi = __shfl_down(i, o);
            if (ov < v || (ov == v && oi < i)) { v = ov; i = oi; }
        }
        int w = tid >> 6;
        if ((tid & 63) == 0) { rv[w] = v; ri[w] = i; }
        __syncthreads();
        if (tid == 0) {
            float vv = rv[0]; int ii = ri[0];
            for (int k = 1; k < 4; ++k)
                if (rv[k] < vv || (rv[k] == vv && ri[k] < ii)) { vv = rv[k]; ii = ri[k]; }
            knn[r] = ii;
            win_sh = ii;
        }
        __syncthreads();
        int win = win_sh;
        if ((win & 255) == tid) {
            removed |= 1ull << (win >> 8);
            bv = 3.9e38f; bi = 1 << 30;
#pragma unroll
            for (int j = 0; j < 64; ++j) {
                if (!((removed >> j) & 1ull) && d2[j] < bv) { bv = d2[j]; bi = tid + 256 * j; }
            }
        }
    }
    __syncthreads();

    if (tid < 192) {
        int k = tid / 6, c = tid % 6;
        int p = knn[k];
        float val = xb[c * N_PTS + p];
        if (c == 0) val = __fsub_rn(val, cx);
        else if (c == 1) val = __fsub_rn(val, cy);
        else if (c == 2) val = __fsub_rn(val, cz);
        xout[(size_t)bg * 192 + tid] = val;
    }
}

// ---------------- Prep: weights -> bf16, transposed (k-contiguous rows) ----------------
// w2t[256][128], w3t[512][512], w4t[384][512]. Coalesced source reads.
__global__ __launch_bounds__(256) void prep_kernel(const float* __restrict__ w2,
                                                   const float* __restrict__ w3,
                                                   const float* __restrict__ w4,
                                                   unsigned short* __restrict__ w2t,
                                                   unsigned short* __restrict__ w3t,
                                                   unsigned short* __restrict__ w4t) {
    int i = blockIdx.x * 256 + threadIdx.x;
    if (i < 128 * 256) {
        int k = i >> 8, n = i & 255;
        w2t[n * 128 + k] = f2bf(w2[i]);
    } else if (i < 128 * 256 + 512 * 512) {
        int j = i - 128 * 256;
        int k = j >> 9, n = j & 511;
        w3t[n * 512 + k] = f2bf(w3[j]);
    } else {
        int j = i - 128 * 256 - 512 * 512;
        int k = j / 384, n = j % 384;
        w4t[n * 512 + k] = f2bf(w4[j]);
    }
}

// ---------------- Phase C: MFMA MLP. One block = 2 groups (M=64), 4 waves. ----------------
// Transposed-compute trick: D = mfma(Wfrag, Actfrag) -> lane holds point-col m = lane&15,
// 4 consecutive weight-cols n = (lane>>4)*4+r. Both operand frags read 16 consecutive rows
// x 8 contiguous k (one b128 each).
__global__ __launch_bounds__(256, 2) void mlp_mfma_kernel(
    const float* __restrict__ xin,
    const float* __restrict__ w1, const float* __restrict__ b1,
    const float* __restrict__ g1, const float* __restrict__ be1,
    const float* __restrict__ m1, const float* __restrict__ v1,
    const unsigned short* __restrict__ w2t, const float* __restrict__ b2,
    const unsigned short* __restrict__ w3t, const float* __restrict__ b3,
    const float* __restrict__ g2, const float* __restrict__ be2,
    const float* __restrict__ m2, const float* __restrict__ v2,
    const unsigned short* __restrict__ w4t, const float* __restrict__ b4,
    float* __restrict__ out) {
    const int bg0 = blockIdx.x * 2;
    const int t = threadIdx.x;
    const int w = t >> 6;        // wave 0..3
    const int lane = t & 63;
    const int lr = lane & 15;    // point-row within m-tile
    const int lq = lane >> 4;    // quad

    // f1s row stride 136 (272B = 68 dw, %32=4 -> 2-way bank = free); reused as f3 chunk.
    // f2s row stride 264 (528B = 132 dw, %32=4 -> free).
    __shared__ __align__(16) unsigned short f1s[64 * 136];
    __shared__ __align__(16) unsigned short f2s[64 * 264];
    __shared__ __align__(16) unsigned short fgs[2 * 256];
    __shared__ float xs[2 * 32 * 6];

    // ---- load inputs (2 groups x 32 x 6, contiguous) ----
    for (int i = t; i < 384; i += 256) xs[i] = xin[(size_t)bg0 * 192 + i];
    __syncthreads();

    // ---- L1: 6->128, bn1, relu (VALU, tiny) -> f1s bf16 ----
    {
        const int d = t & 127, mh = t >> 7;  // wave-uniform mh
        float wv[6];
#pragma unroll
        for (int c = 0; c < 6; ++c) wv[c] = w1[c * 128 + d];
        const float sc = g1[d] * rsqrtf(v1[d] + EPSF);
        const float sh = be1[d] - m1[d] * sc;
        const float bias = b1[d];
#pragma unroll
        for (int j = 0; j < 32; ++j) {
            float s = bias;
#pragma unroll
            for (int c = 0; c < 6; ++c) s += xs[mh * 192 + j * 6 + c] * wv[c];
            f1s[(mh * 32 + j) * 136 + d] = f2bf(fmaxf(s * sc + sh, 0.0f));
        }
    }
    __syncthreads();

    // ---- L2: [64x128] @ w2[128x256] -> f2s bf16. Wave w owns cols [64w,64w+64). ----
    {
        const int n0 = w * 64;
        f32x4 acc[4][4];  // [mt][nti]
#pragma unroll
        for (int nti = 0; nti < 4; ++nti) {
            f32x4 bq = *(const f32x4*)(b2 + n0 + nti * 16 + lq * 4);
#pragma unroll
            for (int mt = 0; mt < 4; ++mt) acc[mt][nti] = bq;
        }
        for (int ks = 0; ks < 4; ++ks) {
            bf16x8 xf[4], wf[4];
#pragma unroll
            for (int mt = 0; mt < 4; ++mt)
                xf[mt] = *(const bf16x8*)(f1s + (mt * 16 + lr) * 136 + ks * 32 + lq * 8);
#pragma unroll
            for (int nti = 0; nti < 4; ++nti)
                wf[nti] = *(const bf16x8*)(w2t + (n0 + nti * 16 + lr) * 128 + ks * 32 + lq * 8);
#pragma unroll
            for (int mt = 0; mt < 4; ++mt)
#pragma unroll
                for (int nti = 0; nti < 4; ++nti)
                    acc[mt][nti] = __builtin_amdgcn_mfma_f32_16x16x32_bf16(wf[nti], xf[mt], acc[mt][nti], 0, 0, 0);
        }
#pragma unroll
        for (int mt = 0; mt < 4; ++mt)
#pragma unroll
            for (int nti = 0; nti < 4; ++nti) {
                bf16x4 p;
#pragma unroll
                for (int r = 0; r < 4; ++r) p[r] = (short)f2bf(acc[mt][nti][r]);
                *(bf16x4*)(f2s + (mt * 16 + lr) * 264 + n0 + nti * 16 + lq * 4) = p;
            }
    }
    __syncthreads();

    // ---- fg = column max per group ----
    for (int idx = t; idx < 512; idx += 256) {
        int g = idx >> 8, n = idx & 255;
        float m = -3.9e38f;
#pragma unroll
        for (int k = 0; k < 32; ++k) m = fmaxf(m, bf2f(f2s[(g * 32 + k) * 264 + n]));
        fgs[g * 256 + n] = f2bf(m);
    }
    __syncthreads();

    // ---- L3 (K=512: fg-part broadcast + f2-part) chunked x4, fused with L4 partials ----
    f32x4 acc4[6][4];  // [nti][mt], wave cols [96w, 96w+96)
#pragma unroll
    for (int nti = 0; nti < 6; ++nti) {
        f32x4 bq = *(const f32x4*)(b4 + w * 96 + nti * 16 + lq * 4);
#pragma unroll
        for (int mt = 0; mt < 4; ++mt) acc4[nti][mt] = bq;
    }

    for (int cb = 0; cb < 4; ++cb) {
        // L3 chunk: f3 cols [cb*128, cb*128+128); wave sub-cols [32w, 32w+32)
        f32x4 acc3[2][4];  // [nti][mt]
#pragma unroll
        for (int nti = 0; nti < 2; ++nti) {
            f32x4 bq = *(const f32x4*)(b3 + cb * 128 + w * 32 + nti * 16 + lq * 4);
#pragma unroll
            for (int mt = 0; mt < 4; ++mt) acc3[nti][mt] = bq;
        }
        for (int ks = 0; ks < 16; ++ks) {
            bf16x8 xf[4];
            if (ks < 8) {
                bf16x8 x0 = *(const bf16x8*)(fgs + ks * 32 + lq * 8);
                bf16x8 x1 = *(const bf16x8*)(fgs + 256 + ks * 32 + lq * 8);
                xf[0] = x0; xf[1] = x0; xf[2] = x1; xf[3] = x1;
            } else {
#pragma unroll
                for (int mt = 0; mt < 4; ++mt)
                    xf[mt] = *(const bf16x8*)(f2s + (mt * 16 + lr) * 264 + (ks - 8) * 32 + lq * 8);
            }
#pragma unroll
            for (int nti = 0; nti < 2; ++nti) {
                bf16x8 wf = *(const bf16x8*)(w3t + (size_t)(cb * 128 + w * 32 + nti * 16 + lr) * 512 + ks * 32 + lq * 8);
#pragma unroll
                for (int mt = 0; mt < 4; ++mt)
                    acc3[nti][mt] = __builtin_amdgcn_mfma_f32_16x16x32_bf16(wf, xf[mt], acc3[nti][mt], 0, 0, 0);
            }
        }
        // bn2 + relu -> f3 chunk (reuse f1s)
#pragma unroll
        for (int nti = 0; nti < 2; ++nti) {
            const int nq = cb * 128 + w * 32 + nti * 16 + lq * 4;
            f32x4 g2q = *(const f32x4*)(g2 + nq);
            f32x4 v2q = *(const f32x4*)(v2 + nq);
            f32x4 m2q = *(const f32x4*)(m2 + nq);
            f32x4 beq = *(const f32x4*)(be2 + nq);
            f32x4 sc, sh;
#pragma unroll
            for (int r = 0; r < 4; ++r) {
                sc[r] = g2q[r] * rsqrtf(v2q[r] + EPSF);
                sh[r] = beq[r] - m2q[r] * sc[r];
            }
#pragma unroll
            for (int mt = 0; mt < 4; ++mt) {
                bf16x4 p;
#pragma unroll
                for (int r = 0; r < 4; ++r)
                    p[r] = (short)f2bf(fmaxf(acc3[nti][mt][r] * sc[r] + sh[r], 0.0f));
                *(bf16x4*)(f1s + (mt * 16 + lr) * 136 + w * 32 + nti * 16 + lq * 4) = p;
            }
        }
        __syncthreads();
        // L4 partial over this chunk's 128 k
        for (int kl = 0; kl < 4; ++kl) {
            bf16x8 xf[4];
#pragma unroll
            for (int mt = 0; mt < 4; ++mt)
                xf[mt] = *(const bf16x8*)(f1s + (mt * 16 + lr) * 136 + kl * 32 + lq * 8);
#pragma unroll
            for (int nti = 0; nti < 6; ++nti) {
                bf16x8 wf = *(const bf16x8*)(w4t + (size_t)(w * 96 + nti * 16 + lr) * 512 + cb * 128 + kl * 32 + lq * 8);
#pragma unroll
                for (int mt = 0; mt < 4; ++mt)
                    acc4[nti][mt] = __builtin_amdgcn_mfma_f32_16x16x32_bf16(wf, xf[mt], acc4[nti][mt], 0, 0, 0);
            }
        }
        if (cb < 3) __syncthreads();
    }

    // ---- max over 32 points per group, write out ----
#pragma unroll
    for (int nti = 0; nti < 6; ++nti) {
#pragma unroll
        for (int g = 0; g < 2; ++g) {
            f32x4 vv;
#pragma unroll
            for (int r = 0; r < 4; ++r)
                vv[r] = fmaxf(acc4[nti][2 * g][r], acc4[nti][2 * g + 1][r]);
#pragma unroll
            for (int mask = 1; mask <= 8; mask <<= 1) {
#pragma unroll
                for (int r = 0; r < 4; ++r)
                    vv[r] = fmaxf(vv[r], __shfl_xor(vv[r], mask, 64));
            }
            if (lr == 0)
                *(f32x4*)(out + (size_t)(bg0 + g) * 384 + w * 96 + nti * 16 + lq * 4) = vv;
        }
    }
}

extern "C" void kernel_launch(void* const* d_in, const int* in_sizes, int n_in,
                              void* d_out, int out_size, void* d_ws, size_t ws_size,
                              hipStream_t stream) {
    const float* pcd = (const float*)d_in[0];
    const float* w1 = (const float*)d_in[2];
    const float* b1 = (const float*)d_in[3];
    const float* g1 = (const float*)d_in[4];
    const float* be1 = (const float*)d_in[5];
    const float* m1 = (const float*)d_in[6];
    const float* v1 = (const float*)d_in[7];
    const float* w2 = (const float*)d_in[8];
    const float* b2 = (const float*)d_in[9];
    const float* w3 = (const float*)d_in[10];
    const float* b3 = (const float*)d_in[11];
    const float* g2 = (const float*)d_in[12];
    const float* be2 = (const float*)d_in[13];
    const float* m2 = (const float*)d_in[14];
    const float* v2 = (const float*)d_in[15];
    const float* w4 = (const float*)d_in[16];
    const float* b4 = (const float*)d_in[17];
    float* out = (float*)d_out;

    char* ws = (char*)d_ws;
    int* cidx = (int*)ws;                                   // 8192 B
    float* xg = (float*)(ws + 8192);                        // 1,572,864 B
    unsigned short* w2t = (unsigned short*)(ws + 1581056);  // 65,536 B
    unsigned short* w3t = (unsigned short*)(ws + 1646592);  // 524,288 B
    unsigned short* w4t = (unsigned short*)(ws + 2170880);  // 393,216 B

    prep_kernel<<<1920, 256, 0, stream>>>(w2, w3, w4, w2t, w3t, w4t);
    fps_kernel<<<32, 1024, 0, stream>>>(pcd, cidx);
    knn_kernel<<<2048, 256, 0, stream>>>(pcd, cidx, xg);
    mlp_mfma_kernel<<<1024, 256, 0, stream>>>(xg, w1, b1, g1, be1, m1, v1,
                                              w2t, b2, w3t, b3, g2, be2, m2, v2,
                                              w4t, b4, out);
}

// Round 3
// 552.297 us; speedup vs baseline: 3.0369x; 1.2740x over previous
//
#include <hip/hip_runtime.h>
#include <hip/hip_bf16.h>
#include <math.h>

#define N_PTS 16384
#define NUM_G 64
#define GRP_K 32
#define EPSF 1e-5f

typedef short bf16x8 __attribute__((ext_vector_type(8)));
typedef short bf16x4 __attribute__((ext_vector_type(4)));
typedef float f32x4 __attribute__((ext_vector_type(4)));

__device__ __forceinline__ unsigned short f2bf(float x) {
    unsigned int u = __builtin_bit_cast(unsigned int, x);
    u = (u + 0x7FFFu + ((u >> 16) & 1u)) >> 16;
    return (unsigned short)u;
}
__device__ __forceinline__ float bf2f(unsigned short h) {
    unsigned int u = ((unsigned int)h) << 16;
    return __builtin_bit_cast(float, u);
}

// ---------------- Phase A: farthest point sampling ----------------
// 1 block/batch, 1024 thr x 16 pts. One barrier per iteration: butterfly wave
// reduce -> parity-buffered LDS -> all threads merge 16 wave results.
__global__ __launch_bounds__(1024) void fps_kernel(const float* __restrict__ pcd,
                                                   int* __restrict__ cidx) {
    const int b = blockIdx.x;
    const int tid = threadIdx.x;
    const int lane = tid & 63, w = tid >> 6;
    const float* xb = pcd + (size_t)b * 6 * N_PTS;

    float px[16], py[16], pz[16], dist[16];
#pragma unroll
    for (int j = 0; j < 16; ++j) {
        int p = tid + 1024 * j;
        px[j] = xb[p];
        py[j] = xb[N_PTS + p];
        pz[j] = xb[2 * N_PTS + p];
        dist[j] = 1e10f;
    }

    __shared__ float rv[2][16];
    __shared__ int ri[2][16];

    int far = 0;
    for (int it = 0; it < NUM_G; ++it) {
        if (tid == 0) cidx[b * NUM_G + it] = far;
        float cx = xb[far], cy = xb[N_PTS + far], cz = xb[2 * N_PTS + far];

        float bv = -1.0f;
        int bi = 0;
#pragma unroll
        for (int j = 0; j < 16; ++j) {
            float dx = __fsub_rn(px[j], cx);
            float dy = __fsub_rn(py[j], cy);
            float dz = __fsub_rn(pz[j], cz);
            float d = __fadd_rn(__fadd_rn(__fmul_rn(dx, dx), __fmul_rn(dy, dy)),
                                __fmul_rn(dz, dz));
            dist[j] = fminf(dist[j], d);
            if (dist[j] > bv) { bv = dist[j]; bi = tid + 1024 * j; }  // j asc => idx asc
        }
        // butterfly wave reduce: lexicographic max on (v, -i) => assoc+comm, exact
#pragma unroll
        for (int m = 1; m < 64; m <<= 1) {
            float ov = __shfl_xor(bv, m, 64);
            int oi = __shfl_xor(bi, m, 64);
            if (ov > bv || (ov == bv && oi < bi)) { bv = ov; bi = oi; }
        }
        if (lane == 0) { rv[it & 1][w] = bv; ri[it & 1][w] = bi; }
        __syncthreads();
        float gv = rv[it & 1][0];
        int gi = ri[it & 1][0];
#pragma unroll
        for (int k = 1; k < 16; ++k) {
            float ov = rv[it & 1][k];
            int oi = ri[it & 1][k];
            if (ov > gv || (ov == gv && oi < gi)) { gv = ov; gi = oi; }
        }
        far = gi;  // identical in every thread
    }
}

// ---------------- Phase B: KNN via per-thread top-2 + 16 dual-extraction rounds ----------------
// Packed key u64 = (d2bits<<32)|idx: u64 order == (d2, idx) lexicographic (d2>=0).
// Tournament of per-thread sorted top-2 pairs gives exact global top-2 per round.
__device__ __forceinline__ void merge2(unsigned long long& a1, unsigned long long& a2,
                                       unsigned long long o1, unsigned long long o2) {
    unsigned long long hi = a1 > o1 ? a1 : o1;
    a1 = a1 < o1 ? a1 : o1;
    unsigned long long lo2 = a2 < o2 ? a2 : o2;
    a2 = hi < lo2 ? hi : lo2;
}

__global__ __launch_bounds__(256) void knn_kernel(const float* __restrict__ pcd,
                                                  const int* __restrict__ cidx,
                                                  float* __restrict__ xout) {
    const int bg = blockIdx.x;
    const int b = bg >> 6;
    const int tid = threadIdx.x;
    const int lane = tid & 63, myw = tid >> 6;
    const float* xb = pcd + (size_t)b * 6 * N_PTS;

    const int ci = cidx[bg];
    const float cx = xb[ci], cy = xb[N_PTS + ci], cz = xb[2 * N_PTS + ci];

    // per-thread sorted top-2 of its 64 points p = tid + 256*j
    unsigned long long b1 = ~0ull, b2 = ~0ull;
#pragma unroll
    for (int j = 0; j < 64; ++j) {
        int p = tid + (j << 8);
        float dx = __fsub_rn(cx, xb[p]);
        float dy = __fsub_rn(cy, xb[N_PTS + p]);
        float dz = __fsub_rn(cz, xb[2 * N_PTS + p]);
        float d = __fadd_rn(__fadd_rn(__fmul_rn(dx, dx), __fmul_rn(dy, dy)),
                            __fmul_rn(dz, dz));
        unsigned long long v = ((unsigned long long)__float_as_uint(d) << 32) | (unsigned int)p;
        unsigned long long hi = b1 > v ? b1 : v;
        b1 = b1 < v ? b1 : v;
        b2 = b2 < hi ? b2 : hi;
    }

    __shared__ unsigned long long wb1[2][4], wb2[2][4];
    __shared__ int knn_sh[GRP_K];

    unsigned long long removed = 0ull;

    for (int r = 0; r < 16; ++r) {
        // wave butterfly top-2 (all lanes end with wave result)
        unsigned long long r1 = b1, r2 = b2;
#pragma unroll
        for (int m = 1; m < 64; m <<= 1) {
            unsigned long long o1 = __shfl_xor(r1, m, 64);
            unsigned long long o2 = __shfl_xor(r2, m, 64);
            merge2(r1, r2, o1, o2);
        }
        if (lane == 0) { wb1[r & 1][myw] = r1; wb2[r & 1][myw] = r2; }
        __syncthreads();
        // all threads merge the 4 wave pairs (identical result everywhere)
        unsigned long long g1 = wb1[r & 1][0], g2 = wb2[r & 1][0];
#pragma unroll
        for (int k = 1; k < 4; ++k) merge2(g1, g2, wb1[r & 1][k], wb2[r & 1][k]);

        int q1 = (int)(unsigned int)g1;  // low 32 = point index
        int q2 = (int)(unsigned int)g2;
        if (tid == 0) { knn_sh[2 * r] = q1; knn_sh[2 * r + 1] = q2; }

        int wt1 = q1 & 255, wt2 = q2 & 255;
        if (tid == wt1) removed |= 1ull << (q1 >> 8);
        if (tid == wt2) removed |= 1ull << (q2 >> 8);

        // winner-wave parallel rescan (recompute, masked) -> new top-2 for that thread
#pragma unroll 1
        for (int s = 0; s < 2; ++s) {
            if (s == 1 && wt2 == wt1) break;       // block-uniform
            int wt = s ? wt2 : wt1;
            if ((wt >> 6) != myw) continue;        // wave-uniform
            unsigned long long rm = __shfl(removed, wt & 63, 64);
            int q = wt + (lane << 8);
            float dx = __fsub_rn(cx, xb[q]);
            float dy = __fsub_rn(cy, xb[N_PTS + q]);
            float dz = __fsub_rn(cz, xb[2 * N_PTS + q]);
            float d = __fadd_rn(__fadd_rn(__fmul_rn(dx, dx), __fmul_rn(dy, dy)),
                                __fmul_rn(dz, dz));
            unsigned long long v = ((unsigned long long)__float_as_uint(d) << 32) | (unsigned int)q;
            if ((rm >> lane) & 1ull) v = ~0ull;
            unsigned long long s1 = v, s2 = ~0ull;
#pragma unroll
            for (int m = 1; m < 64; m <<= 1) {
                unsigned long long o1 = __shfl_xor(s1, m, 64);
                unsigned long long o2 = __shfl_xor(s2, m, 64);
                merge2(s1, s2, o1, o2);
            }
            if (tid == wt) { b1 = s1; b2 = s2; }
        }
    }
    __syncthreads();

    // gather 32 x 6, subtract center from xyz channels (set order-invariant downstream)
    if (tid < 192) {
        int k = tid / 6, c = tid % 6;
        int p = knn_sh[k];
        float val = xb[c * N_PTS + p];
        if (c == 0) val = __fsub_rn(val, cx);
        else if (c == 1) val = __fsub_rn(val, cy);
        else if (c == 2) val = __fsub_rn(val, cz);
        xout[(size_t)bg * 192 + tid] = val;
    }
}

// ---------------- Prep: weights -> bf16, transposed (k-contiguous rows) ----------------
__global__ __launch_bounds__(256) void prep_kernel(const float* __restrict__ w2,
                                                   const float* __restrict__ w3,
                                                   const float* __restrict__ w4,
                                                   unsigned short* __restrict__ w2t,
                                                   unsigned short* __restrict__ w3t,
                                                   unsigned short* __restrict__ w4t) {
    int i = blockIdx.x * 256 + threadIdx.x;
    if (i < 128 * 256) {
        int k = i >> 8, n = i & 255;
        w2t[n * 128 + k] = f2bf(w2[i]);
    } else if (i < 128 * 256 + 512 * 512) {
        int j = i - 128 * 256;
        int k = j >> 9, n = j & 511;
        w3t[n * 512 + k] = f2bf(w3[j]);
    } else {
        int j = i - 128 * 256 - 512 * 512;
        int k = j / 384, n = j % 384;
        w4t[n * 512 + k] = f2bf(w4[j]);
    }
}

// ---------------- Phase C: MFMA MLP (unchanged from R1) ----------------
__global__ __launch_bounds__(256, 2) void mlp_mfma_kernel(
    const float* __restrict__ xin,
    const float* __restrict__ w1, const float* __restrict__ b1,
    const float* __restrict__ g1, const float* __restrict__ be1,
    const float* __restrict__ m1, const float* __restrict__ v1,
    const unsigned short* __restrict__ w2t, const float* __restrict__ b2,
    const unsigned short* __restrict__ w3t, const float* __restrict__ b3,
    const float* __restrict__ g2, const float* __restrict__ be2,
    const float* __restrict__ m2, const float* __restrict__ v2,
    const unsigned short* __restrict__ w4t, const float* __restrict__ b4,
    float* __restrict__ out) {
    const int bg0 = blockIdx.x * 2;
    const int t = threadIdx.x;
    const int w = t >> 6;
    const int lane = t & 63;
    const int lr = lane & 15;
    const int lq = lane >> 4;

    __shared__ __align__(16) unsigned short f1s[64 * 136];
    __shared__ __align__(16) unsigned short f2s[64 * 264];
    __shared__ __align__(16) unsigned short fgs[2 * 256];
    __shared__ float xs[2 * 32 * 6];

    for (int i = t; i < 384; i += 256) xs[i] = xin[(size_t)bg0 * 192 + i];
    __syncthreads();

    {
        const int d = t & 127, mh = t >> 7;
        float wv[6];
#pragma unroll
        for (int c = 0; c < 6; ++c) wv[c] = w1[c * 128 + d];
        const float sc = g1[d] * rsqrtf(v1[d] + EPSF);
        const float sh = be1[d] - m1[d] * sc;
        const float bias = b1[d];
#pragma unroll
        for (int j = 0; j < 32; ++j) {
            float s = bias;
#pragma unroll
            for (int c = 0; c < 6; ++c) s += xs[mh * 192 + j * 6 + c] * wv[c];
            f1s[(mh * 32 + j) * 136 + d] = f2bf(fmaxf(s * sc + sh, 0.0f));
        }
    }
    __syncthreads();

    {
        const int n0 = w * 64;
        f32x4 acc[4][4];
#pragma unroll
        for (int nti = 0; nti < 4; ++nti) {
            f32x4 bq = *(const f32x4*)(b2 + n0 + nti * 16 + lq * 4);
#pragma unroll
            for (int mt = 0; mt < 4; ++mt) acc[mt][nti] = bq;
        }
        for (int ks = 0; ks < 4; ++ks) {
            bf16x8 xf[4], wf[4];
#pragma unroll
            for (int mt = 0; mt < 4; ++mt)
                xf[mt] = *(const bf16x8*)(f1s + (mt * 16 + lr) * 136 + ks * 32 + lq * 8);
#pragma unroll
            for (int nti = 0; nti < 4; ++nti)
                wf[nti] = *(const bf16x8*)(w2t + (n0 + nti * 16 + lr) * 128 + ks * 32 + lq * 8);
#pragma unroll
            for (int mt = 0; mt < 4; ++mt)
#pragma unroll
                for (int nti = 0; nti < 4; ++nti)
                    acc[mt][nti] = __builtin_amdgcn_mfma_f32_16x16x32_bf16(wf[nti], xf[mt], acc[mt][nti], 0, 0, 0);
        }
#pragma unroll
        for (int mt = 0; mt < 4; ++mt)
#pragma unroll
            for (int nti = 0; nti < 4; ++nti) {
                bf16x4 p;
#pragma unroll
                for (int r = 0; r < 4; ++r) p[r] = (short)f2bf(acc[mt][nti][r]);
                *(bf16x4*)(f2s + (mt * 16 + lr) * 264 + n0 + nti * 16 + lq * 4) = p;
            }
    }
    __syncthreads();

    for (int idx = t; idx < 512; idx += 256) {
        int g = idx >> 8, n = idx & 255;
        float m = -3.9e38f;
#pragma unroll
        for (int k = 0; k < 32; ++k) m = fmaxf(m, bf2f(f2s[(g * 32 + k) * 264 + n]));
        fgs[g * 256 + n] = f2bf(m);
    }
    __syncthreads();

    f32x4 acc4[6][4];
#pragma unroll
    for (int nti = 0; nti < 6; ++nti) {
        f32x4 bq = *(const f32x4*)(b4 + w * 96 + nti * 16 + lq * 4);
#pragma unroll
        for (int mt = 0; mt < 4; ++mt) acc4[nti][mt] = bq;
    }

    for (int cb = 0; cb < 4; ++cb) {
        f32x4 acc3[2][4];
#pragma unroll
        for (int nti = 0; nti < 2; ++nti) {
            f32x4 bq = *(const f32x4*)(b3 + cb * 128 + w * 32 + nti * 16 + lq * 4);
#pragma unroll
            for (int mt = 0; mt < 4; ++mt) acc3[nti][mt] = bq;
        }
        for (int ks = 0; ks < 16; ++ks) {
            bf16x8 xf[4];
            if (ks < 8) {
                bf16x8 x0 = *(const bf16x8*)(fgs + ks * 32 + lq * 8);
                bf16x8 x1 = *(const bf16x8*)(fgs + 256 + ks * 32 + lq * 8);
                xf[0] = x0; xf[1] = x0; xf[2] = x1; xf[3] = x1;
            } else {
#pragma unroll
                for (int mt = 0; mt < 4; ++mt)
                    xf[mt] = *(const bf16x8*)(f2s + (mt * 16 + lr) * 264 + (ks - 8) * 32 + lq * 8);
            }
#pragma unroll
            for (int nti = 0; nti < 2; ++nti) {
                bf16x8 wf = *(const bf16x8*)(w3t + (size_t)(cb * 128 + w * 32 + nti * 16 + lr) * 512 + ks * 32 + lq * 8);
#pragma unroll
                for (int mt = 0; mt < 4; ++mt)
                    acc3[nti][mt] = __builtin_amdgcn_mfma_f32_16x16x32_bf16(wf, xf[mt], acc3[nti][mt], 0, 0, 0);
            }
        }
#pragma unroll
        for (int nti = 0; nti < 2; ++nti) {
            const int nq = cb * 128 + w * 32 + nti * 16 + lq * 4;
            f32x4 g2q = *(const f32x4*)(g2 + nq);
            f32x4 v2q = *(const f32x4*)(v2 + nq);
            f32x4 m2q = *(const f32x4*)(m2 + nq);
            f32x4 beq = *(const f32x4*)(be2 + nq);
            f32x4 sc, sh;
#pragma unroll
            for (int r = 0; r < 4; ++r) {
                sc[r] = g2q[r] * rsqrtf(v2q[r] + EPSF);
                sh[r] = beq[r] - m2q[r] * sc[r];
            }
#pragma unroll
            for (int mt = 0; mt < 4; ++mt) {
                bf16x4 p;
#pragma unroll
                for (int r = 0; r < 4; ++r)
                    p[r] = (short)f2bf(fmaxf(acc3[nti][mt][r] * sc[r] + sh[r], 0.0f));
                *(bf16x4*)(f1s + (mt * 16 + lr) * 136 + w * 32 + nti * 16 + lq * 4) = p;
            }
        }
        __syncthreads();
        for (int kl = 0; kl < 4; ++kl) {
            bf16x8 xf[4];
#pragma unroll
            for (int mt = 0; mt < 4; ++mt)
                xf[mt] = *(const bf16x8*)(f1s + (mt * 16 + lr) * 136 + kl * 32 + lq * 8);
#pragma unroll
            for (int nti = 0; nti < 6; ++nti) {
                bf16x8 wf = *(const bf16x8*)(w4t + (size_t)(w * 96 + nti * 16 + lr) * 512 + cb * 128 + kl * 32 + lq * 8);
#pragma unroll
                for (int mt = 0; mt < 4; ++mt)
                    acc4[nti][mt] = __builtin_amdgcn_mfma_f32_16x16x32_bf16(wf, xf[mt], acc4[nti][mt], 0, 0, 0);
            }
        }
        if (cb < 3) __syncthreads();
    }

#pragma unroll
    for (int nti = 0; nti < 6; ++nti) {
#pragma unroll
        for (int g = 0; g < 2; ++g) {
            f32x4 vv;
#pragma unroll
            for (int r = 0; r < 4; ++r)
                vv[r] = fmaxf(acc4[nti][2 * g][r], acc4[nti][2 * g + 1][r]);
#pragma unroll
            for (int mask = 1; mask <= 8; mask <<= 1) {
#pragma unroll
                for (int r = 0; r < 4; ++r)
                    vv[r] = fmaxf(vv[r], __shfl_xor(vv[r], mask, 64));
            }
            if (lr == 0)
                *(f32x4*)(out + (size_t)(bg0 + g) * 384 + w * 96 + nti * 16 + lq * 4) = vv;
        }
    }
}

extern "C" void kernel_launch(void* const* d_in, const int* in_sizes, int n_in,
                              void* d_out, int out_size, void* d_ws, size_t ws_size,
                              hipStream_t stream) {
    const float* pcd = (const float*)d_in[0];
    const float* w1 = (const float*)d_in[2];
    const float* b1 = (const float*)d_in[3];
    const float* g1 = (const float*)d_in[4];
    const float* be1 = (const float*)d_in[5];
    const float* m1 = (const float*)d_in[6];
    const float* v1 = (const float*)d_in[7];
    const float* w2 = (const float*)d_in[8];
    const float* b2 = (const float*)d_in[9];
    const float* w3 = (const float*)d_in[10];
    const float* b3 = (const float*)d_in[11];
    const float* g2 = (const float*)d_in[12];
    const float* be2 = (const float*)d_in[13];
    const float* m2 = (const float*)d_in[14];
    const float* v2 = (const float*)d_in[15];
    const float* w4 = (const float*)d_in[16];
    const float* b4 = (const float*)d_in[17];
    float* out = (float*)d_out;

    char* ws = (char*)d_ws;
    int* cidx = (int*)ws;                                   // 8192 B
    float* xg = (float*)(ws + 8192);                        // 1,572,864 B
    unsigned short* w2t = (unsigned short*)(ws + 1581056);  // 65,536 B
    unsigned short* w3t = (unsigned short*)(ws + 1646592);  // 524,288 B
    unsigned short* w4t = (unsigned short*)(ws + 2170880);  // 393,216 B

    prep_kernel<<<1920, 256, 0, stream>>>(w2, w3, w4, w2t, w3t, w4t);
    fps_kernel<<<32, 1024, 0, stream>>>(pcd, cidx);
    knn_kernel<<<2048, 256, 0, stream>>>(pcd, cidx, xg);
    mlp_mfma_kernel<<<1024, 256, 0, stream>>>(xg, w1, b1, g1, be1, m1, v1,
                                              w2t, b2, w3t, b3, g2, be2, m2, v2,
                                              w4t, b4, out);
}

// Round 4
// 545.219 us; speedup vs baseline: 3.0763x; 1.0130x over previous
//
#include <hip/hip_runtime.h>
#include <hip/hip_bf16.h>
#include <math.h>

#define N_PTS 16384
#define NUM_G 64
#define GRP_K 32
#define EPSF 1e-5f

typedef short bf16x8 __attribute__((ext_vector_type(8)));
typedef short bf16x4 __attribute__((ext_vector_type(4)));
typedef float f32x4 __attribute__((ext_vector_type(4)));
typedef unsigned short u16x8 __attribute__((ext_vector_type(8)));

__device__ __forceinline__ unsigned short f2bf(float x) {
    unsigned int u = __builtin_bit_cast(unsigned int, x);
    u = (u + 0x7FFFu + ((u >> 16) & 1u)) >> 16;
    return (unsigned short)u;
}
__device__ __forceinline__ float bf2f(unsigned short h) {
    unsigned int u = ((unsigned int)h) << 16;
    return __builtin_bit_cast(float, u);
}

// ---------------- Phase A: farthest point sampling ----------------
// 1 block/batch, 1024 thr x 16 pts. One barrier/iter (parity LDS buffer).
// cidx kept in LDS until the end: no global-store vmcnt drain at the barrier.
__global__ __launch_bounds__(1024) void fps_kernel(const float* __restrict__ pcd,
                                                   int* __restrict__ cidx) {
    const int b = blockIdx.x;
    const int tid = threadIdx.x;
    const int lane = tid & 63, w = tid >> 6;
    const float* xb = pcd + (size_t)b * 6 * N_PTS;

    float px[16], py[16], pz[16], dist[16];
#pragma unroll
    for (int j = 0; j < 16; ++j) {
        int p = tid + 1024 * j;
        px[j] = xb[p];
        py[j] = xb[N_PTS + p];
        pz[j] = xb[2 * N_PTS + p];
        dist[j] = 1e10f;
    }

    __shared__ float rv[2][16];
    __shared__ int ri[2][16];
    __shared__ int clds[NUM_G];

    int far = 0;
    for (int it = 0; it < NUM_G; ++it) {
        float cx = xb[far], cy = xb[N_PTS + far], cz = xb[2 * N_PTS + far];

        float bv = -1.0f;
        int bi = 0;
#pragma unroll
        for (int j = 0; j < 16; ++j) {
            float dx = __fsub_rn(px[j], cx);
            float dy = __fsub_rn(py[j], cy);
            float dz = __fsub_rn(pz[j], cz);
            float d = __fadd_rn(__fadd_rn(__fmul_rn(dx, dx), __fmul_rn(dy, dy)),
                                __fmul_rn(dz, dz));
            dist[j] = fminf(dist[j], d);
            if (dist[j] > bv) { bv = dist[j]; bi = tid + 1024 * j; }  // j asc => idx asc
        }
        // butterfly wave reduce: lexicographic max on (v, -i), assoc+comm => exact
#pragma unroll
        for (int m = 1; m < 64; m <<= 1) {
            float ov = __shfl_xor(bv, m, 64);
            int oi = __shfl_xor(bi, m, 64);
            if (ov > bv || (ov == bv && oi < bi)) { bv = ov; bi = oi; }
        }
        if (lane == 0) { rv[it & 1][w] = bv; ri[it & 1][w] = bi; }
        if (tid == 0) clds[it] = far;  // LDS only
        __syncthreads();
        float gv = rv[it & 1][0];
        int gi = ri[it & 1][0];
#pragma unroll
        for (int k = 1; k < 16; ++k) {
            float ov = rv[it & 1][k];
            int oi = ri[it & 1][k];
            if (ov > gv || (ov == gv && oi < gi)) { gv = ov; gi = oi; }
        }
        far = gi;  // identical in every thread
    }
    __syncthreads();
    if (tid < NUM_G) cidx[b * NUM_G + tid] = clds[tid];
}

// ---------------- Phase B: KNN via per-thread top-2 + 16 dual-extraction rounds ----------------
__device__ __forceinline__ void merge2(unsigned long long& a1, unsigned long long& a2,
                                       unsigned long long o1, unsigned long long o2) {
    unsigned long long hi = a1 > o1 ? a1 : o1;
    a1 = a1 < o1 ? a1 : o1;
    unsigned long long lo2 = a2 < o2 ? a2 : o2;
    a2 = hi < lo2 ? hi : lo2;
}

__global__ __launch_bounds__(256) void knn_kernel(const float* __restrict__ pcd,
                                                  const int* __restrict__ cidx,
                                                  float* __restrict__ xout) {
    const int bg = blockIdx.x;
    const int b = bg >> 6;
    const int tid = threadIdx.x;
    const int lane = tid & 63, myw = tid >> 6;
    const float* xb = pcd + (size_t)b * 6 * N_PTS;

    const int ci = cidx[bg];
    const float cx = xb[ci], cy = xb[N_PTS + ci], cz = xb[2 * N_PTS + ci];

    unsigned long long b1 = ~0ull, b2 = ~0ull;
#pragma unroll
    for (int j = 0; j < 64; ++j) {
        int p = tid + (j << 8);
        float dx = __fsub_rn(cx, xb[p]);
        float dy = __fsub_rn(cy, xb[N_PTS + p]);
        float dz = __fsub_rn(cz, xb[2 * N_PTS + p]);
        float d = __fadd_rn(__fadd_rn(__fmul_rn(dx, dx), __fmul_rn(dy, dy)),
                            __fmul_rn(dz, dz));
        unsigned long long v = ((unsigned long long)__float_as_uint(d) << 32) | (unsigned int)p;
        unsigned long long hi = b1 > v ? b1 : v;
        b1 = b1 < v ? b1 : v;
        b2 = b2 < hi ? b2 : hi;
    }

    __shared__ unsigned long long wb1[2][4], wb2[2][4];
    __shared__ int knn_sh[GRP_K];

    unsigned long long removed = 0ull;

    for (int r = 0; r < 16; ++r) {
        unsigned long long r1 = b1, r2 = b2;
#pragma unroll
        for (int m = 1; m < 64; m <<= 1) {
            unsigned long long o1 = __shfl_xor(r1, m, 64);
            unsigned long long o2 = __shfl_xor(r2, m, 64);
            merge2(r1, r2, o1, o2);
        }
        if (lane == 0) { wb1[r & 1][myw] = r1; wb2[r & 1][myw] = r2; }
        __syncthreads();
        unsigned long long g1 = wb1[r & 1][0], g2 = wb2[r & 1][0];
#pragma unroll
        for (int k = 1; k < 4; ++k) merge2(g1, g2, wb1[r & 1][k], wb2[r & 1][k]);

        int q1 = (int)(unsigned int)g1;
        int q2 = (int)(unsigned int)g2;
        if (tid == 0) { knn_sh[2 * r] = q1; knn_sh[2 * r + 1] = q2; }

        int wt1 = q1 & 255, wt2 = q2 & 255;
        if (tid == wt1) removed |= 1ull << (q1 >> 8);
        if (tid == wt2) removed |= 1ull << (q2 >> 8);

#pragma unroll 1
        for (int s = 0; s < 2; ++s) {
            if (s == 1 && wt2 == wt1) break;
            int wt = s ? wt2 : wt1;
            if ((wt >> 6) != myw) continue;
            unsigned long long rm = __shfl(removed, wt & 63, 64);
            int q = wt + (lane << 8);
            float dx = __fsub_rn(cx, xb[q]);
            float dy = __fsub_rn(cy, xb[N_PTS + q]);
            float dz = __fsub_rn(cz, xb[2 * N_PTS + q]);
            float d = __fadd_rn(__fadd_rn(__fmul_rn(dx, dx), __fmul_rn(dy, dy)),
                                __fmul_rn(dz, dz));
            unsigned long long v = ((unsigned long long)__float_as_uint(d) << 32) | (unsigned int)q;
            if ((rm >> lane) & 1ull) v = ~0ull;
            unsigned long long s1 = v, s2 = ~0ull;
#pragma unroll
            for (int m = 1; m < 64; m <<= 1) {
                unsigned long long o1 = __shfl_xor(s1, m, 64);
                unsigned long long o2 = __shfl_xor(s2, m, 64);
                merge2(s1, s2, o1, o2);
            }
            if (tid == wt) { b1 = s1; b2 = s2; }
        }
    }
    __syncthreads();

    if (tid < 192) {
        int k = tid / 6, c = tid % 6;
        int p = knn_sh[k];
        float val = xb[c * N_PTS + p];
        if (c == 0) val = __fsub_rn(val, cx);
        else if (c == 1) val = __fsub_rn(val, cy);
        else if (c == 2) val = __fsub_rn(val, cz);
        xout[(size_t)bg * 192 + tid] = val;
    }
}

// ---------------- Prep: LDS-tiled transpose fp32[K][N] -> bf16[N][K] ----------------
// 64x64 tiles; reads coalesced fp32, writes ushort8 (16B): 16 lanes = 128B contiguous.
__global__ __launch_bounds__(256) void prep_kernel(const float* __restrict__ w2,
                                                   const float* __restrict__ w3,
                                                   const float* __restrict__ w4,
                                                   unsigned short* __restrict__ w2t,
                                                   unsigned short* __restrict__ w3t,
                                                   unsigned short* __restrict__ w4t) {
    const int tile = blockIdx.x;
    const float* src;
    unsigned short* dst;
    int K, N, kt, nt;
    if (tile < 8) {            // w2: 128x256 -> 2x4 tiles
        src = w2; dst = w2t; K = 128; N = 256;
        kt = tile >> 2; nt = tile & 3;
    } else if (tile < 72) {    // w3: 512x512 -> 8x8 tiles
        int t2 = tile - 8;
        src = w3; dst = w3t; K = 512; N = 512;
        kt = t2 >> 3; nt = t2 & 7;
    } else {                   // w4: 512x384 -> 8x6 tiles
        int t2 = tile - 72;
        src = w4; dst = w4t; K = 512; N = 384;
        kt = t2 / 6; nt = t2 % 6;
    }
    const int k0 = kt * 64, n0 = nt * 64;

    __shared__ unsigned short tl[64][72];

    const int c = threadIdx.x & 63, r0 = threadIdx.x >> 6;
#pragma unroll
    for (int i = 0; i < 16; ++i) {
        int r = 4 * i + r0;
        tl[r][c] = f2bf(src[(size_t)(k0 + r) * N + n0 + c]);
    }
    __syncthreads();

    const int n = threadIdx.x >> 2;           // 0..63
    const int kc = (threadIdx.x & 3) * 16;    // 0,16,32,48
    u16x8 v0, v1;
#pragma unroll
    for (int j = 0; j < 8; ++j) {
        v0[j] = tl[kc + j][n];
        v1[j] = tl[kc + 8 + j][n];
    }
    *(u16x8*)(dst + (size_t)(n0 + n) * K + k0 + kc) = v0;
    *(u16x8*)(dst + (size_t)(n0 + n) * K + k0 + kc + 8) = v1;
}

// ---------------- Phase C: MFMA MLP with weight-stream software pipelining ----------------
__global__ __launch_bounds__(256, 2) void mlp_mfma_kernel(
    const float* __restrict__ xin,
    const float* __restrict__ w1, const float* __restrict__ b1,
    const float* __restrict__ g1, const float* __restrict__ be1,
    const float* __restrict__ m1, const float* __restrict__ v1,
    const unsigned short* __restrict__ w2t, const float* __restrict__ b2,
    const unsigned short* __restrict__ w3t, const float* __restrict__ b3,
    const float* __restrict__ g2, const float* __restrict__ be2,
    const float* __restrict__ m2, const float* __restrict__ v2,
    const unsigned short* __restrict__ w4t, const float* __restrict__ b4,
    float* __restrict__ out) {
    const int bg0 = blockIdx.x * 2;
    const int t = threadIdx.x;
    const int w = t >> 6;
    const int lane = t & 63;
    const int lr = lane & 15;
    const int lq = lane >> 4;

    __shared__ __align__(16) unsigned short f1s[64 * 136];
    __shared__ __align__(16) unsigned short f2s[64 * 264];
    __shared__ __align__(16) unsigned short fgs[2 * 256];
    __shared__ float xs[2 * 32 * 6];

    for (int i = t; i < 384; i += 256) xs[i] = xin[(size_t)bg0 * 192 + i];
    __syncthreads();

    // ---- L1: 6->128, bn1, relu ----
    {
        const int d = t & 127, mh = t >> 7;
        float wv[6];
#pragma unroll
        for (int c = 0; c < 6; ++c) wv[c] = w1[c * 128 + d];
        const float sc = g1[d] * rsqrtf(v1[d] + EPSF);
        const float sh = be1[d] - m1[d] * sc;
        const float bias = b1[d];
#pragma unroll
        for (int j = 0; j < 32; ++j) {
            float s = bias;
#pragma unroll
            for (int c = 0; c < 6; ++c) s += xs[mh * 192 + j * 6 + c] * wv[c];
            f1s[(mh * 32 + j) * 136 + d] = f2bf(fmaxf(s * sc + sh, 0.0f));
        }
    }
    __syncthreads();

    // ---- L2: [64x128] @ w2[128x256] -> f2s ----
    {
        const int n0 = w * 64;
        f32x4 acc[4][4];
#pragma unroll
        for (int nti = 0; nti < 4; ++nti) {
            f32x4 bq = *(const f32x4*)(b2 + n0 + nti * 16 + lq * 4);
#pragma unroll
            for (int mt = 0; mt < 4; ++mt) acc[mt][nti] = bq;
        }
#pragma unroll
        for (int ks = 0; ks < 4; ++ks) {
            bf16x8 xf[4], wf[4];
#pragma unroll
            for (int mt = 0; mt < 4; ++mt)
                xf[mt] = *(const bf16x8*)(f1s + (mt * 16 + lr) * 136 + ks * 32 + lq * 8);
#pragma unroll
            for (int nti = 0; nti < 4; ++nti)
                wf[nti] = *(const bf16x8*)(w2t + (n0 + nti * 16 + lr) * 128 + ks * 32 + lq * 8);
#pragma unroll
            for (int mt = 0; mt < 4; ++mt)
#pragma unroll
                for (int nti = 0; nti < 4; ++nti)
                    acc[mt][nti] = __builtin_amdgcn_mfma_f32_16x16x32_bf16(wf[nti], xf[mt], acc[mt][nti], 0, 0, 0);
        }
#pragma unroll
        for (int mt = 0; mt < 4; ++mt)
#pragma unroll
            for (int nti = 0; nti < 4; ++nti) {
                bf16x4 p;
#pragma unroll
                for (int r = 0; r < 4; ++r) p[r] = (short)f2bf(acc[mt][nti][r]);
                *(bf16x4*)(f2s + (mt * 16 + lr) * 264 + n0 + nti * 16 + lq * 4) = p;
            }
    }
    __syncthreads();

    // ---- fg = column max per group ----
    for (int idx = t; idx < 512; idx += 256) {
        int g = idx >> 8, n = idx & 255;
        float m = -3.9e38f;
#pragma unroll
        for (int k = 0; k < 32; ++k) m = fmaxf(m, bf2f(f2s[(g * 32 + k) * 264 + n]));
        fgs[g * 256 + n] = f2bf(m);
    }
    __syncthreads();

    // ---- L3 (K=512) chunked x4, fused with L4 partials; ping-pong weight prefetch ----
    auto ldw3f = [&](int cb_, int ks_, int nti_) -> bf16x8 {
        return *(const bf16x8*)(w3t + (size_t)(cb_ * 128 + w * 32 + nti_ * 16 + lr) * 512 + ks_ * 32 + lq * 8);
    };
    auto ldw4f = [&](int cb_, int kl_, int nti_) -> bf16x8 {
        return *(const bf16x8*)(w4t + (size_t)(w * 96 + nti_ * 16 + lr) * 512 + cb_ * 128 + kl_ * 32 + lq * 8);
    };
    auto ldxf3 = [&](int ks_, bf16x8* xf) {
        if (ks_ < 8) {
            bf16x8 x0 = *(const bf16x8*)(fgs + ks_ * 32 + lq * 8);
            bf16x8 x1 = *(const bf16x8*)(fgs + 256 + ks_ * 32 + lq * 8);
            xf[0] = x0; xf[1] = x0; xf[2] = x1; xf[3] = x1;
        } else {
#pragma unroll
            for (int mt = 0; mt < 4; ++mt)
                xf[mt] = *(const bf16x8*)(f2s + (mt * 16 + lr) * 264 + (ks_ - 8) * 32 + lq * 8);
        }
    };

    f32x4 acc4[6][4];
#pragma unroll
    for (int nti = 0; nti < 6; ++nti) {
        f32x4 bq = *(const f32x4*)(b4 + w * 96 + nti * 16 + lq * 4);
#pragma unroll
        for (int mt = 0; mt < 4; ++mt) acc4[nti][mt] = bq;
    }

    bf16x8 wa0 = ldw3f(0, 0, 0), wa1 = ldw3f(0, 0, 1);

    for (int cb = 0; cb < 4; ++cb) {
        f32x4 acc3[2][4];
#pragma unroll
        for (int nti = 0; nti < 2; ++nti) {
            f32x4 bq = *(const f32x4*)(b3 + cb * 128 + w * 32 + nti * 16 + lq * 4);
#pragma unroll
            for (int mt = 0; mt < 4; ++mt) acc3[nti][mt] = bq;
        }
        for (int ks = 0; ks < 16; ks += 2) {
            bf16x8 wb0 = ldw3f(cb, ks + 1, 0), wb1 = ldw3f(cb, ks + 1, 1);
            bf16x8 xf[4];
            ldxf3(ks, xf);
#pragma unroll
            for (int mt = 0; mt < 4; ++mt) {
                acc3[0][mt] = __builtin_amdgcn_mfma_f32_16x16x32_bf16(wa0, xf[mt], acc3[0][mt], 0, 0, 0);
                acc3[1][mt] = __builtin_amdgcn_mfma_f32_16x16x32_bf16(wa1, xf[mt], acc3[1][mt], 0, 0, 0);
            }
            if (ks + 2 < 16) { wa0 = ldw3f(cb, ks + 2, 0); wa1 = ldw3f(cb, ks + 2, 1); }
            ldxf3(ks + 1, xf);
#pragma unroll
            for (int mt = 0; mt < 4; ++mt) {
                acc3[0][mt] = __builtin_amdgcn_mfma_f32_16x16x32_bf16(wb0, xf[mt], acc3[0][mt], 0, 0, 0);
                acc3[1][mt] = __builtin_amdgcn_mfma_f32_16x16x32_bf16(wb1, xf[mt], acc3[1][mt], 0, 0, 0);
            }
        }
        // bn2 + relu -> f3 chunk (reuse f1s)
#pragma unroll
        for (int nti = 0; nti < 2; ++nti) {
            const int nq = cb * 128 + w * 32 + nti * 16 + lq * 4;
            f32x4 g2q = *(const f32x4*)(g2 + nq);
            f32x4 v2q = *(const f32x4*)(v2 + nq);
            f32x4 m2q = *(const f32x4*)(m2 + nq);
            f32x4 beq = *(const f32x4*)(be2 + nq);
            f32x4 sc, sh;
#pragma unroll
            for (int r = 0; r < 4; ++r) {
                sc[r] = g2q[r] * rsqrtf(v2q[r] + EPSF);
                sh[r] = beq[r] - m2q[r] * sc[r];
            }
#pragma unroll
            for (int mt = 0; mt < 4; ++mt) {
                bf16x4 p;
#pragma unroll
                for (int r = 0; r < 4; ++r)
                    p[r] = (short)f2bf(fmaxf(acc3[nti][mt][r] * sc[r] + sh[r], 0.0f));
                *(bf16x4*)(f1s + (mt * 16 + lr) * 136 + w * 32 + nti * 16 + lq * 4) = p;
            }
        }
        // hoist L4 kl=0 weight loads above the barrier (global, LDS-independent)
        bf16x8 w4a[6];
#pragma unroll
        for (int nti = 0; nti < 6; ++nti) w4a[nti] = ldw4f(cb, 0, nti);
        __syncthreads();
        for (int kl = 0; kl < 4; kl += 2) {
            bf16x8 w4b[6];
#pragma unroll
            for (int nti = 0; nti < 6; ++nti) w4b[nti] = ldw4f(cb, kl + 1, nti);
            bf16x8 xf[4];
#pragma unroll
            for (int mt = 0; mt < 4; ++mt)
                xf[mt] = *(const bf16x8*)(f1s + (mt * 16 + lr) * 136 + kl * 32 + lq * 8);
#pragma unroll
            for (int nti = 0; nti < 6; ++nti)
#pragma unroll
                for (int mt = 0; mt < 4; ++mt)
                    acc4[nti][mt] = __builtin_amdgcn_mfma_f32_16x16x32_bf16(w4a[nti], xf[mt], acc4[nti][mt], 0, 0, 0);
            if (kl + 2 < 4) {
#pragma unroll
                for (int nti = 0; nti < 6; ++nti) w4a[nti] = ldw4f(cb, kl + 2, nti);
            }
#pragma unroll
            for (int mt = 0; mt < 4; ++mt)
                xf[mt] = *(const bf16x8*)(f1s + (mt * 16 + lr) * 136 + (kl + 1) * 32 + lq * 8);
#pragma unroll
            for (int nti = 0; nti < 6; ++nti)
#pragma unroll
                for (int mt = 0; mt < 4; ++mt)
                    acc4[nti][mt] = __builtin_amdgcn_mfma_f32_16x16x32_bf16(w4b[nti], xf[mt], acc4[nti][mt], 0, 0, 0);
        }
        if (cb < 3) {
            // hoist next L3 chunk's first weights above the barrier
            wa0 = ldw3f(cb + 1, 0, 0); wa1 = ldw3f(cb + 1, 0, 1);
            __syncthreads();
        }
    }

    // ---- max over 32 points per group, write out ----
#pragma unroll
    for (int nti = 0; nti < 6; ++nti) {
#pragma unroll
        for (int g = 0; g < 2; ++g) {
            f32x4 vv;
#pragma unroll
            for (int r = 0; r < 4; ++r)
                vv[r] = fmaxf(acc4[nti][2 * g][r], acc4[nti][2 * g + 1][r]);
#pragma unroll
            for (int mask = 1; mask <= 8; mask <<= 1) {
#pragma unroll
                for (int r = 0; r < 4; ++r)
                    vv[r] = fmaxf(vv[r], __shfl_xor(vv[r], mask, 64));
            }
            if (lr == 0)
                *(f32x4*)(out + (size_t)(bg0 + g) * 384 + w * 96 + nti * 16 + lq * 4) = vv;
        }
    }
}

extern "C" void kernel_launch(void* const* d_in, const int* in_sizes, int n_in,
                              void* d_out, int out_size, void* d_ws, size_t ws_size,
                              hipStream_t stream) {
    const float* pcd = (const float*)d_in[0];
    const float* w1 = (const float*)d_in[2];
    const float* b1 = (const float*)d_in[3];
    const float* g1 = (const float*)d_in[4];
    const float* be1 = (const float*)d_in[5];
    const float* m1 = (const float*)d_in[6];
    const float* v1 = (const float*)d_in[7];
    const float* w2 = (const float*)d_in[8];
    const float* b2 = (const float*)d_in[9];
    const float* w3 = (const float*)d_in[10];
    const float* b3 = (const float*)d_in[11];
    const float* g2 = (const float*)d_in[12];
    const float* be2 = (const float*)d_in[13];
    const float* m2 = (const float*)d_in[14];
    const float* v2 = (const float*)d_in[15];
    const float* w4 = (const float*)d_in[16];
    const float* b4 = (const float*)d_in[17];
    float* out = (float*)d_out;

    char* ws = (char*)d_ws;
    int* cidx = (int*)ws;                                   // 8192 B
    float* xg = (float*)(ws + 8192);                        // 1,572,864 B
    unsigned short* w2t = (unsigned short*)(ws + 1581056);  // 65,536 B
    unsigned short* w3t = (unsigned short*)(ws + 1646592);  // 524,288 B
    unsigned short* w4t = (unsigned short*)(ws + 2170880);  // 393,216 B

    prep_kernel<<<120, 256, 0, stream>>>(w2, w3, w4, w2t, w3t, w4t);
    fps_kernel<<<32, 1024, 0, stream>>>(pcd, cidx);
    knn_kernel<<<2048, 256, 0, stream>>>(pcd, cidx, xg);
    mlp_mfma_kernel<<<1024, 256, 0, stream>>>(xg, w1, b1, g1, be1, m1, v1,
                                              w2t, b2, w3t, b3, g2, be2, m2, v2,
                                              w4t, b4, out);
}

// Round 5
// 508.761 us; speedup vs baseline: 3.2968x; 1.0717x over previous
//
#include <hip/hip_runtime.h>
#include <hip/hip_bf16.h>
#include <math.h>

#define N_PTS 16384
#define NUM_G 64
#define GRP_K 32
#define EPSF 1e-5f

typedef short bf16x8 __attribute__((ext_vector_type(8)));
typedef short bf16x4 __attribute__((ext_vector_type(4)));
typedef float f32x4 __attribute__((ext_vector_type(4)));
typedef unsigned short u16x8 __attribute__((ext_vector_type(8)));

__device__ __forceinline__ unsigned short f2bf(float x) {
    unsigned int u = __builtin_bit_cast(unsigned int, x);
    u = (u + 0x7FFFu + ((u >> 16) & 1u)) >> 16;
    return (unsigned short)u;
}
__device__ __forceinline__ float bf2f(unsigned short h) {
    unsigned int u = ((unsigned int)h) << 16;
    return __builtin_bit_cast(float, u);
}

// ---------------- Phase A: farthest point sampling ----------------
// 1 block/batch, 1024 thr x 16 pts IN REGISTERS (launch_bounds(,4) -> 128 VGPR cap,
// no scratch spill; prior rounds spilled at 60 VGPR). One barrier/iter.
// Key u64 = (dist_bits<<32) | ~p : max key => max dist, tie => min index (numpy argmax).
__global__ __launch_bounds__(1024, 4) void fps_kernel(const float* __restrict__ pcd,
                                                      int* __restrict__ cidx) {
    const int b = blockIdx.x;
    const int tid = threadIdx.x;
    const int lane = tid & 63, w = tid >> 6;
    const float* xb = pcd + (size_t)b * 6 * N_PTS;

    float px[16], py[16], pz[16], dist[16];
#pragma unroll
    for (int j = 0; j < 16; ++j) {
        int p = tid + 1024 * j;
        px[j] = xb[p];
        py[j] = xb[N_PTS + p];
        pz[j] = xb[2 * N_PTS + p];
        dist[j] = 1e10f;
    }

    __shared__ unsigned long long wk[2][16];
    __shared__ int clds[NUM_G];

    int far = 0;
    for (int it = 0; it < NUM_G; ++it) {
        int fu = __builtin_amdgcn_readfirstlane(far);  // scalar center load path
        float cx = xb[fu], cy = xb[N_PTS + fu], cz = xb[2 * N_PTS + fu];
        if (tid == 0) clds[it] = fu;

        unsigned long long kmax = 0ull;
#pragma unroll
        for (int j = 0; j < 16; ++j) {
            float dx = __fsub_rn(px[j], cx);
            float dy = __fsub_rn(py[j], cy);
            float dz = __fsub_rn(pz[j], cz);
            float d = __fadd_rn(__fadd_rn(__fmul_rn(dx, dx), __fmul_rn(dy, dy)),
                                __fmul_rn(dz, dz));
            dist[j] = fminf(dist[j], d);
            unsigned long long key =
                ((unsigned long long)__float_as_uint(dist[j]) << 32) |
                (unsigned int)~(tid + 1024 * j);
            kmax = kmax > key ? kmax : key;
        }
        // butterfly wave reduce (u64 max, assoc+comm => exact)
#pragma unroll
        for (int m = 1; m < 64; m <<= 1) {
            unsigned long long o = __shfl_xor(kmax, m, 64);
            kmax = o > kmax ? o : kmax;
        }
        if (lane == 0) wk[it & 1][w] = kmax;
        __syncthreads();
        unsigned long long g = wk[it & 1][0];
#pragma unroll
        for (int k = 1; k < 16; ++k) {
            unsigned long long o = wk[it & 1][k];
            g = o > g ? o : g;
        }
        far = (int)(~(unsigned int)g);  // identical in every thread
    }
    __syncthreads();
    if (tid < NUM_G) cidx[b * NUM_G + tid] = clds[tid];
}

// ---------------- Phase B: KNN via per-thread top-2 + 16 dual-extraction rounds ----------------
// Thread t owns 64 CONSECUTIVE points [64t, 64t+64): float4 loads (48 VMEM/thread vs 192).
// Key u64 = (d2bits<<32)|idx: u64 order == (d2, idx) lexicographic (set exact vs top_k).
__device__ __forceinline__ void merge2(unsigned long long& a1, unsigned long long& a2,
                                       unsigned long long o1, unsigned long long o2) {
    unsigned long long hi = a1 > o1 ? a1 : o1;
    a1 = a1 < o1 ? a1 : o1;
    unsigned long long lo2 = a2 < o2 ? a2 : o2;
    a2 = hi < lo2 ? hi : lo2;
}

__global__ __launch_bounds__(256, 4) void knn_kernel(const float* __restrict__ pcd,
                                                     const int* __restrict__ cidx,
                                                     float* __restrict__ xout) {
    const int bg = blockIdx.x;
    const int b = bg >> 6;
    const int tid = threadIdx.x;
    const int lane = tid & 63, myw = tid >> 6;
    const float* xb = pcd + (size_t)b * 6 * N_PTS;

    const int ci = cidx[bg];
    const float cx = xb[ci], cy = xb[N_PTS + ci], cz = xb[2 * N_PTS + ci];

    const float4* x4 = (const float4*)(xb) + tid * 16;
    const float4* y4 = (const float4*)(xb + N_PTS) + tid * 16;
    const float4* z4 = (const float4*)(xb + 2 * N_PTS) + tid * 16;
    const unsigned int p0 = (unsigned int)tid << 6;

    unsigned long long b1 = ~0ull, b2 = ~0ull;
#pragma unroll
    for (int jj = 0; jj < 16; ++jj) {
        float4 xv = x4[jj], yv = y4[jj], zv = z4[jj];
        float xs4[4] = {xv.x, xv.y, xv.z, xv.w};
        float ys4[4] = {yv.x, yv.y, yv.z, yv.w};
        float zs4[4] = {zv.x, zv.y, zv.z, zv.w};
#pragma unroll
        for (int u = 0; u < 4; ++u) {
            float dx = __fsub_rn(cx, xs4[u]);
            float dy = __fsub_rn(cy, ys4[u]);
            float dz = __fsub_rn(cz, zs4[u]);
            float d = __fadd_rn(__fadd_rn(__fmul_rn(dx, dx), __fmul_rn(dy, dy)),
                                __fmul_rn(dz, dz));
            unsigned long long v =
                ((unsigned long long)__float_as_uint(d) << 32) | (p0 + jj * 4 + u);
            unsigned long long hi = b1 > v ? b1 : v;
            b1 = b1 < v ? b1 : v;
            b2 = b2 < hi ? b2 : hi;
        }
    }

    __shared__ unsigned long long wb1[2][4], wb2[2][4];
    __shared__ int knn_sh[GRP_K];

    unsigned long long removed = 0ull;

    for (int r = 0; r < 16; ++r) {
        unsigned long long r1 = b1, r2 = b2;
#pragma unroll
        for (int m = 1; m < 64; m <<= 1) {
            unsigned long long o1 = __shfl_xor(r1, m, 64);
            unsigned long long o2 = __shfl_xor(r2, m, 64);
            merge2(r1, r2, o1, o2);
        }
        if (lane == 0) { wb1[r & 1][myw] = r1; wb2[r & 1][myw] = r2; }
        __syncthreads();
        unsigned long long g1 = wb1[r & 1][0], g2 = wb2[r & 1][0];
#pragma unroll
        for (int k = 1; k < 4; ++k) merge2(g1, g2, wb1[r & 1][k], wb2[r & 1][k]);

        int q1 = (int)(unsigned int)g1;
        int q2 = (int)(unsigned int)g2;
        if (tid == 0) { knn_sh[2 * r] = q1; knn_sh[2 * r + 1] = q2; }

        int wt1 = q1 >> 6, wt2 = q2 >> 6;  // owner thread
        if (tid == wt1) removed |= 1ull << (q1 & 63);
        if (tid == wt2) removed |= 1ull << (q2 & 63);

#pragma unroll 1
        for (int s = 0; s < 2; ++s) {
            if (s == 1 && wt2 == wt1) break;       // block-uniform
            int wt = s ? wt2 : wt1;
            if ((wt >> 6) != myw) continue;        // wave-uniform
            unsigned long long rm = __shfl(removed, wt & 63, 64);
            int q = (wt << 6) + lane;              // coalesced rescan
            float dx = __fsub_rn(cx, xb[q]);
            float dy = __fsub_rn(cy, xb[N_PTS + q]);
            float dz = __fsub_rn(cz, xb[2 * N_PTS + q]);
            float d = __fadd_rn(__fadd_rn(__fmul_rn(dx, dx), __fmul_rn(dy, dy)),
                                __fmul_rn(dz, dz));
            unsigned long long v =
                ((unsigned long long)__float_as_uint(d) << 32) | (unsigned int)q;
            if ((rm >> lane) & 1ull) v = ~0ull;
            unsigned long long s1 = v, s2 = ~0ull;
#pragma unroll
            for (int m = 1; m < 64; m <<= 1) {
                unsigned long long o1 = __shfl_xor(s1, m, 64);
                unsigned long long o2 = __shfl_xor(s2, m, 64);
                merge2(s1, s2, o1, o2);
            }
            if (tid == wt) { b1 = s1; b2 = s2; }
        }
    }
    __syncthreads();

    if (tid < 192) {
        int k = tid / 6, c = tid % 6;
        int p = knn_sh[k];
        float val = xb[c * N_PTS + p];
        if (c == 0) val = __fsub_rn(val, cx);
        else if (c == 1) val = __fsub_rn(val, cy);
        else if (c == 2) val = __fsub_rn(val, cz);
        xout[(size_t)bg * 192 + tid] = val;
    }
}

// ---------------- Prep: LDS-tiled transpose fp32[K][N] -> bf16[N][K] ----------------
__global__ __launch_bounds__(256) void prep_kernel(const float* __restrict__ w2,
                                                   const float* __restrict__ w3,
                                                   const float* __restrict__ w4,
                                                   unsigned short* __restrict__ w2t,
                                                   unsigned short* __restrict__ w3t,
                                                   unsigned short* __restrict__ w4t) {
    const int tile = blockIdx.x;
    const float* src;
    unsigned short* dst;
    int K, N, kt, nt;
    if (tile < 8) {            // w2: 128x256 -> 2x4 tiles
        src = w2; dst = w2t; K = 128; N = 256;
        kt = tile >> 2; nt = tile & 3;
    } else if (tile < 72) {    // w3: 512x512 -> 8x8 tiles
        int t2 = tile - 8;
        src = w3; dst = w3t; K = 512; N = 512;
        kt = t2 >> 3; nt = t2 & 7;
    } else {                   // w4: 512x384 -> 8x6 tiles
        int t2 = tile - 72;
        src = w4; dst = w4t; K = 512; N = 384;
        kt = t2 / 6; nt = t2 % 6;
    }
    const int k0 = kt * 64, n0 = nt * 64;

    __shared__ unsigned short tl[64][72];

    const int c = threadIdx.x & 63, r0 = threadIdx.x >> 6;
#pragma unroll
    for (int i = 0; i < 16; ++i) {
        int r = 4 * i + r0;
        tl[r][c] = f2bf(src[(size_t)(k0 + r) * N + n0 + c]);
    }
    __syncthreads();

    const int n = threadIdx.x >> 2;
    const int kc = (threadIdx.x & 3) * 16;
    u16x8 v0, v1;
#pragma unroll
    for (int j = 0; j < 8; ++j) {
        v0[j] = tl[kc + j][n];
        v1[j] = tl[kc + 8 + j][n];
    }
    *(u16x8*)(dst + (size_t)(n0 + n) * K + k0 + kc) = v0;
    *(u16x8*)(dst + (size_t)(n0 + n) * K + k0 + kc + 8) = v1;
}

// ---------------- Phase C: MFMA MLP with weight-stream software pipelining ----------------
__global__ __launch_bounds__(256, 2) void mlp_mfma_kernel(
    const float* __restrict__ xin,
    const float* __restrict__ w1, const float* __restrict__ b1,
    const float* __restrict__ g1, const float* __restrict__ be1,
    const float* __restrict__ m1, const float* __restrict__ v1,
    const unsigned short* __restrict__ w2t, const float* __restrict__ b2,
    const unsigned short* __restrict__ w3t, const float* __restrict__ b3,
    const float* __restrict__ g2, const float* __restrict__ be2,
    const float* __restrict__ m2, const float* __restrict__ v2,
    const unsigned short* __restrict__ w4t, const float* __restrict__ b4,
    float* __restrict__ out) {
    const int bg0 = blockIdx.x * 2;
    const int t = threadIdx.x;
    const int w = t >> 6;
    const int lane = t & 63;
    const int lr = lane & 15;
    const int lq = lane >> 4;

    __shared__ __align__(16) unsigned short f1s[64 * 136];
    __shared__ __align__(16) unsigned short f2s[64 * 264];
    __shared__ __align__(16) unsigned short fgs[2 * 256];
    __shared__ float xs[2 * 32 * 6];

    for (int i = t; i < 384; i += 256) xs[i] = xin[(size_t)bg0 * 192 + i];
    __syncthreads();

    // ---- L1: 6->128, bn1, relu ----
    {
        const int d = t & 127, mh = t >> 7;
        float wv[6];
#pragma unroll
        for (int c = 0; c < 6; ++c) wv[c] = w1[c * 128 + d];
        const float sc = g1[d] * rsqrtf(v1[d] + EPSF);
        const float sh = be1[d] - m1[d] * sc;
        const float bias = b1[d];
#pragma unroll
        for (int j = 0; j < 32; ++j) {
            float s = bias;
#pragma unroll
            for (int c = 0; c < 6; ++c) s += xs[mh * 192 + j * 6 + c] * wv[c];
            f1s[(mh * 32 + j) * 136 + d] = f2bf(fmaxf(s * sc + sh, 0.0f));
        }
    }
    __syncthreads();

    // ---- L2: [64x128] @ w2[128x256] -> f2s ----
    {
        const int n0 = w * 64;
        f32x4 acc[4][4];
#pragma unroll
        for (int nti = 0; nti < 4; ++nti) {
            f32x4 bq = *(const f32x4*)(b2 + n0 + nti * 16 + lq * 4);
#pragma unroll
            for (int mt = 0; mt < 4; ++mt) acc[mt][nti] = bq;
        }
#pragma unroll
        for (int ks = 0; ks < 4; ++ks) {
            bf16x8 xf[4], wf[4];
#pragma unroll
            for (int mt = 0; mt < 4; ++mt)
                xf[mt] = *(const bf16x8*)(f1s + (mt * 16 + lr) * 136 + ks * 32 + lq * 8);
#pragma unroll
            for (int nti = 0; nti < 4; ++nti)
                wf[nti] = *(const bf16x8*)(w2t + (n0 + nti * 16 + lr) * 128 + ks * 32 + lq * 8);
#pragma unroll
            for (int mt = 0; mt < 4; ++mt)
#pragma unroll
                for (int nti = 0; nti < 4; ++nti)
                    acc[mt][nti] = __builtin_amdgcn_mfma_f32_16x16x32_bf16(wf[nti], xf[mt], acc[mt][nti], 0, 0, 0);
        }
#pragma unroll
        for (int mt = 0; mt < 4; ++mt)
#pragma unroll
            for (int nti = 0; nti < 4; ++nti) {
                bf16x4 p;
#pragma unroll
                for (int r = 0; r < 4; ++r) p[r] = (short)f2bf(acc[mt][nti][r]);
                *(bf16x4*)(f2s + (mt * 16 + lr) * 264 + n0 + nti * 16 + lq * 4) = p;
            }
    }
    __syncthreads();

    // ---- fg = column max per group ----
    for (int idx = t; idx < 512; idx += 256) {
        int g = idx >> 8, n = idx & 255;
        float m = -3.9e38f;
#pragma unroll
        for (int k = 0; k < 32; ++k) m = fmaxf(m, bf2f(f2s[(g * 32 + k) * 264 + n]));
        fgs[g * 256 + n] = f2bf(m);
    }
    __syncthreads();

    auto ldw3f = [&](int cb_, int ks_, int nti_) -> bf16x8 {
        return *(const bf16x8*)(w3t + (size_t)(cb_ * 128 + w * 32 + nti_ * 16 + lr) * 512 + ks_ * 32 + lq * 8);
    };
    auto ldw4f = [&](int cb_, int kl_, int nti_) -> bf16x8 {
        return *(const bf16x8*)(w4t + (size_t)(w * 96 + nti_ * 16 + lr) * 512 + cb_ * 128 + kl_ * 32 + lq * 8);
    };
    auto ldxf3 = [&](int ks_, bf16x8* xf) {
        if (ks_ < 8) {
            bf16x8 x0 = *(const bf16x8*)(fgs + ks_ * 32 + lq * 8);
            bf16x8 x1 = *(const bf16x8*)(fgs + 256 + ks_ * 32 + lq * 8);
            xf[0] = x0; xf[1] = x0; xf[2] = x1; xf[3] = x1;
        } else {
#pragma unroll
            for (int mt = 0; mt < 4; ++mt)
                xf[mt] = *(const bf16x8*)(f2s + (mt * 16 + lr) * 264 + (ks_ - 8) * 32 + lq * 8);
        }
    };

    f32x4 acc4[6][4];
#pragma unroll
    for (int nti = 0; nti < 6; ++nti) {
        f32x4 bq = *(const f32x4*)(b4 + w * 96 + nti * 16 + lq * 4);
#pragma unroll
        for (int mt = 0; mt < 4; ++mt) acc4[nti][mt] = bq;
    }

    bf16x8 wa0 = ldw3f(0, 0, 0), wa1 = ldw3f(0, 0, 1);

    for (int cb = 0; cb < 4; ++cb) {
        f32x4 acc3[2][4];
#pragma unroll
        for (int nti = 0; nti < 2; ++nti) {
            f32x4 bq = *(const f32x4*)(b3 + cb * 128 + w * 32 + nti * 16 + lq * 4);
#pragma unroll
            for (int mt = 0; mt < 4; ++mt) acc3[nti][mt] = bq;
        }
        for (int ks = 0; ks < 16; ks += 2) {
            bf16x8 wb0 = ldw3f(cb, ks + 1, 0), wb1 = ldw3f(cb, ks + 1, 1);
            bf16x8 xf[4];
            ldxf3(ks, xf);
#pragma unroll
            for (int mt = 0; mt < 4; ++mt) {
                acc3[0][mt] = __builtin_amdgcn_mfma_f32_16x16x32_bf16(wa0, xf[mt], acc3[0][mt], 0, 0, 0);
                acc3[1][mt] = __builtin_amdgcn_mfma_f32_16x16x32_bf16(wa1, xf[mt], acc3[1][mt], 0, 0, 0);
            }
            if (ks + 2 < 16) { wa0 = ldw3f(cb, ks + 2, 0); wa1 = ldw3f(cb, ks + 2, 1); }
            ldxf3(ks + 1, xf);
#pragma unroll
            for (int mt = 0; mt < 4; ++mt) {
                acc3[0][mt] = __builtin_amdgcn_mfma_f32_16x16x32_bf16(wb0, xf[mt], acc3[0][mt], 0, 0, 0);
                acc3[1][mt] = __builtin_amdgcn_mfma_f32_16x16x32_bf16(wb1, xf[mt], acc3[1][mt], 0, 0, 0);
            }
        }
#pragma unroll
        for (int nti = 0; nti < 2; ++nti) {
            const int nq = cb * 128 + w * 32 + nti * 16 + lq * 4;
            f32x4 g2q = *(const f32x4*)(g2 + nq);
            f32x4 v2q = *(const f32x4*)(v2 + nq);
            f32x4 m2q = *(const f32x4*)(m2 + nq);
            f32x4 beq = *(const f32x4*)(be2 + nq);
            f32x4 sc, sh;
#pragma unroll
            for (int r = 0; r < 4; ++r) {
                sc[r] = g2q[r] * rsqrtf(v2q[r] + EPSF);
                sh[r] = beq[r] - m2q[r] * sc[r];
            }
#pragma unroll
            for (int mt = 0; mt < 4; ++mt) {
                bf16x4 p;
#pragma unroll
                for (int r = 0; r < 4; ++r)
                    p[r] = (short)f2bf(fmaxf(acc3[nti][mt][r] * sc[r] + sh[r], 0.0f));
                *(bf16x4*)(f1s + (mt * 16 + lr) * 136 + w * 32 + nti * 16 + lq * 4) = p;
            }
        }
        bf16x8 w4a[6];
#pragma unroll
        for (int nti = 0; nti < 6; ++nti) w4a[nti] = ldw4f(cb, 0, nti);
        __syncthreads();
        for (int kl = 0; kl < 4; kl += 2) {
            bf16x8 w4b[6];
#pragma unroll
            for (int nti = 0; nti < 6; ++nti) w4b[nti] = ldw4f(cb, kl + 1, nti);
            bf16x8 xf[4];
#pragma unroll
            for (int mt = 0; mt < 4; ++mt)
                xf[mt] = *(const bf16x8*)(f1s + (mt * 16 + lr) * 136 + kl * 32 + lq * 8);
#pragma unroll
            for (int nti = 0; nti < 6; ++nti)
#pragma unroll
                for (int mt = 0; mt < 4; ++mt)
                    acc4[nti][mt] = __builtin_amdgcn_mfma_f32_16x16x32_bf16(w4a[nti], xf[mt], acc4[nti][mt], 0, 0, 0);
            if (kl + 2 < 4) {
#pragma unroll
                for (int nti = 0; nti < 6; ++nti) w4a[nti] = ldw4f(cb, kl + 2, nti);
            }
#pragma unroll
            for (int mt = 0; mt < 4; ++mt)
                xf[mt] = *(const bf16x8*)(f1s + (mt * 16 + lr) * 136 + (kl + 1) * 32 + lq * 8);
#pragma unroll
            for (int nti = 0; nti < 6; ++nti)
#pragma unroll
                for (int mt = 0; mt < 4; ++mt)
                    acc4[nti][mt] = __builtin_amdgcn_mfma_f32_16x16x32_bf16(w4b[nti], xf[mt], acc4[nti][mt], 0, 0, 0);
        }
        if (cb < 3) {
            wa0 = ldw3f(cb + 1, 0, 0); wa1 = ldw3f(cb + 1, 0, 1);
            __syncthreads();
        }
    }

#pragma unroll
    for (int nti = 0; nti < 6; ++nti) {
#pragma unroll
        for (int g = 0; g < 2; ++g) {
            f32x4 vv;
#pragma unroll
            for (int r = 0; r < 4; ++r)
                vv[r] = fmaxf(acc4[nti][2 * g][r], acc4[nti][2 * g + 1][r]);
#pragma unroll
            for (int mask = 1; mask <= 8; mask <<= 1) {
#pragma unroll
                for (int r = 0; r < 4; ++r)
                    vv[r] = fmaxf(vv[r], __shfl_xor(vv[r], mask, 64));
            }
            if (lr == 0)
                *(f32x4*)(out + (size_t)(bg0 + g) * 384 + w * 96 + nti * 16 + lq * 4) = vv;
        }
    }
}

extern "C" void kernel_launch(void* const* d_in, const int* in_sizes, int n_in,
                              void* d_out, int out_size, void* d_ws, size_t ws_size,
                              hipStream_t stream) {
    const float* pcd = (const float*)d_in[0];
    const float* w1 = (const float*)d_in[2];
    const float* b1 = (const float*)d_in[3];
    const float* g1 = (const float*)d_in[4];
    const float* be1 = (const float*)d_in[5];
    const float* m1 = (const float*)d_in[6];
    const float* v1 = (const float*)d_in[7];
    const float* w2 = (const float*)d_in[8];
    const float* b2 = (const float*)d_in[9];
    const float* w3 = (const float*)d_in[10];
    const float* b3 = (const float*)d_in[11];
    const float* g2 = (const float*)d_in[12];
    const float* be2 = (const float*)d_in[13];
    const float* m2 = (const float*)d_in[14];
    const float* v2 = (const float*)d_in[15];
    const float* w4 = (const float*)d_in[16];
    const float* b4 = (const float*)d_in[17];
    float* out = (float*)d_out;

    char* ws = (char*)d_ws;
    int* cidx = (int*)ws;                                   // 8192 B
    float* xg = (float*)(ws + 8192);                        // 1,572,864 B
    unsigned short* w2t = (unsigned short*)(ws + 1581056);  // 65,536 B
    unsigned short* w3t = (unsigned short*)(ws + 1646592);  // 524,288 B
    unsigned short* w4t = (unsigned short*)(ws + 2170880);  // 393,216 B

    prep_kernel<<<120, 256, 0, stream>>>(w2, w3, w4, w2t, w3t, w4t);
    fps_kernel<<<32, 1024, 0, stream>>>(pcd, cidx);
    knn_kernel<<<2048, 256, 0, stream>>>(pcd, cidx, xg);
    mlp_mfma_kernel<<<1024, 256, 0, stream>>>(xg, w1, b1, g1, be1, m1, v1,
                                              w2t, b2, w3t, b3, g2, be2, m2, v2,
                                              w4t, b4, out);
}

// Round 6
// 457.321 us; speedup vs baseline: 3.6676x; 1.1125x over previous
//
#include <hip/hip_runtime.h>
#include <hip/hip_bf16.h>
#include <math.h>

#define N_PTS 16384
#define NUM_G 64
#define GRP_K 32
#define EPSF 1e-5f

typedef short bf16x8 __attribute__((ext_vector_type(8)));
typedef short bf16x4 __attribute__((ext_vector_type(4)));
typedef float f32x4 __attribute__((ext_vector_type(4)));
typedef unsigned short u16x8 __attribute__((ext_vector_type(8)));

__device__ __forceinline__ unsigned short f2bf(float x) {
    unsigned int u = __builtin_bit_cast(unsigned int, x);
    u = (u + 0x7FFFu + ((u >> 16) & 1u)) >> 16;
    return (unsigned short)u;
}
__device__ __forceinline__ float bf2f(unsigned short h) {
    unsigned int u = ((unsigned int)h) << 16;
    return __builtin_bit_cast(float, u);
}

// ---------------- Phase A: farthest point sampling ----------------
// 1 block/batch, 1024 thr x 16 pts in registers. One barrier/iter.
// Reduce: wave butterfly -> 16 LDS entries -> lanes 0-15 of EVERY wave do a
// 4-step mini-butterfly + lane0 broadcast (replaces the old all-threads 16-way
// LDS merge that moved ~130KB/iter through LDS).
// Key u64 = (dist_bits<<32) | ~p : max => max dist, tie => min index.
__global__ __launch_bounds__(1024, 4) void fps_kernel(const float* __restrict__ pcd,
                                                      int* __restrict__ cidx) {
    const int b = blockIdx.x;
    const int tid = threadIdx.x;
    const int lane = tid & 63, w = tid >> 6;
    const float* xb = pcd + (size_t)b * 6 * N_PTS;

    float px[16], py[16], pz[16], dist[16];
#pragma unroll
    for (int j = 0; j < 16; ++j) {
        int p = tid + 1024 * j;
        px[j] = xb[p];
        py[j] = xb[N_PTS + p];
        pz[j] = xb[2 * N_PTS + p];
        dist[j] = 1e10f;
    }

    __shared__ unsigned long long wk[2][16];
    __shared__ int clds[NUM_G];

    int far = 0;
    for (int it = 0; it < NUM_G; ++it) {
        int fu = __builtin_amdgcn_readfirstlane(far);
        float cx = xb[fu], cy = xb[N_PTS + fu], cz = xb[2 * N_PTS + fu];
        if (tid == 0) clds[it] = fu;

        unsigned long long kmax = 0ull;
#pragma unroll
        for (int j = 0; j < 16; ++j) {
            float dx = __fsub_rn(px[j], cx);
            float dy = __fsub_rn(py[j], cy);
            float dz = __fsub_rn(pz[j], cz);
            float d = __fadd_rn(__fadd_rn(__fmul_rn(dx, dx), __fmul_rn(dy, dy)),
                                __fmul_rn(dz, dz));
            dist[j] = fminf(dist[j], d);
            unsigned long long key =
                ((unsigned long long)__float_as_uint(dist[j]) << 32) |
                (unsigned int)~(tid + 1024 * j);
            kmax = kmax > key ? kmax : key;
        }
#pragma unroll
        for (int m = 1; m < 64; m <<= 1) {
            unsigned long long o = __shfl_xor(kmax, m, 64);
            kmax = o > kmax ? o : kmax;
        }
        if (lane == 0) wk[it & 1][w] = kmax;
        __syncthreads();
        unsigned long long k2 = (lane < 16) ? wk[it & 1][lane] : 0ull;
#pragma unroll
        for (int m = 1; m < 16; m <<= 1) {
            unsigned long long o = __shfl_xor(k2, m, 64);
            k2 = o > k2 ? o : k2;
        }
        k2 = __shfl(k2, 0, 64);  // lane0 of each wave has global max; broadcast
        far = (int)(~(unsigned int)k2);
    }
    __syncthreads();
    if (tid < NUM_G) cidx[b * NUM_G + tid] = clds[tid];
}

// ---------------- Phase B: KNN — ONE WAVE per group, zero barriers ----------------
// Layout: point p = j*256 + lane*4 + u  (j<64, u<4): lane reads float4 at 16B
// stride -> coalesced 1KB/instruction. Owner of p: lane (p>>2)&63, slot
// ((p>>8)<<2)|(p&3) in a 256-bit removed mask (4x u64, branchless select).
// 16 dual-extraction rounds, all wave-synchronous shfl (no __syncthreads).
__device__ __forceinline__ void merge2(unsigned long long& a1, unsigned long long& a2,
                                       unsigned long long o1, unsigned long long o2) {
    unsigned long long hi = a1 > o1 ? a1 : o1;
    a1 = a1 < o1 ? a1 : o1;
    unsigned long long lo2 = a2 < o2 ? a2 : o2;
    a2 = hi < lo2 ? hi : lo2;
}
__device__ __forceinline__ void top2upd(unsigned long long& b1, unsigned long long& b2,
                                        unsigned long long v) {
    unsigned long long hi = b1 > v ? b1 : v;
    b1 = b1 < v ? b1 : v;
    b2 = b2 < hi ? b2 : hi;
}

__global__ __launch_bounds__(64, 4) void knn_kernel(const float* __restrict__ pcd,
                                                    const int* __restrict__ cidx,
                                                    float* __restrict__ xout) {
    const int bg = blockIdx.x;
    const int b = bg >> 6;
    const int lane = threadIdx.x;
    const float* xb = pcd + (size_t)b * 6 * N_PTS;

    const int ci = cidx[bg];
    const float cx = xb[ci], cy = xb[N_PTS + ci], cz = xb[2 * N_PTS + ci];

    const float4* X4 = (const float4*)xb;
    const float4* Y4 = (const float4*)(xb + N_PTS);
    const float4* Z4 = (const float4*)(xb + 2 * N_PTS);

    unsigned long long b1 = ~0ull, b2 = ~0ull;
#pragma unroll 8
    for (int j = 0; j < 64; ++j) {
        float4 xv = X4[j * 64 + lane];
        float4 yv = Y4[j * 64 + lane];
        float4 zv = Z4[j * 64 + lane];
        float xs4[4] = {xv.x, xv.y, xv.z, xv.w};
        float ys4[4] = {yv.x, yv.y, yv.z, yv.w};
        float zs4[4] = {zv.x, zv.y, zv.z, zv.w};
        unsigned int p = (unsigned int)(j * 256 + lane * 4);
#pragma unroll
        for (int u = 0; u < 4; ++u) {
            float dx = __fsub_rn(cx, xs4[u]);
            float dy = __fsub_rn(cy, ys4[u]);
            float dz = __fsub_rn(cz, zs4[u]);
            float d = __fadd_rn(__fadd_rn(__fmul_rn(dx, dx), __fmul_rn(dy, dy)),
                                __fmul_rn(dz, dz));
            top2upd(b1, b2, ((unsigned long long)__float_as_uint(d) << 32) | (p + u));
        }
    }

    unsigned long long rm0 = 0, rm1 = 0, rm2 = 0, rm3 = 0;
    __shared__ int knn_sh[GRP_K];

    for (int r = 0; r < 16; ++r) {
        unsigned long long r1 = b1, r2 = b2;
#pragma unroll
        for (int m = 1; m < 64; m <<= 1) {
            unsigned long long o1 = __shfl_xor(r1, m, 64);
            unsigned long long o2 = __shfl_xor(r2, m, 64);
            merge2(r1, r2, o1, o2);
        }
        const int q1 = (int)(unsigned int)r1;
        const int q2 = (int)(unsigned int)r2;
        if (lane == 0) { knn_sh[2 * r] = q1; knn_sh[2 * r + 1] = q2; }

        const int wl1 = (q1 >> 2) & 63, s1 = ((q1 >> 8) << 2) | (q1 & 3);
        const int wl2 = (q2 >> 2) & 63, s2 = ((q2 >> 8) << 2) | (q2 & 3);
        {
            unsigned long long bit1 = 1ull << (s1 & 63);
            unsigned long long bit2 = 1ull << (s2 & 63);
            if (lane == wl1) {
                rm0 |= ((s1 >> 6) == 0) ? bit1 : 0ull;
                rm1 |= ((s1 >> 6) == 1) ? bit1 : 0ull;
                rm2 |= ((s1 >> 6) == 2) ? bit1 : 0ull;
                rm3 |= ((s1 >> 6) == 3) ? bit1 : 0ull;
            }
            if (lane == wl2) {
                rm0 |= ((s2 >> 6) == 0) ? bit2 : 0ull;
                rm1 |= ((s2 >> 6) == 1) ? bit2 : 0ull;
                rm2 |= ((s2 >> 6) == 2) ? bit2 : 0ull;
                rm3 |= ((s2 >> 6) == 3) ? bit2 : 0ull;
            }
        }

        // wave-parallel rescan of each winner lane's 256 points (masked recompute)
#pragma unroll 1
        for (int s = 0; s < 2; ++s) {
            if (s == 1 && wl2 == wl1) break;  // wave-uniform
            const int wl = s ? wl2 : wl1;
            unsigned long long m0 = __shfl(rm0, wl, 64);
            unsigned long long m1 = __shfl(rm1, wl, 64);
            unsigned long long m2 = __shfl(rm2, wl, 64);
            unsigned long long m3 = __shfl(rm3, wl, 64);
            const int wsel = lane >> 4;
            unsigned long long mw = wsel == 0 ? m0 : (wsel == 1 ? m1 : (wsel == 2 ? m2 : m3));
            // lane i covers points p = i*256 + wl*4 + u
            float4 xv = X4[lane * 64 + wl];
            float4 yv = Y4[lane * 64 + wl];
            float4 zv = Z4[lane * 64 + wl];
            float xs4[4] = {xv.x, xv.y, xv.z, xv.w};
            float ys4[4] = {yv.x, yv.y, yv.z, yv.w};
            float zs4[4] = {zv.x, zv.y, zv.z, zv.w};
            unsigned int p = (unsigned int)(lane * 256 + wl * 4);
            unsigned long long s1v = ~0ull, s2v = ~0ull;
#pragma unroll
            for (int u = 0; u < 4; ++u) {
                float dx = __fsub_rn(cx, xs4[u]);
                float dy = __fsub_rn(cy, ys4[u]);
                float dz = __fsub_rn(cz, zs4[u]);
                float d = __fadd_rn(__fadd_rn(__fmul_rn(dx, dx), __fmul_rn(dy, dy)),
                                    __fmul_rn(dz, dz));
                unsigned long long v =
                    ((unsigned long long)__float_as_uint(d) << 32) | (p + u);
                if ((mw >> (((lane & 15) << 2) | u)) & 1ull) v = ~0ull;
                top2upd(s1v, s2v, v);
            }
#pragma unroll
            for (int m = 1; m < 64; m <<= 1) {
                unsigned long long o1 = __shfl_xor(s1v, m, 64);
                unsigned long long o2 = __shfl_xor(s2v, m, 64);
                merge2(s1v, s2v, o1, o2);
            }
            if (lane == wl) { b1 = s1v; b2 = s2v; }
        }
    }
    __syncthreads();  // single-wave block: cheap; orders knn_sh for the gather

    // gather 32 x 6, subtract center from xyz channels
#pragma unroll
    for (int t = 0; t < 3; ++t) {
        int i = lane + 64 * t;
        int k = i / 6, c = i % 6;
        int p = knn_sh[k];
        float val = xb[c * N_PTS + p];
        if (c == 0) val = __fsub_rn(val, cx);
        else if (c == 1) val = __fsub_rn(val, cy);
        else if (c == 2) val = __fsub_rn(val, cz);
        xout[(size_t)bg * 192 + i] = val;
    }
}

// ---------------- Prep: LDS-tiled transpose fp32[K][N] -> bf16[N][K] ----------------
__global__ __launch_bounds__(256) void prep_kernel(const float* __restrict__ w2,
                                                   const float* __restrict__ w3,
                                                   const float* __restrict__ w4,
                                                   unsigned short* __restrict__ w2t,
                                                   unsigned short* __restrict__ w3t,
                                                   unsigned short* __restrict__ w4t) {
    const int tile = blockIdx.x;
    const float* src;
    unsigned short* dst;
    int K, N, kt, nt;
    if (tile < 8) {
        src = w2; dst = w2t; K = 128; N = 256;
        kt = tile >> 2; nt = tile & 3;
    } else if (tile < 72) {
        int t2 = tile - 8;
        src = w3; dst = w3t; K = 512; N = 512;
        kt = t2 >> 3; nt = t2 & 7;
    } else {
        int t2 = tile - 72;
        src = w4; dst = w4t; K = 512; N = 384;
        kt = t2 / 6; nt = t2 % 6;
    }
    const int k0 = kt * 64, n0 = nt * 64;

    __shared__ unsigned short tl[64][72];

    const int c = threadIdx.x & 63, r0 = threadIdx.x >> 6;
#pragma unroll
    for (int i = 0; i < 16; ++i) {
        int r = 4 * i + r0;
        tl[r][c] = f2bf(src[(size_t)(k0 + r) * N + n0 + c]);
    }
    __syncthreads();

    const int n = threadIdx.x >> 2;
    const int kc = (threadIdx.x & 3) * 16;
    u16x8 v0, v1;
#pragma unroll
    for (int j = 0; j < 8; ++j) {
        v0[j] = tl[kc + j][n];
        v1[j] = tl[kc + 8 + j][n];
    }
    *(u16x8*)(dst + (size_t)(n0 + n) * K + k0 + kc) = v0;
    *(u16x8*)(dst + (size_t)(n0 + n) * K + k0 + kc + 8) = v1;
}

// ---------------- Phase C: MFMA MLP; L3 weight stream depth-4 pipelined ----------------
__global__ __launch_bounds__(256, 2) void mlp_mfma_kernel(
    const float* __restrict__ xin,
    const float* __restrict__ w1, const float* __restrict__ b1,
    const float* __restrict__ g1, const float* __restrict__ be1,
    const float* __restrict__ m1, const float* __restrict__ v1,
    const unsigned short* __restrict__ w2t, const float* __restrict__ b2,
    const unsigned short* __restrict__ w3t, const float* __restrict__ b3,
    const float* __restrict__ g2, const float* __restrict__ be2,
    const float* __restrict__ m2, const float* __restrict__ v2,
    const unsigned short* __restrict__ w4t, const float* __restrict__ b4,
    float* __restrict__ out) {
    const int bg0 = blockIdx.x * 2;
    const int t = threadIdx.x;
    const int w = t >> 6;
    const int lane = t & 63;
    const int lr = lane & 15;
    const int lq = lane >> 4;

    __shared__ __align__(16) unsigned short f1s[64 * 136];
    __shared__ __align__(16) unsigned short f2s[64 * 264];
    __shared__ __align__(16) unsigned short fgs[2 * 256];
    __shared__ float xs[2 * 32 * 6];

    for (int i = t; i < 384; i += 256) xs[i] = xin[(size_t)bg0 * 192 + i];
    __syncthreads();

    // ---- L1: 6->128, bn1, relu ----
    {
        const int d = t & 127, mh = t >> 7;
        float wv[6];
#pragma unroll
        for (int c = 0; c < 6; ++c) wv[c] = w1[c * 128 + d];
        const float sc = g1[d] * rsqrtf(v1[d] + EPSF);
        const float sh = be1[d] - m1[d] * sc;
        const float bias = b1[d];
#pragma unroll
        for (int j = 0; j < 32; ++j) {
            float s = bias;
#pragma unroll
            for (int c = 0; c < 6; ++c) s += xs[mh * 192 + j * 6 + c] * wv[c];
            f1s[(mh * 32 + j) * 136 + d] = f2bf(fmaxf(s * sc + sh, 0.0f));
        }
    }
    __syncthreads();

    // ---- L2: [64x128] @ w2[128x256] -> f2s ----
    {
        const int n0 = w * 64;
        f32x4 acc[4][4];
#pragma unroll
        for (int nti = 0; nti < 4; ++nti) {
            f32x4 bq = *(const f32x4*)(b2 + n0 + nti * 16 + lq * 4);
#pragma unroll
            for (int mt = 0; mt < 4; ++mt) acc[mt][nti] = bq;
        }
#pragma unroll
        for (int ks = 0; ks < 4; ++ks) {
            bf16x8 xf[4], wf[4];
#pragma unroll
            for (int mt = 0; mt < 4; ++mt)
                xf[mt] = *(const bf16x8*)(f1s + (mt * 16 + lr) * 136 + ks * 32 + lq * 8);
#pragma unroll
            for (int nti = 0; nti < 4; ++nti)
                wf[nti] = *(const bf16x8*)(w2t + (n0 + nti * 16 + lr) * 128 + ks * 32 + lq * 8);
#pragma unroll
            for (int mt = 0; mt < 4; ++mt)
#pragma unroll
                for (int nti = 0; nti < 4; ++nti)
                    acc[mt][nti] = __builtin_amdgcn_mfma_f32_16x16x32_bf16(wf[nti], xf[mt], acc[mt][nti], 0, 0, 0);
        }
#pragma unroll
        for (int mt = 0; mt < 4; ++mt)
#pragma unroll
            for (int nti = 0; nti < 4; ++nti) {
                bf16x4 p;
#pragma unroll
                for (int r = 0; r < 4; ++r) p[r] = (short)f2bf(acc[mt][nti][r]);
                *(bf16x4*)(f2s + (mt * 16 + lr) * 264 + n0 + nti * 16 + lq * 4) = p;
            }
    }
    __syncthreads();

    // ---- fg = column max per group ----
    for (int idx = t; idx < 512; idx += 256) {
        int g = idx >> 8, n = idx & 255;
        float m = -3.9e38f;
#pragma unroll
        for (int k = 0; k < 32; ++k) m = fmaxf(m, bf2f(f2s[(g * 32 + k) * 264 + n]));
        fgs[g * 256 + n] = f2bf(m);
    }
    __syncthreads();

    auto ldw3f = [&](int cb_, int ks_, int nti_) -> bf16x8 {
        return *(const bf16x8*)(w3t + (size_t)(cb_ * 128 + w * 32 + nti_ * 16 + lr) * 512 + ks_ * 32 + lq * 8);
    };
    auto ldw4f = [&](int cb_, int kl_, int nti_) -> bf16x8 {
        return *(const bf16x8*)(w4t + (size_t)(w * 96 + nti_ * 16 + lr) * 512 + cb_ * 128 + kl_ * 32 + lq * 8);
    };
    auto ldxf3 = [&](int ks_, bf16x8* xf) {
        if (ks_ < 8) {
            bf16x8 x0 = *(const bf16x8*)(fgs + ks_ * 32 + lq * 8);
            bf16x8 x1 = *(const bf16x8*)(fgs + 256 + ks_ * 32 + lq * 8);
            xf[0] = x0; xf[1] = x0; xf[2] = x1; xf[3] = x1;
        } else {
#pragma unroll
            for (int mt = 0; mt < 4; ++mt)
                xf[mt] = *(const bf16x8*)(f2s + (mt * 16 + lr) * 264 + (ks_ - 8) * 32 + lq * 8);
        }
    };

    f32x4 acc4[6][4];
#pragma unroll
    for (int nti = 0; nti < 6; ++nti) {
        f32x4 bq = *(const f32x4*)(b4 + w * 96 + nti * 16 + lq * 4);
#pragma unroll
        for (int mt = 0; mt < 4; ++mt) acc4[nti][mt] = bq;
    }

    for (int cb = 0; cb < 4; ++cb) {
        f32x4 acc3[2][4];
#pragma unroll
        for (int nti = 0; nti < 2; ++nti) {
            f32x4 bq = *(const f32x4*)(b3 + cb * 128 + w * 32 + nti * 16 + lq * 4);
#pragma unroll
            for (int mt = 0; mt < 4; ++mt) acc3[nti][mt] = bq;
        }
        // depth-4 weight pipeline: 8 fragments in flight
        bf16x8 wf3[4][2];
#pragma unroll
        for (int kp = 0; kp < 4; ++kp) {
            wf3[kp][0] = ldw3f(cb, kp, 0);
            wf3[kp][1] = ldw3f(cb, kp, 1);
        }
#pragma unroll
        for (int ks = 0; ks < 16; ++ks) {
            const int slot = ks & 3;
            bf16x8 w0 = wf3[slot][0], w1f = wf3[slot][1];
            if (ks < 12) {
                wf3[slot][0] = ldw3f(cb, ks + 4, 0);
                wf3[slot][1] = ldw3f(cb, ks + 4, 1);
            }
            bf16x8 xf[4];
            ldxf3(ks, xf);
#pragma unroll
            for (int mt = 0; mt < 4; ++mt) {
                acc3[0][mt] = __builtin_amdgcn_mfma_f32_16x16x32_bf16(w0, xf[mt], acc3[0][mt], 0, 0, 0);
                acc3[1][mt] = __builtin_amdgcn_mfma_f32_16x16x32_bf16(w1f, xf[mt], acc3[1][mt], 0, 0, 0);
            }
        }
        // bn2 + relu -> f3 chunk (reuse f1s)
#pragma unroll
        for (int nti = 0; nti < 2; ++nti) {
            const int nq = cb * 128 + w * 32 + nti * 16 + lq * 4;
            f32x4 g2q = *(const f32x4*)(g2 + nq);
            f32x4 v2q = *(const f32x4*)(v2 + nq);
            f32x4 m2q = *(const f32x4*)(m2 + nq);
            f32x4 beq = *(const f32x4*)(be2 + nq);
            f32x4 sc, sh;
#pragma unroll
            for (int r = 0; r < 4; ++r) {
                sc[r] = g2q[r] * rsqrtf(v2q[r] + EPSF);
                sh[r] = beq[r] - m2q[r] * sc[r];
            }
#pragma unroll
            for (int mt = 0; mt < 4; ++mt) {
                bf16x4 p;
#pragma unroll
                for (int r = 0; r < 4; ++r)
                    p[r] = (short)f2bf(fmaxf(acc3[nti][mt][r] * sc[r] + sh[r], 0.0f));
                *(bf16x4*)(f1s + (mt * 16 + lr) * 136 + w * 32 + nti * 16 + lq * 4) = p;
            }
        }
        bf16x8 w4a[6];
#pragma unroll
        for (int nti = 0; nti < 6; ++nti) w4a[nti] = ldw4f(cb, 0, nti);
        __syncthreads();
        for (int kl = 0; kl < 4; kl += 2) {
            bf16x8 w4b[6];
#pragma unroll
            for (int nti = 0; nti < 6; ++nti) w4b[nti] = ldw4f(cb, kl + 1, nti);
            bf16x8 xf[4];
#pragma unroll
            for (int mt = 0; mt < 4; ++mt)
                xf[mt] = *(const bf16x8*)(f1s + (mt * 16 + lr) * 136 + kl * 32 + lq * 8);
#pragma unroll
            for (int nti = 0; nti < 6; ++nti)
#pragma unroll
                for (int mt = 0; mt < 4; ++mt)
                    acc4[nti][mt] = __builtin_amdgcn_mfma_f32_16x16x32_bf16(w4a[nti], xf[mt], acc4[nti][mt], 0, 0, 0);
            if (kl + 2 < 4) {
#pragma unroll
                for (int nti = 0; nti < 6; ++nti) w4a[nti] = ldw4f(cb, kl + 2, nti);
            }
#pragma unroll
            for (int mt = 0; mt < 4; ++mt)
                xf[mt] = *(const bf16x8*)(f1s + (mt * 16 + lr) * 136 + (kl + 1) * 32 + lq * 8);
#pragma unroll
            for (int nti = 0; nti < 6; ++nti)
#pragma unroll
                for (int mt = 0; mt < 4; ++mt)
                    acc4[nti][mt] = __builtin_amdgcn_mfma_f32_16x16x32_bf16(w4b[nti], xf[mt], acc4[nti][mt], 0, 0, 0);
        }
        if (cb < 3) __syncthreads();
    }

#pragma unroll
    for (int nti = 0; nti < 6; ++nti) {
#pragma unroll
        for (int g = 0; g < 2; ++g) {
            f32x4 vv;
#pragma unroll
            for (int r = 0; r < 4; ++r)
                vv[r] = fmaxf(acc4[nti][2 * g][r], acc4[nti][2 * g + 1][r]);
#pragma unroll
            for (int mask = 1; mask <= 8; mask <<= 1) {
#pragma unroll
                for (int r = 0; r < 4; ++r)
                    vv[r] = fmaxf(vv[r], __shfl_xor(vv[r], mask, 64));
            }
            if (lr == 0)
                *(f32x4*)(out + (size_t)(bg0 + g) * 384 + w * 96 + nti * 16 + lq * 4) = vv;
        }
    }
}

extern "C" void kernel_launch(void* const* d_in, const int* in_sizes, int n_in,
                              void* d_out, int out_size, void* d_ws, size_t ws_size,
                              hipStream_t stream) {
    const float* pcd = (const float*)d_in[0];
    const float* w1 = (const float*)d_in[2];
    const float* b1 = (const float*)d_in[3];
    const float* g1 = (const float*)d_in[4];
    const float* be1 = (const float*)d_in[5];
    const float* m1 = (const float*)d_in[6];
    const float* v1 = (const float*)d_in[7];
    const float* w2 = (const float*)d_in[8];
    const float* b2 = (const float*)d_in[9];
    const float* w3 = (const float*)d_in[10];
    const float* b3 = (const float*)d_in[11];
    const float* g2 = (const float*)d_in[12];
    const float* be2 = (const float*)d_in[13];
    const float* m2 = (const float*)d_in[14];
    const float* v2 = (const float*)d_in[15];
    const float* w4 = (const float*)d_in[16];
    const float* b4 = (const float*)d_in[17];
    float* out = (float*)d_out;

    char* ws = (char*)d_ws;
    int* cidx = (int*)ws;                                   // 8192 B
    float* xg = (float*)(ws + 8192);                        // 1,572,864 B
    unsigned short* w2t = (unsigned short*)(ws + 1581056);  // 65,536 B
    unsigned short* w3t = (unsigned short*)(ws + 1646592);  // 524,288 B
    unsigned short* w4t = (unsigned short*)(ws + 2170880);  // 393,216 B

    prep_kernel<<<120, 256, 0, stream>>>(w2, w3, w4, w2t, w3t, w4t);
    fps_kernel<<<32, 1024, 0, stream>>>(pcd, cidx);
    knn_kernel<<<2048, 64, 0, stream>>>(pcd, cidx, xg);
    mlp_mfma_kernel<<<1024, 256, 0, stream>>>(xg, w1, b1, g1, be1, m1, v1,
                                              w2t, b2, w3t, b3, g2, be2, m2, v2,
                                              w4t, b4, out);
}

// Round 7
// 421.354 us; speedup vs baseline: 3.9807x; 1.0854x over previous
//
#include <hip/hip_runtime.h>
#include <hip/hip_bf16.h>
#include <math.h>

#define N_PTS 16384
#define NUM_G 64
#define GRP_K 32
#define EPSF 1e-5f

typedef short bf16x8 __attribute__((ext_vector_type(8)));
typedef short bf16x4 __attribute__((ext_vector_type(4)));
typedef float f32x4 __attribute__((ext_vector_type(4)));
typedef unsigned short u16x8 __attribute__((ext_vector_type(8)));

__device__ __forceinline__ unsigned short f2bf(float x) {
    unsigned int u = __builtin_bit_cast(unsigned int, x);
    u = (u + 0x7FFFu + ((u >> 16) & 1u)) >> 16;
    return (unsigned short)u;
}
__device__ __forceinline__ float bf2f(unsigned short h) {
    unsigned int u = ((unsigned int)h) << 16;
    return __builtin_bit_cast(float, u);
}

// ---------------- Phase A: farthest point sampling (unchanged from R5) ----------------
__global__ __launch_bounds__(1024, 4) void fps_kernel(const float* __restrict__ pcd,
                                                      int* __restrict__ cidx) {
    const int b = blockIdx.x;
    const int tid = threadIdx.x;
    const int lane = tid & 63, w = tid >> 6;
    const float* xb = pcd + (size_t)b * 6 * N_PTS;

    float px[16], py[16], pz[16], dist[16];
#pragma unroll
    for (int j = 0; j < 16; ++j) {
        int p = tid + 1024 * j;
        px[j] = xb[p];
        py[j] = xb[N_PTS + p];
        pz[j] = xb[2 * N_PTS + p];
        dist[j] = 1e10f;
    }

    __shared__ unsigned long long wk[2][16];
    __shared__ int clds[NUM_G];

    int far = 0;
    for (int it = 0; it < NUM_G; ++it) {
        int fu = __builtin_amdgcn_readfirstlane(far);
        float cx = xb[fu], cy = xb[N_PTS + fu], cz = xb[2 * N_PTS + fu];
        if (tid == 0) clds[it] = fu;

        unsigned long long kmax = 0ull;
#pragma unroll
        for (int j = 0; j < 16; ++j) {
            float dx = __fsub_rn(px[j], cx);
            float dy = __fsub_rn(py[j], cy);
            float dz = __fsub_rn(pz[j], cz);
            float d = __fadd_rn(__fadd_rn(__fmul_rn(dx, dx), __fmul_rn(dy, dy)),
                                __fmul_rn(dz, dz));
            dist[j] = fminf(dist[j], d);
            unsigned long long key =
                ((unsigned long long)__float_as_uint(dist[j]) << 32) |
                (unsigned int)~(tid + 1024 * j);
            kmax = kmax > key ? kmax : key;
        }
#pragma unroll
        for (int m = 1; m < 64; m <<= 1) {
            unsigned long long o = __shfl_xor(kmax, m, 64);
            kmax = o > kmax ? o : kmax;
        }
        if (lane == 0) wk[it & 1][w] = kmax;
        __syncthreads();
        unsigned long long k2 = (lane < 16) ? wk[it & 1][lane] : 0ull;
#pragma unroll
        for (int m = 1; m < 16; m <<= 1) {
            unsigned long long o = __shfl_xor(k2, m, 64);
            k2 = o > k2 ? o : k2;
        }
        k2 = __shfl(k2, 0, 64);
        far = (int)(~(unsigned int)k2);
    }
    __syncthreads();
    if (tid < NUM_G) cidx[b * NUM_G + tid] = clds[tid];
}

// ---------------- Phase B: KNN — one wave per group (unchanged from R5) ----------------
__device__ __forceinline__ void merge2(unsigned long long& a1, unsigned long long& a2,
                                       unsigned long long o1, unsigned long long o2) {
    unsigned long long hi = a1 > o1 ? a1 : o1;
    a1 = a1 < o1 ? a1 : o1;
    unsigned long long lo2 = a2 < o2 ? a2 : o2;
    a2 = hi < lo2 ? hi : lo2;
}
__device__ __forceinline__ void top2upd(unsigned long long& b1, unsigned long long& b2,
                                        unsigned long long v) {
    unsigned long long hi = b1 > v ? b1 : v;
    b1 = b1 < v ? b1 : v;
    b2 = b2 < hi ? b2 : hi;
}

__global__ __launch_bounds__(64, 4) void knn_kernel(const float* __restrict__ pcd,
                                                    const int* __restrict__ cidx,
                                                    float* __restrict__ xout) {
    const int bg = blockIdx.x;
    const int b = bg >> 6;
    const int lane = threadIdx.x;
    const float* xb = pcd + (size_t)b * 6 * N_PTS;

    const int ci = cidx[bg];
    const float cx = xb[ci], cy = xb[N_PTS + ci], cz = xb[2 * N_PTS + ci];

    const float4* X4 = (const float4*)xb;
    const float4* Y4 = (const float4*)(xb + N_PTS);
    const float4* Z4 = (const float4*)(xb + 2 * N_PTS);

    unsigned long long b1 = ~0ull, b2 = ~0ull;
#pragma unroll 8
    for (int j = 0; j < 64; ++j) {
        float4 xv = X4[j * 64 + lane];
        float4 yv = Y4[j * 64 + lane];
        float4 zv = Z4[j * 64 + lane];
        float xs4[4] = {xv.x, xv.y, xv.z, xv.w};
        float ys4[4] = {yv.x, yv.y, yv.z, yv.w};
        float zs4[4] = {zv.x, zv.y, zv.z, zv.w};
        unsigned int p = (unsigned int)(j * 256 + lane * 4);
#pragma unroll
        for (int u = 0; u < 4; ++u) {
            float dx = __fsub_rn(cx, xs4[u]);
            float dy = __fsub_rn(cy, ys4[u]);
            float dz = __fsub_rn(cz, zs4[u]);
            float d = __fadd_rn(__fadd_rn(__fmul_rn(dx, dx), __fmul_rn(dy, dy)),
                                __fmul_rn(dz, dz));
            top2upd(b1, b2, ((unsigned long long)__float_as_uint(d) << 32) | (p + u));
        }
    }

    unsigned long long rm0 = 0, rm1 = 0, rm2 = 0, rm3 = 0;
    __shared__ int knn_sh[GRP_K];

    for (int r = 0; r < 16; ++r) {
        unsigned long long r1 = b1, r2 = b2;
#pragma unroll
        for (int m = 1; m < 64; m <<= 1) {
            unsigned long long o1 = __shfl_xor(r1, m, 64);
            unsigned long long o2 = __shfl_xor(r2, m, 64);
            merge2(r1, r2, o1, o2);
        }
        const int q1 = (int)(unsigned int)r1;
        const int q2 = (int)(unsigned int)r2;
        if (lane == 0) { knn_sh[2 * r] = q1; knn_sh[2 * r + 1] = q2; }

        const int wl1 = (q1 >> 2) & 63, s1 = ((q1 >> 8) << 2) | (q1 & 3);
        const int wl2 = (q2 >> 2) & 63, s2 = ((q2 >> 8) << 2) | (q2 & 3);
        {
            unsigned long long bit1 = 1ull << (s1 & 63);
            unsigned long long bit2 = 1ull << (s2 & 63);
            if (lane == wl1) {
                rm0 |= ((s1 >> 6) == 0) ? bit1 : 0ull;
                rm1 |= ((s1 >> 6) == 1) ? bit1 : 0ull;
                rm2 |= ((s1 >> 6) == 2) ? bit1 : 0ull;
                rm3 |= ((s1 >> 6) == 3) ? bit1 : 0ull;
            }
            if (lane == wl2) {
                rm0 |= ((s2 >> 6) == 0) ? bit2 : 0ull;
                rm1 |= ((s2 >> 6) == 1) ? bit2 : 0ull;
                rm2 |= ((s2 >> 6) == 2) ? bit2 : 0ull;
                rm3 |= ((s2 >> 6) == 3) ? bit2 : 0ull;
            }
        }

#pragma unroll 1
        for (int s = 0; s < 2; ++s) {
            if (s == 1 && wl2 == wl1) break;
            const int wl = s ? wl2 : wl1;
            unsigned long long m0 = __shfl(rm0, wl, 64);
            unsigned long long m1 = __shfl(rm1, wl, 64);
            unsigned long long m2 = __shfl(rm2, wl, 64);
            unsigned long long m3 = __shfl(rm3, wl, 64);
            const int wsel = lane >> 4;
            unsigned long long mw = wsel == 0 ? m0 : (wsel == 1 ? m1 : (wsel == 2 ? m2 : m3));
            float4 xv = X4[lane * 64 + wl];
            float4 yv = Y4[lane * 64 + wl];
            float4 zv = Z4[lane * 64 + wl];
            float xs4[4] = {xv.x, xv.y, xv.z, xv.w};
            float ys4[4] = {yv.x, yv.y, yv.z, yv.w};
            float zs4[4] = {zv.x, zv.y, zv.z, zv.w};
            unsigned int p = (unsigned int)(lane * 256 + wl * 4);
            unsigned long long s1v = ~0ull, s2v = ~0ull;
#pragma unroll
            for (int u = 0; u < 4; ++u) {
                float dx = __fsub_rn(cx, xs4[u]);
                float dy = __fsub_rn(cy, ys4[u]);
                float dz = __fsub_rn(cz, zs4[u]);
                float d = __fadd_rn(__fadd_rn(__fmul_rn(dx, dx), __fmul_rn(dy, dy)),
                                    __fmul_rn(dz, dz));
                unsigned long long v =
                    ((unsigned long long)__float_as_uint(d) << 32) | (p + u);
                if ((mw >> (((lane & 15) << 2) | u)) & 1ull) v = ~0ull;
                top2upd(s1v, s2v, v);
            }
#pragma unroll
            for (int m = 1; m < 64; m <<= 1) {
                unsigned long long o1 = __shfl_xor(s1v, m, 64);
                unsigned long long o2 = __shfl_xor(s2v, m, 64);
                merge2(s1v, s2v, o1, o2);
            }
            if (lane == wl) { b1 = s1v; b2 = s2v; }
        }
    }
    __syncthreads();

#pragma unroll
    for (int t = 0; t < 3; ++t) {
        int i = lane + 64 * t;
        int k = i / 6, c = i % 6;
        int p = knn_sh[k];
        float val = xb[c * N_PTS + p];
        if (c == 0) val = __fsub_rn(val, cx);
        else if (c == 1) val = __fsub_rn(val, cy);
        else if (c == 2) val = __fsub_rn(val, cz);
        xout[(size_t)bg * 192 + i] = val;
    }
}

// ---------------- Prep: LDS-tiled transpose fp32[K][N] -> bf16[N][K] (unchanged) ----------------
__global__ __launch_bounds__(256) void prep_kernel(const float* __restrict__ w2,
                                                   const float* __restrict__ w3,
                                                   const float* __restrict__ w4,
                                                   unsigned short* __restrict__ w2t,
                                                   unsigned short* __restrict__ w3t,
                                                   unsigned short* __restrict__ w4t) {
    const int tile = blockIdx.x;
    const float* src;
    unsigned short* dst;
    int K, N, kt, nt;
    if (tile < 8) {
        src = w2; dst = w2t; K = 128; N = 256;
        kt = tile >> 2; nt = tile & 3;
    } else if (tile < 72) {
        int t2 = tile - 8;
        src = w3; dst = w3t; K = 512; N = 512;
        kt = t2 >> 3; nt = t2 & 7;
    } else {
        int t2 = tile - 72;
        src = w4; dst = w4t; K = 512; N = 384;
        kt = t2 / 6; nt = t2 % 6;
    }
    const int k0 = kt * 64, n0 = nt * 64;

    __shared__ unsigned short tl[64][72];

    const int c = threadIdx.x & 63, r0 = threadIdx.x >> 6;
#pragma unroll
    for (int i = 0; i < 16; ++i) {
        int r = 4 * i + r0;
        tl[r][c] = f2bf(src[(size_t)(k0 + r) * N + n0 + c]);
    }
    __syncthreads();

    const int n = threadIdx.x >> 2;
    const int kc = (threadIdx.x & 3) * 16;
    u16x8 v0, v1;
#pragma unroll
    for (int j = 0; j < 8; ++j) {
        v0[j] = tl[kc + j][n];
        v1[j] = tl[kc + 8 + j][n];
    }
    *(u16x8*)(dst + (size_t)(n0 + n) * K + k0 + kc) = v0;
    *(u16x8*)(dst + (size_t)(n0 + n) * K + k0 + kc + 8) = v1;
}

// ---------------- Phase C v2: M=128 mega-block (4 groups, 512 thr, 1 block/CU) ----------------
// Wave w owns DISTINCT col slices: L2 32 cols, L3 16 cols/chunk, L4 48 cols ->
// every weight fragment is read exactly once per block (0.53 GB total L2 traffic).
// h-trick: fg-part of L3 (K=0..256) computed once per group into accH (rows=groups),
// broadcast into acc3 via shfl -> 23% fewer MFMAs; accumulation order unchanged.
__global__ __launch_bounds__(512, 2) void mlp_mfma_kernel(
    const float* __restrict__ xin,
    const float* __restrict__ w1, const float* __restrict__ b1,
    const float* __restrict__ g1, const float* __restrict__ be1,
    const float* __restrict__ m1, const float* __restrict__ v1,
    const unsigned short* __restrict__ w2t, const float* __restrict__ b2,
    const unsigned short* __restrict__ w3t, const float* __restrict__ b3,
    const float* __restrict__ g2, const float* __restrict__ be2,
    const float* __restrict__ m2, const float* __restrict__ v2,
    const unsigned short* __restrict__ w4t, const float* __restrict__ b4,
    float* __restrict__ out) {
    const int g0 = blockIdx.x * 4;
    const int t = threadIdx.x;
    const int w = t >> 6;        // wave 0..7
    const int lane = t & 63;
    const int lr = lane & 15;
    const int lq = lane >> 4;

    __shared__ __align__(16) unsigned short f2s[128 * 264];  // 67,584 B
    __shared__ __align__(16) unsigned short ubuf[128 * 136]; // 34,816 B: f1s(64x136) / f3c(128x136)
    __shared__ __align__(16) unsigned short fgs[4 * 256];    // 2,048 B
    __shared__ float xs[4 * 192];                            // 3,072 B

    unsigned short* f1s = ubuf;
    unsigned short* f3c = ubuf;

    for (int i = t; i < 768; i += 512) xs[i] = xin[(size_t)g0 * 192 + i];
    __syncthreads();

    // ---- L1 + L2 in two row-halves of 64 ----
    {
        const int d = t & 127, rq = t >> 7;  // rq 0..3
        float wv[6];
#pragma unroll
        for (int c = 0; c < 6; ++c) wv[c] = w1[c * 128 + d];
        const float sc = g1[d] * rsqrtf(v1[d] + EPSF);
        const float sh = be1[d] - m1[d] * sc;
        const float bias = b1[d];

        for (int s = 0; s < 2; ++s) {
            // L1: stage rows rl 0..63 = global rows s*64+rl
#pragma unroll
            for (int j = 0; j < 16; ++j) {
                const int rl = rq * 16 + j;
                const int gr = s * 64 + rl;
                const int g = gr >> 5, k = gr & 31;
                float acc = bias;
#pragma unroll
                for (int c = 0; c < 6; ++c) acc += xs[g * 192 + k * 6 + c] * wv[c];
                f1s[rl * 136 + d] = f2bf(fmaxf(acc * sc + sh, 0.0f));
            }
            __syncthreads();
            // L2: wave w cols [32w, 32w+32)
            f32x4 acc[4][2];
#pragma unroll
            for (int nti = 0; nti < 2; ++nti) {
                f32x4 bq = *(const f32x4*)(b2 + w * 32 + nti * 16 + lq * 4);
#pragma unroll
                for (int mtl = 0; mtl < 4; ++mtl) acc[mtl][nti] = bq;
            }
#pragma unroll
            for (int ks = 0; ks < 4; ++ks) {
                bf16x8 xf[4], wf[2];
#pragma unroll
                for (int mtl = 0; mtl < 4; ++mtl)
                    xf[mtl] = *(const bf16x8*)(f1s + (mtl * 16 + lr) * 136 + ks * 32 + lq * 8);
#pragma unroll
                for (int nti = 0; nti < 2; ++nti)
                    wf[nti] = *(const bf16x8*)(w2t + (w * 32 + nti * 16 + lr) * 128 + ks * 32 + lq * 8);
#pragma unroll
                for (int mtl = 0; mtl < 4; ++mtl)
#pragma unroll
                    for (int nti = 0; nti < 2; ++nti)
                        acc[mtl][nti] = __builtin_amdgcn_mfma_f32_16x16x32_bf16(wf[nti], xf[mtl], acc[mtl][nti], 0, 0, 0);
            }
#pragma unroll
            for (int mtl = 0; mtl < 4; ++mtl)
#pragma unroll
                for (int nti = 0; nti < 2; ++nti) {
                    bf16x4 p;
#pragma unroll
                    for (int r = 0; r < 4; ++r) p[r] = (short)f2bf(acc[mtl][nti][r]);
                    *(bf16x4*)(f2s + (size_t)(s * 64 + mtl * 16 + lr) * 264 + w * 32 + nti * 16 + lq * 4) = p;
                }
            __syncthreads();
        }
    }

    // ---- fg = column max per group (4 groups x 256 cols) ----
    for (int idx = t; idx < 1024; idx += 512) {
        int g = idx >> 8, n = idx & 255;
        float m = -3.9e38f;
#pragma unroll
        for (int k = 0; k < 32; ++k) m = fmaxf(m, bf2f(f2s[(size_t)(g * 32 + k) * 264 + n]));
        fgs[g * 256 + n] = f2bf(m);
    }
    __syncthreads();

    auto ldw3 = [&](int cb_, int ks_) -> bf16x8 {
        return *(const bf16x8*)(w3t + (size_t)(cb_ * 128 + w * 16 + lr) * 512 + ks_ * 32 + lq * 8);
    };
    auto ldw4 = [&](int cb_, int kl_, int nti_) -> bf16x8 {
        return *(const bf16x8*)(w4t + (size_t)(w * 48 + nti_ * 16 + lr) * 512 + cb_ * 128 + kl_ * 32 + lq * 8);
    };

    f32x4 acc4[3][8];
#pragma unroll
    for (int nti = 0; nti < 3; ++nti) {
        f32x4 bq = *(const f32x4*)(b4 + w * 48 + nti * 16 + lq * 4);
#pragma unroll
        for (int mt = 0; mt < 8; ++mt) acc4[nti][mt] = bq;
    }

    for (int cb = 0; cb < 4; ++cb) {
        // depth-4 weight pipeline over the unified ks stream 0..16
        bf16x8 wp[4];
#pragma unroll
        for (int kp = 0; kp < 4; ++kp) wp[kp] = ldw3(cb, kp);

        // H phase: ks 0..8, A rows = group fg vectors (rows identical within group)
        f32x4 accH = *(const f32x4*)(b3 + cb * 128 + w * 16 + lq * 4);
#pragma unroll
        for (int ks = 0; ks < 8; ++ks) {
            bf16x8 wf = wp[ks & 3];
            wp[ks & 3] = ldw3(cb, ks + 4);
            bf16x8 xfh = *(const bf16x8*)(fgs + (lr & 3) * 256 + ks * 32 + lq * 8);
            accH = __builtin_amdgcn_mfma_f32_16x16x32_bf16(wf, xfh, accH, 0, 0, 0);
        }
        // broadcast h rows (groups) into acc3 init
        f32x4 acc3[8];
#pragma unroll
        for (int mt = 0; mt < 8; ++mt) {
            const int gg = mt >> 1;
#pragma unroll
            for (int r = 0; r < 4; ++r)
                acc3[mt][r] = __shfl(accH[r], (lane & 48) | gg, 64);
        }
        // main phase: ks 8..16, f2 rows
#pragma unroll
        for (int ks = 8; ks < 16; ++ks) {
            bf16x8 wf = wp[ks & 3];
            if (ks + 4 < 16) wp[ks & 3] = ldw3(cb, ks + 4);
#pragma unroll
            for (int mt = 0; mt < 8; ++mt) {
                bf16x8 xf = *(const bf16x8*)(f2s + (size_t)(mt * 16 + lr) * 264 + (ks - 8) * 32 + lq * 8);
                acc3[mt] = __builtin_amdgcn_mfma_f32_16x16x32_bf16(wf, xf, acc3[mt], 0, 0, 0);
            }
        }
        // bn2 + relu -> f3c
        {
            const int nq = cb * 128 + w * 16 + lq * 4;
            f32x4 g2q = *(const f32x4*)(g2 + nq);
            f32x4 v2q = *(const f32x4*)(v2 + nq);
            f32x4 m2q = *(const f32x4*)(m2 + nq);
            f32x4 beq = *(const f32x4*)(be2 + nq);
            f32x4 sc, sh;
#pragma unroll
            for (int r = 0; r < 4; ++r) {
                sc[r] = g2q[r] * rsqrtf(v2q[r] + EPSF);
                sh[r] = beq[r] - m2q[r] * sc[r];
            }
#pragma unroll
            for (int mt = 0; mt < 8; ++mt) {
                bf16x4 p;
#pragma unroll
                for (int r = 0; r < 4; ++r)
                    p[r] = (short)f2bf(fmaxf(acc3[mt][r] * sc[r] + sh[r], 0.0f));
                *(bf16x4*)(f3c + (size_t)(mt * 16 + lr) * 136 + w * 16 + lq * 4) = p;
            }
        }
        // preload L4 kl=0 weights above the barrier (global, f3c-independent)
        bf16x8 w4a[3];
#pragma unroll
        for (int nti = 0; nti < 3; ++nti) w4a[nti] = ldw4(cb, 0, nti);
        __syncthreads();
        // L4 partial over this chunk's 128 k
        for (int kl = 0; kl < 4; ++kl) {
            bf16x8 w4n[3];
            if (kl < 3) {
#pragma unroll
                for (int nti = 0; nti < 3; ++nti) w4n[nti] = ldw4(cb, kl + 1, nti);
            }
            bf16x8 xf8[8];
#pragma unroll
            for (int mt = 0; mt < 8; ++mt)
                xf8[mt] = *(const bf16x8*)(f3c + (size_t)(mt * 16 + lr) * 136 + kl * 32 + lq * 8);
#pragma unroll
            for (int nti = 0; nti < 3; ++nti)
#pragma unroll
                for (int mt = 0; mt < 8; ++mt)
                    acc4[nti][mt] = __builtin_amdgcn_mfma_f32_16x16x32_bf16(w4a[nti], xf8[mt], acc4[nti][mt], 0, 0, 0);
            if (kl < 3) {
#pragma unroll
                for (int nti = 0; nti < 3; ++nti) w4a[nti] = w4n[nti];
            }
        }
        __syncthreads();
    }

    // ---- max over 32 points per group, write out ----
#pragma unroll
    for (int nti = 0; nti < 3; ++nti) {
#pragma unroll
        for (int gg = 0; gg < 4; ++gg) {
            f32x4 vv;
#pragma unroll
            for (int r = 0; r < 4; ++r)
                vv[r] = fmaxf(acc4[nti][2 * gg][r], acc4[nti][2 * gg + 1][r]);
#pragma unroll
            for (int mask = 1; mask <= 8; mask <<= 1) {
#pragma unroll
                for (int r = 0; r < 4; ++r)
                    vv[r] = fmaxf(vv[r], __shfl_xor(vv[r], mask, 64));
            }
            if (lr == 0)
                *(f32x4*)(out + (size_t)(g0 + gg) * 384 + w * 48 + nti * 16 + lq * 4) = vv;
        }
    }
}

extern "C" void kernel_launch(void* const* d_in, const int* in_sizes, int n_in,
                              void* d_out, int out_size, void* d_ws, size_t ws_size,
                              hipStream_t stream) {
    const float* pcd = (const float*)d_in[0];
    const float* w1 = (const float*)d_in[2];
    const float* b1 = (const float*)d_in[3];
    const float* g1 = (const float*)d_in[4];
    const float* be1 = (const float*)d_in[5];
    const float* m1 = (const float*)d_in[6];
    const float* v1 = (const float*)d_in[7];
    const float* w2 = (const float*)d_in[8];
    const float* b2 = (const float*)d_in[9];
    const float* w3 = (const float*)d_in[10];
    const float* b3 = (const float*)d_in[11];
    const float* g2 = (const float*)d_in[12];
    const float* be2 = (const float*)d_in[13];
    const float* m2 = (const float*)d_in[14];
    const float* v2 = (const float*)d_in[15];
    const float* w4 = (const float*)d_in[16];
    const float* b4 = (const float*)d_in[17];
    float* out = (float*)d_out;

    char* ws = (char*)d_ws;
    int* cidx = (int*)ws;                                   // 8192 B
    float* xg = (float*)(ws + 8192);                        // 1,572,864 B
    unsigned short* w2t = (unsigned short*)(ws + 1581056);  // 65,536 B
    unsigned short* w3t = (unsigned short*)(ws + 1646592);  // 524,288 B
    unsigned short* w4t = (unsigned short*)(ws + 2170880);  // 393,216 B

    prep_kernel<<<120, 256, 0, stream>>>(w2, w3, w4, w2t, w3t, w4t);
    fps_kernel<<<32, 1024, 0, stream>>>(pcd, cidx);
    knn_kernel<<<2048, 64, 0, stream>>>(pcd, cidx, xg);
    mlp_mfma_kernel<<<512, 512, 0, stream>>>(xg, w1, b1, g1, be1, m1, v1,
                                             w2t, b2, w3t, b3, g2, be2, m2, v2,
                                             w4t, b4, out);
}

// Round 8
// 392.588 us; speedup vs baseline: 4.2723x; 1.0733x over previous
//
#include <hip/hip_runtime.h>
#include <hip/hip_bf16.h>
#include <math.h>

#define N_PTS 16384
#define NUM_G 64
#define GRP_K 32
#define EPSF 1e-5f

typedef short bf16x8 __attribute__((ext_vector_type(8)));
typedef short bf16x4 __attribute__((ext_vector_type(4)));
typedef float f32x4 __attribute__((ext_vector_type(4)));
typedef unsigned short u16x8 __attribute__((ext_vector_type(8)));

__device__ __forceinline__ unsigned short f2bf(float x) {
    unsigned int u = __builtin_bit_cast(unsigned int, x);
    u = (u + 0x7FFFu + ((u >> 16) & 1u)) >> 16;
    return (unsigned short)u;
}
__device__ __forceinline__ float bf2f(unsigned short h) {
    unsigned int u = ((unsigned int)h) << 16;
    return __builtin_bit_cast(float, u);
}

// ---------------- Phase A: farthest point sampling (unchanged) ----------------
__global__ __launch_bounds__(1024, 4) void fps_kernel(const float* __restrict__ pcd,
                                                      int* __restrict__ cidx) {
    const int b = blockIdx.x;
    const int tid = threadIdx.x;
    const int lane = tid & 63, w = tid >> 6;
    const float* xb = pcd + (size_t)b * 6 * N_PTS;

    float px[16], py[16], pz[16], dist[16];
#pragma unroll
    for (int j = 0; j < 16; ++j) {
        int p = tid + 1024 * j;
        px[j] = xb[p];
        py[j] = xb[N_PTS + p];
        pz[j] = xb[2 * N_PTS + p];
        dist[j] = 1e10f;
    }

    __shared__ unsigned long long wk[2][16];
    __shared__ int clds[NUM_G];

    int far = 0;
    for (int it = 0; it < NUM_G; ++it) {
        int fu = __builtin_amdgcn_readfirstlane(far);
        float cx = xb[fu], cy = xb[N_PTS + fu], cz = xb[2 * N_PTS + fu];
        if (tid == 0) clds[it] = fu;

        unsigned long long kmax = 0ull;
#pragma unroll
        for (int j = 0; j < 16; ++j) {
            float dx = __fsub_rn(px[j], cx);
            float dy = __fsub_rn(py[j], cy);
            float dz = __fsub_rn(pz[j], cz);
            float d = __fadd_rn(__fadd_rn(__fmul_rn(dx, dx), __fmul_rn(dy, dy)),
                                __fmul_rn(dz, dz));
            dist[j] = fminf(dist[j], d);
            unsigned long long key =
                ((unsigned long long)__float_as_uint(dist[j]) << 32) |
                (unsigned int)~(tid + 1024 * j);
            kmax = kmax > key ? kmax : key;
        }
#pragma unroll
        for (int m = 1; m < 64; m <<= 1) {
            unsigned long long o = __shfl_xor(kmax, m, 64);
            kmax = o > kmax ? o : kmax;
        }
        if (lane == 0) wk[it & 1][w] = kmax;
        __syncthreads();
        unsigned long long k2 = (lane < 16) ? wk[it & 1][lane] : 0ull;
#pragma unroll
        for (int m = 1; m < 16; m <<= 1) {
            unsigned long long o = __shfl_xor(k2, m, 64);
            k2 = o > k2 ? o : k2;
        }
        k2 = __shfl(k2, 0, 64);
        far = (int)(~(unsigned int)k2);
    }
    __syncthreads();
    if (tid < NUM_G) cidx[b * NUM_G + tid] = clds[tid];
}

// ---------------- Phase B: KNN — one wave per group, XCD-swizzled ----------------
// blockIdx = g*32 + b  =>  for fixed batch b, blockIdx % 8 == b % 8: all 64 blocks
// of a batch dispatch to ONE XCD (round-robin), whose L2 working set is then
// 4 batches x 196 KB = 786 KB << 4 MB. Fixes R7's 281 MB HBM re-fetch.
__device__ __forceinline__ void merge2(unsigned long long& a1, unsigned long long& a2,
                                       unsigned long long o1, unsigned long long o2) {
    unsigned long long hi = a1 > o1 ? a1 : o1;
    a1 = a1 < o1 ? a1 : o1;
    unsigned long long lo2 = a2 < o2 ? a2 : o2;
    a2 = hi < lo2 ? hi : lo2;
}
__device__ __forceinline__ void top2upd(unsigned long long& b1, unsigned long long& b2,
                                        unsigned long long v) {
    unsigned long long hi = b1 > v ? b1 : v;
    b1 = b1 < v ? b1 : v;
    b2 = b2 < hi ? b2 : hi;
}

__global__ __launch_bounds__(64, 4) void knn_kernel(const float* __restrict__ pcd,
                                                    const int* __restrict__ cidx,
                                                    float* __restrict__ xout) {
    const int b = blockIdx.x & 31;       // XCD-locality swizzle
    const int g = blockIdx.x >> 5;
    const int bg_out = b * NUM_G + g;    // canonical (b,g) index for cidx/xout
    const int lane = threadIdx.x;
    const float* xb = pcd + (size_t)b * 6 * N_PTS;

    const int ci = cidx[bg_out];
    const float cx = xb[ci], cy = xb[N_PTS + ci], cz = xb[2 * N_PTS + ci];

    const float4* X4 = (const float4*)xb;
    const float4* Y4 = (const float4*)(xb + N_PTS);
    const float4* Z4 = (const float4*)(xb + 2 * N_PTS);

    unsigned long long b1 = ~0ull, b2 = ~0ull;
#pragma unroll 8
    for (int j = 0; j < 64; ++j) {
        float4 xv = X4[j * 64 + lane];
        float4 yv = Y4[j * 64 + lane];
        float4 zv = Z4[j * 64 + lane];
        float xs4[4] = {xv.x, xv.y, xv.z, xv.w};
        float ys4[4] = {yv.x, yv.y, yv.z, yv.w};
        float zs4[4] = {zv.x, zv.y, zv.z, zv.w};
        unsigned int p = (unsigned int)(j * 256 + lane * 4);
#pragma unroll
        for (int u = 0; u < 4; ++u) {
            float dx = __fsub_rn(cx, xs4[u]);
            float dy = __fsub_rn(cy, ys4[u]);
            float dz = __fsub_rn(cz, zs4[u]);
            float d = __fadd_rn(__fadd_rn(__fmul_rn(dx, dx), __fmul_rn(dy, dy)),
                                __fmul_rn(dz, dz));
            top2upd(b1, b2, ((unsigned long long)__float_as_uint(d) << 32) | (p + u));
        }
    }

    unsigned long long rm0 = 0, rm1 = 0, rm2 = 0, rm3 = 0;
    __shared__ int knn_sh[GRP_K];

    for (int r = 0; r < 16; ++r) {
        unsigned long long r1 = b1, r2 = b2;
#pragma unroll
        for (int m = 1; m < 64; m <<= 1) {
            unsigned long long o1 = __shfl_xor(r1, m, 64);
            unsigned long long o2 = __shfl_xor(r2, m, 64);
            merge2(r1, r2, o1, o2);
        }
        const int q1 = (int)(unsigned int)r1;
        const int q2 = (int)(unsigned int)r2;
        if (lane == 0) { knn_sh[2 * r] = q1; knn_sh[2 * r + 1] = q2; }

        const int wl1 = (q1 >> 2) & 63, s1 = ((q1 >> 8) << 2) | (q1 & 3);
        const int wl2 = (q2 >> 2) & 63, s2 = ((q2 >> 8) << 2) | (q2 & 3);
        {
            unsigned long long bit1 = 1ull << (s1 & 63);
            unsigned long long bit2 = 1ull << (s2 & 63);
            if (lane == wl1) {
                rm0 |= ((s1 >> 6) == 0) ? bit1 : 0ull;
                rm1 |= ((s1 >> 6) == 1) ? bit1 : 0ull;
                rm2 |= ((s1 >> 6) == 2) ? bit1 : 0ull;
                rm3 |= ((s1 >> 6) == 3) ? bit1 : 0ull;
            }
            if (lane == wl2) {
                rm0 |= ((s2 >> 6) == 0) ? bit2 : 0ull;
                rm1 |= ((s2 >> 6) == 1) ? bit2 : 0ull;
                rm2 |= ((s2 >> 6) == 2) ? bit2 : 0ull;
                rm3 |= ((s2 >> 6) == 3) ? bit2 : 0ull;
            }
        }

#pragma unroll 1
        for (int s = 0; s < 2; ++s) {
            if (s == 1 && wl2 == wl1) break;
            const int wl = s ? wl2 : wl1;
            unsigned long long m0 = __shfl(rm0, wl, 64);
            unsigned long long m1 = __shfl(rm1, wl, 64);
            unsigned long long m2 = __shfl(rm2, wl, 64);
            unsigned long long m3 = __shfl(rm3, wl, 64);
            const int wsel = lane >> 4;
            unsigned long long mw = wsel == 0 ? m0 : (wsel == 1 ? m1 : (wsel == 2 ? m2 : m3));
            float4 xv = X4[lane * 64 + wl];
            float4 yv = Y4[lane * 64 + wl];
            float4 zv = Z4[lane * 64 + wl];
            float xs4[4] = {xv.x, xv.y, xv.z, xv.w};
            float ys4[4] = {yv.x, yv.y, yv.z, yv.w};
            float zs4[4] = {zv.x, zv.y, zv.z, zv.w};
            unsigned int p = (unsigned int)(lane * 256 + wl * 4);
            unsigned long long s1v = ~0ull, s2v = ~0ull;
#pragma unroll
            for (int u = 0; u < 4; ++u) {
                float dx = __fsub_rn(cx, xs4[u]);
                float dy = __fsub_rn(cy, ys4[u]);
                float dz = __fsub_rn(cz, zs4[u]);
                float d = __fadd_rn(__fadd_rn(__fmul_rn(dx, dx), __fmul_rn(dy, dy)),
                                    __fmul_rn(dz, dz));
                unsigned long long v =
                    ((unsigned long long)__float_as_uint(d) << 32) | (p + u);
                if ((mw >> (((lane & 15) << 2) | u)) & 1ull) v = ~0ull;
                top2upd(s1v, s2v, v);
            }
#pragma unroll
            for (int m = 1; m < 64; m <<= 1) {
                unsigned long long o1 = __shfl_xor(s1v, m, 64);
                unsigned long long o2 = __shfl_xor(s2v, m, 64);
                merge2(s1v, s2v, o1, o2);
            }
            if (lane == wl) { b1 = s1v; b2 = s2v; }
        }
    }
    __syncthreads();

#pragma unroll
    for (int t = 0; t < 3; ++t) {
        int i = lane + 64 * t;
        int k = i / 6, c = i % 6;
        int p = knn_sh[k];
        float val = xb[c * N_PTS + p];
        if (c == 0) val = __fsub_rn(val, cx);
        else if (c == 1) val = __fsub_rn(val, cy);
        else if (c == 2) val = __fsub_rn(val, cz);
        xout[(size_t)bg_out * 192 + i] = val;
    }
}

// ---------------- Prep: LDS-tiled transpose fp32[K][N] -> bf16[N][K] (unchanged) ----------------
__global__ __launch_bounds__(256) void prep_kernel(const float* __restrict__ w2,
                                                   const float* __restrict__ w3,
                                                   const float* __restrict__ w4,
                                                   unsigned short* __restrict__ w2t,
                                                   unsigned short* __restrict__ w3t,
                                                   unsigned short* __restrict__ w4t) {
    const int tile = blockIdx.x;
    const float* src;
    unsigned short* dst;
    int K, N, kt, nt;
    if (tile < 8) {
        src = w2; dst = w2t; K = 128; N = 256;
        kt = tile >> 2; nt = tile & 3;
    } else if (tile < 72) {
        int t2 = tile - 8;
        src = w3; dst = w3t; K = 512; N = 512;
        kt = t2 >> 3; nt = t2 & 7;
    } else {
        int t2 = tile - 72;
        src = w4; dst = w4t; K = 512; N = 384;
        kt = t2 / 6; nt = t2 % 6;
    }
    const int k0 = kt * 64, n0 = nt * 64;

    __shared__ unsigned short tl[64][72];

    const int c = threadIdx.x & 63, r0 = threadIdx.x >> 6;
#pragma unroll
    for (int i = 0; i < 16; ++i) {
        int r = 4 * i + r0;
        tl[r][c] = f2bf(src[(size_t)(k0 + r) * N + n0 + c]);
    }
    __syncthreads();

    const int n = threadIdx.x >> 2;
    const int kc = (threadIdx.x & 3) * 16;
    u16x8 v0, v1;
#pragma unroll
    for (int j = 0; j < 8; ++j) {
        v0[j] = tl[kc + j][n];
        v1[j] = tl[kc + 8 + j][n];
    }
    *(u16x8*)(dst + (size_t)(n0 + n) * K + k0 + kc) = v0;
    *(u16x8*)(dst + (size_t)(n0 + n) * K + k0 + kc + 8) = v1;
}

// ---------------- Phase C: M=128 mega-block MFMA MLP (unchanged from R6) ----------------
__global__ __launch_bounds__(512, 2) void mlp_mfma_kernel(
    const float* __restrict__ xin,
    const float* __restrict__ w1, const float* __restrict__ b1,
    const float* __restrict__ g1, const float* __restrict__ be1,
    const float* __restrict__ m1, const float* __restrict__ v1,
    const unsigned short* __restrict__ w2t, const float* __restrict__ b2,
    const unsigned short* __restrict__ w3t, const float* __restrict__ b3,
    const float* __restrict__ g2, const float* __restrict__ be2,
    const float* __restrict__ m2, const float* __restrict__ v2,
    const unsigned short* __restrict__ w4t, const float* __restrict__ b4,
    float* __restrict__ out) {
    const int g0 = blockIdx.x * 4;
    const int t = threadIdx.x;
    const int w = t >> 6;
    const int lane = t & 63;
    const int lr = lane & 15;
    const int lq = lane >> 4;

    __shared__ __align__(16) unsigned short f2s[128 * 264];
    __shared__ __align__(16) unsigned short ubuf[128 * 136];
    __shared__ __align__(16) unsigned short fgs[4 * 256];
    __shared__ float xs[4 * 192];

    unsigned short* f1s = ubuf;
    unsigned short* f3c = ubuf;

    for (int i = t; i < 768; i += 512) xs[i] = xin[(size_t)g0 * 192 + i];
    __syncthreads();

    {
        const int d = t & 127, rq = t >> 7;
        float wv[6];
#pragma unroll
        for (int c = 0; c < 6; ++c) wv[c] = w1[c * 128 + d];
        const float sc = g1[d] * rsqrtf(v1[d] + EPSF);
        const float sh = be1[d] - m1[d] * sc;
        const float bias = b1[d];

        for (int s = 0; s < 2; ++s) {
#pragma unroll
            for (int j = 0; j < 16; ++j) {
                const int rl = rq * 16 + j;
                const int gr = s * 64 + rl;
                const int g = gr >> 5, k = gr & 31;
                float acc = bias;
#pragma unroll
                for (int c = 0; c < 6; ++c) acc += xs[g * 192 + k * 6 + c] * wv[c];
                f1s[rl * 136 + d] = f2bf(fmaxf(acc * sc + sh, 0.0f));
            }
            __syncthreads();
            f32x4 acc[4][2];
#pragma unroll
            for (int nti = 0; nti < 2; ++nti) {
                f32x4 bq = *(const f32x4*)(b2 + w * 32 + nti * 16 + lq * 4);
#pragma unroll
                for (int mtl = 0; mtl < 4; ++mtl) acc[mtl][nti] = bq;
            }
#pragma unroll
            for (int ks = 0; ks < 4; ++ks) {
                bf16x8 xf[4], wf[2];
#pragma unroll
                for (int mtl = 0; mtl < 4; ++mtl)
                    xf[mtl] = *(const bf16x8*)(f1s + (mtl * 16 + lr) * 136 + ks * 32 + lq * 8);
#pragma unroll
                for (int nti = 0; nti < 2; ++nti)
                    wf[nti] = *(const bf16x8*)(w2t + (w * 32 + nti * 16 + lr) * 128 + ks * 32 + lq * 8);
#pragma unroll
                for (int mtl = 0; mtl < 4; ++mtl)
#pragma unroll
                    for (int nti = 0; nti < 2; ++nti)
                        acc[mtl][nti] = __builtin_amdgcn_mfma_f32_16x16x32_bf16(wf[nti], xf[mtl], acc[mtl][nti], 0, 0, 0);
            }
#pragma unroll
            for (int mtl = 0; mtl < 4; ++mtl)
#pragma unroll
                for (int nti = 0; nti < 2; ++nti) {
                    bf16x4 p;
#pragma unroll
                    for (int r = 0; r < 4; ++r) p[r] = (short)f2bf(acc[mtl][nti][r]);
                    *(bf16x4*)(f2s + (size_t)(s * 64 + mtl * 16 + lr) * 264 + w * 32 + nti * 16 + lq * 4) = p;
                }
            __syncthreads();
        }
    }

    for (int idx = t; idx < 1024; idx += 512) {
        int g = idx >> 8, n = idx & 255;
        float m = -3.9e38f;
#pragma unroll
        for (int k = 0; k < 32; ++k) m = fmaxf(m, bf2f(f2s[(size_t)(g * 32 + k) * 264 + n]));
        fgs[g * 256 + n] = f2bf(m);
    }
    __syncthreads();

    auto ldw3 = [&](int cb_, int ks_) -> bf16x8 {
        return *(const bf16x8*)(w3t + (size_t)(cb_ * 128 + w * 16 + lr) * 512 + ks_ * 32 + lq * 8);
    };
    auto ldw4 = [&](int cb_, int kl_, int nti_) -> bf16x8 {
        return *(const bf16x8*)(w4t + (size_t)(w * 48 + nti_ * 16 + lr) * 512 + cb_ * 128 + kl_ * 32 + lq * 8);
    };

    f32x4 acc4[3][8];
#pragma unroll
    for (int nti = 0; nti < 3; ++nti) {
        f32x4 bq = *(const f32x4*)(b4 + w * 48 + nti * 16 + lq * 4);
#pragma unroll
        for (int mt = 0; mt < 8; ++mt) acc4[nti][mt] = bq;
    }

    for (int cb = 0; cb < 4; ++cb) {
        bf16x8 wp[4];
#pragma unroll
        for (int kp = 0; kp < 4; ++kp) wp[kp] = ldw3(cb, kp);

        f32x4 accH = *(const f32x4*)(b3 + cb * 128 + w * 16 + lq * 4);
#pragma unroll
        for (int ks = 0; ks < 8; ++ks) {
            bf16x8 wf = wp[ks & 3];
            wp[ks & 3] = ldw3(cb, ks + 4);
            bf16x8 xfh = *(const bf16x8*)(fgs + (lr & 3) * 256 + ks * 32 + lq * 8);
            accH = __builtin_amdgcn_mfma_f32_16x16x32_bf16(wf, xfh, accH, 0, 0, 0);
        }
        f32x4 acc3[8];
#pragma unroll
        for (int mt = 0; mt < 8; ++mt) {
            const int gg = mt >> 1;
#pragma unroll
            for (int r = 0; r < 4; ++r)
                acc3[mt][r] = __shfl(accH[r], (lane & 48) | gg, 64);
        }
#pragma unroll
        for (int ks = 8; ks < 16; ++ks) {
            bf16x8 wf = wp[ks & 3];
            if (ks + 4 < 16) wp[ks & 3] = ldw3(cb, ks + 4);
#pragma unroll
            for (int mt = 0; mt < 8; ++mt) {
                bf16x8 xf = *(const bf16x8*)(f2s + (size_t)(mt * 16 + lr) * 264 + (ks - 8) * 32 + lq * 8);
                acc3[mt] = __builtin_amdgcn_mfma_f32_16x16x32_bf16(wf, xf, acc3[mt], 0, 0, 0);
            }
        }
        {
            const int nq = cb * 128 + w * 16 + lq * 4;
            f32x4 g2q = *(const f32x4*)(g2 + nq);
            f32x4 v2q = *(const f32x4*)(v2 + nq);
            f32x4 m2q = *(const f32x4*)(m2 + nq);
            f32x4 beq = *(const f32x4*)(be2 + nq);
            f32x4 sc, sh;
#pragma unroll
            for (int r = 0; r < 4; ++r) {
                sc[r] = g2q[r] * rsqrtf(v2q[r] + EPSF);
                sh[r] = beq[r] - m2q[r] * sc[r];
            }
#pragma unroll
            for (int mt = 0; mt < 8; ++mt) {
                bf16x4 p;
#pragma unroll
                for (int r = 0; r < 4; ++r)
                    p[r] = (short)f2bf(fmaxf(acc3[mt][r] * sc[r] + sh[r], 0.0f));
                *(bf16x4*)(f3c + (size_t)(mt * 16 + lr) * 136 + w * 16 + lq * 4) = p;
            }
        }
        bf16x8 w4a[3];
#pragma unroll
        for (int nti = 0; nti < 3; ++nti) w4a[nti] = ldw4(cb, 0, nti);
        __syncthreads();
        for (int kl = 0; kl < 4; ++kl) {
            bf16x8 w4n[3];
            if (kl < 3) {
#pragma unroll
                for (int nti = 0; nti < 3; ++nti) w4n[nti] = ldw4(cb, kl + 1, nti);
            }
            bf16x8 xf8[8];
#pragma unroll
            for (int mt = 0; mt < 8; ++mt)
                xf8[mt] = *(const bf16x8*)(f3c + (size_t)(mt * 16 + lr) * 136 + kl * 32 + lq * 8);
#pragma unroll
            for (int nti = 0; nti < 3; ++nti)
#pragma unroll
                for (int mt = 0; mt < 8; ++mt)
                    acc4[nti][mt] = __builtin_amdgcn_mfma_f32_16x16x32_bf16(w4a[nti], xf8[mt], acc4[nti][mt], 0, 0, 0);
            if (kl < 3) {
#pragma unroll
                for (int nti = 0; nti < 3; ++nti) w4a[nti] = w4n[nti];
            }
        }
        __syncthreads();
    }

#pragma unroll
    for (int nti = 0; nti < 3; ++nti) {
#pragma unroll
        for (int gg = 0; gg < 4; ++gg) {
            f32x4 vv;
#pragma unroll
            for (int r = 0; r < 4; ++r)
                vv[r] = fmaxf(acc4[nti][2 * gg][r], acc4[nti][2 * gg + 1][r]);
#pragma unroll
            for (int mask = 1; mask <= 8; mask <<= 1) {
#pragma unroll
                for (int r = 0; r < 4; ++r)
                    vv[r] = fmaxf(vv[r], __shfl_xor(vv[r], mask, 64));
            }
            if (lr == 0)
                *(f32x4*)(out + (size_t)(g0 + gg) * 384 + w * 48 + nti * 16 + lq * 4) = vv;
        }
    }
}

extern "C" void kernel_launch(void* const* d_in, const int* in_sizes, int n_in,
                              void* d_out, int out_size, void* d_ws, size_t ws_size,
                              hipStream_t stream) {
    const float* pcd = (const float*)d_in[0];
    const float* w1 = (const float*)d_in[2];
    const float* b1 = (const float*)d_in[3];
    const float* g1 = (const float*)d_in[4];
    const float* be1 = (const float*)d_in[5];
    const float* m1 = (const float*)d_in[6];
    const float* v1 = (const float*)d_in[7];
    const float* w2 = (const float*)d_in[8];
    const float* b2 = (const float*)d_in[9];
    const float* w3 = (const float*)d_in[10];
    const float* b3 = (const float*)d_in[11];
    const float* g2 = (const float*)d_in[12];
    const float* be2 = (const float*)d_in[13];
    const float* m2 = (const float*)d_in[14];
    const float* v2 = (const float*)d_in[15];
    const float* w4 = (const float*)d_in[16];
    const float* b4 = (const float*)d_in[17];
    float* out = (float*)d_out;

    char* ws = (char*)d_ws;
    int* cidx = (int*)ws;                                   // 8192 B
    float* xg = (float*)(ws + 8192);                        // 1,572,864 B
    unsigned short* w2t = (unsigned short*)(ws + 1581056);  // 65,536 B
    unsigned short* w3t = (unsigned short*)(ws + 1646592);  // 524,288 B
    unsigned short* w4t = (unsigned short*)(ws + 2170880);  // 393,216 B

    prep_kernel<<<120, 256, 0, stream>>>(w2, w3, w4, w2t, w3t, w4t);
    fps_kernel<<<32, 1024, 0, stream>>>(pcd, cidx);
    knn_kernel<<<2048, 64, 0, stream>>>(pcd, cidx, xg);
    mlp_mfma_kernel<<<512, 512, 0, stream>>>(xg, w1, b1, g1, be1, m1, v1,
                                             w2t, b2, w3t, b3, g2, be2, m2, v2,
                                             w4t, b4, out);
}

// Round 9
// 388.453 us; speedup vs baseline: 4.3178x; 1.0106x over previous
//
#include <hip/hip_runtime.h>
#include <hip/hip_bf16.h>
#include <math.h>

#define N_PTS 16384
#define NUM_G 64
#define GRP_K 32
#define EPSF 1e-5f

typedef short bf16x8 __attribute__((ext_vector_type(8)));
typedef short bf16x4 __attribute__((ext_vector_type(4)));
typedef float f32x4 __attribute__((ext_vector_type(4)));
typedef unsigned short u16x8 __attribute__((ext_vector_type(8)));

__device__ __forceinline__ unsigned short f2bf(float x) {
    unsigned int u = __builtin_bit_cast(unsigned int, x);
    u = (u + 0x7FFFu + ((u >> 16) & 1u)) >> 16;
    return (unsigned short)u;
}
__device__ __forceinline__ float bf2f(unsigned short h) {
    unsigned int u = ((unsigned int)h) << 16;
    return __builtin_bit_cast(float, u);
}

// ---------------- Phase A: farthest point sampling ----------------
// waves_per_eu(4,4): min AND max 4 waves/EU -> 128-VGPR budget, so the
// px/py/pz/dist[16] arrays (64 regs) stay in registers. R4-R8 showed the
// compiler voluntarily targeting 8 waves/EU (VGPR_Count=52/60 => scratch spill).
__global__ __launch_bounds__(1024)
__attribute__((amdgpu_waves_per_eu(4, 4)))
void fps_kernel(const float* __restrict__ pcd, int* __restrict__ cidx) {
    const int b = blockIdx.x;
    const int tid = threadIdx.x;
    const int lane = tid & 63, w = tid >> 6;
    const float* xb = pcd + (size_t)b * 6 * N_PTS;

    float px[16], py[16], pz[16], dist[16];
#pragma unroll
    for (int j = 0; j < 16; ++j) {
        int p = tid + 1024 * j;
        px[j] = xb[p];
        py[j] = xb[N_PTS + p];
        pz[j] = xb[2 * N_PTS + p];
        dist[j] = 1e10f;
    }

    __shared__ unsigned long long wk[2][16];
    __shared__ int clds[NUM_G];

    int far = 0;
    for (int it = 0; it < NUM_G; ++it) {
        int fu = __builtin_amdgcn_readfirstlane(far);
        float cx = xb[fu], cy = xb[N_PTS + fu], cz = xb[2 * N_PTS + fu];
        if (tid == 0) clds[it] = fu;

        unsigned long long kmax = 0ull;
#pragma unroll
        for (int j = 0; j < 16; ++j) {
            float dx = __fsub_rn(px[j], cx);
            float dy = __fsub_rn(py[j], cy);
            float dz = __fsub_rn(pz[j], cz);
            float d = __fadd_rn(__fadd_rn(__fmul_rn(dx, dx), __fmul_rn(dy, dy)),
                                __fmul_rn(dz, dz));
            dist[j] = fminf(dist[j], d);
            unsigned long long key =
                ((unsigned long long)__float_as_uint(dist[j]) << 32) |
                (unsigned int)~(tid + 1024 * j);
            kmax = kmax > key ? kmax : key;
        }
#pragma unroll
        for (int m = 1; m < 64; m <<= 1) {
            unsigned long long o = __shfl_xor(kmax, m, 64);
            kmax = o > kmax ? o : kmax;
        }
        if (lane == 0) wk[it & 1][w] = kmax;
        __syncthreads();
        unsigned long long k2 = (lane < 16) ? wk[it & 1][lane] : 0ull;
#pragma unroll
        for (int m = 1; m < 16; m <<= 1) {
            unsigned long long o = __shfl_xor(k2, m, 64);
            k2 = o > k2 ? o : k2;
        }
        k2 = __shfl(k2, 0, 64);
        far = (int)(~(unsigned int)k2);
    }
    __syncthreads();
    if (tid < NUM_G) cidx[b * NUM_G + tid] = clds[tid];
}

// ---------------- Phase B: KNN — one wave per group, XCD-swizzled ----------------
// waves_per_eu(4,4): stops the 8-waves/EU register-budget spill (R7 counters:
// WRITE_SIZE 53 MB vs 1.57 MB of real output = ~50 MB scratch writes/dispatch).
__device__ __forceinline__ void merge2(unsigned long long& a1, unsigned long long& a2,
                                       unsigned long long o1, unsigned long long o2) {
    unsigned long long hi = a1 > o1 ? a1 : o1;
    a1 = a1 < o1 ? a1 : o1;
    unsigned long long lo2 = a2 < o2 ? a2 : o2;
    a2 = hi < lo2 ? hi : lo2;
}
__device__ __forceinline__ void top2upd(unsigned long long& b1, unsigned long long& b2,
                                        unsigned long long v) {
    unsigned long long hi = b1 > v ? b1 : v;
    b1 = b1 < v ? b1 : v;
    b2 = b2 < hi ? b2 : hi;
}

__global__ __launch_bounds__(64)
__attribute__((amdgpu_waves_per_eu(4, 4)))
void knn_kernel(const float* __restrict__ pcd,
                const int* __restrict__ cidx,
                float* __restrict__ xout) {
    const int b = blockIdx.x & 31;       // XCD-locality swizzle
    const int g = blockIdx.x >> 5;
    const int bg_out = b * NUM_G + g;
    const int lane = threadIdx.x;
    const float* xb = pcd + (size_t)b * 6 * N_PTS;

    const int ci = cidx[bg_out];
    const float cx = xb[ci], cy = xb[N_PTS + ci], cz = xb[2 * N_PTS + ci];

    const float4* X4 = (const float4*)xb;
    const float4* Y4 = (const float4*)(xb + N_PTS);
    const float4* Z4 = (const float4*)(xb + 2 * N_PTS);

    unsigned long long b1 = ~0ull, b2 = ~0ull;
#pragma unroll 8
    for (int j = 0; j < 64; ++j) {
        float4 xv = X4[j * 64 + lane];
        float4 yv = Y4[j * 64 + lane];
        float4 zv = Z4[j * 64 + lane];
        float xs4[4] = {xv.x, xv.y, xv.z, xv.w};
        float ys4[4] = {yv.x, yv.y, yv.z, yv.w};
        float zs4[4] = {zv.x, zv.y, zv.z, zv.w};
        unsigned int p = (unsigned int)(j * 256 + lane * 4);
#pragma unroll
        for (int u = 0; u < 4; ++u) {
            float dx = __fsub_rn(cx, xs4[u]);
            float dy = __fsub_rn(cy, ys4[u]);
            float dz = __fsub_rn(cz, zs4[u]);
            float d = __fadd_rn(__fadd_rn(__fmul_rn(dx, dx), __fmul_rn(dy, dy)),
                                __fmul_rn(dz, dz));
            top2upd(b1, b2, ((unsigned long long)__float_as_uint(d) << 32) | (p + u));
        }
    }

    unsigned long long rm0 = 0, rm1 = 0, rm2 = 0, rm3 = 0;
    __shared__ int knn_sh[GRP_K];

    for (int r = 0; r < 16; ++r) {
        unsigned long long r1 = b1, r2 = b2;
#pragma unroll
        for (int m = 1; m < 64; m <<= 1) {
            unsigned long long o1 = __shfl_xor(r1, m, 64);
            unsigned long long o2 = __shfl_xor(r2, m, 64);
            merge2(r1, r2, o1, o2);
        }
        const int q1 = (int)(unsigned int)r1;
        const int q2 = (int)(unsigned int)r2;
        if (lane == 0) { knn_sh[2 * r] = q1; knn_sh[2 * r + 1] = q2; }

        const int wl1 = (q1 >> 2) & 63, s1 = ((q1 >> 8) << 2) | (q1 & 3);
        const int wl2 = (q2 >> 2) & 63, s2 = ((q2 >> 8) << 2) | (q2 & 3);
        {
            unsigned long long bit1 = 1ull << (s1 & 63);
            unsigned long long bit2 = 1ull << (s2 & 63);
            if (lane == wl1) {
                rm0 |= ((s1 >> 6) == 0) ? bit1 : 0ull;
                rm1 |= ((s1 >> 6) == 1) ? bit1 : 0ull;
                rm2 |= ((s1 >> 6) == 2) ? bit1 : 0ull;
                rm3 |= ((s1 >> 6) == 3) ? bit1 : 0ull;
            }
            if (lane == wl2) {
                rm0 |= ((s2 >> 6) == 0) ? bit2 : 0ull;
                rm1 |= ((s2 >> 6) == 1) ? bit2 : 0ull;
                rm2 |= ((s2 >> 6) == 2) ? bit2 : 0ull;
                rm3 |= ((s2 >> 6) == 3) ? bit2 : 0ull;
            }
        }

#pragma unroll 1
        for (int s = 0; s < 2; ++s) {
            if (s == 1 && wl2 == wl1) break;
            const int wl = s ? wl2 : wl1;
            unsigned long long m0 = __shfl(rm0, wl, 64);
            unsigned long long m1 = __shfl(rm1, wl, 64);
            unsigned long long m2 = __shfl(rm2, wl, 64);
            unsigned long long m3 = __shfl(rm3, wl, 64);
            const int wsel = lane >> 4;
            unsigned long long mw = wsel == 0 ? m0 : (wsel == 1 ? m1 : (wsel == 2 ? m2 : m3));
            float4 xv = X4[lane * 64 + wl];
            float4 yv = Y4[lane * 64 + wl];
            float4 zv = Z4[lane * 64 + wl];
            float xs4[4] = {xv.x, xv.y, xv.z, xv.w};
            float ys4[4] = {yv.x, yv.y, yv.z, yv.w};
            float zs4[4] = {zv.x, zv.y, zv.z, zv.w};
            unsigned int p = (unsigned int)(lane * 256 + wl * 4);
            unsigned long long s1v = ~0ull, s2v = ~0ull;
#pragma unroll
            for (int u = 0; u < 4; ++u) {
                float dx = __fsub_rn(cx, xs4[u]);
                float dy = __fsub_rn(cy, ys4[u]);
                float dz = __fsub_rn(cz, zs4[u]);
                float d = __fadd_rn(__fadd_rn(__fmul_rn(dx, dx), __fmul_rn(dy, dy)),
                                    __fmul_rn(dz, dz));
                unsigned long long v =
                    ((unsigned long long)__float_as_uint(d) << 32) | (p + u);
                if ((mw >> (((lane & 15) << 2) | u)) & 1ull) v = ~0ull;
                top2upd(s1v, s2v, v);
            }
#pragma unroll
            for (int m = 1; m < 64; m <<= 1) {
                unsigned long long o1 = __shfl_xor(s1v, m, 64);
                unsigned long long o2 = __shfl_xor(s2v, m, 64);
                merge2(s1v, s2v, o1, o2);
            }
            if (lane == wl) { b1 = s1v; b2 = s2v; }
        }
    }
    __syncthreads();

#pragma unroll
    for (int t = 0; t < 3; ++t) {
        int i = lane + 64 * t;
        int k = i / 6, c = i % 6;
        int p = knn_sh[k];
        float val = xb[c * N_PTS + p];
        if (c == 0) val = __fsub_rn(val, cx);
        else if (c == 1) val = __fsub_rn(val, cy);
        else if (c == 2) val = __fsub_rn(val, cz);
        xout[(size_t)bg_out * 192 + i] = val;
    }
}

// ---------------- Prep: LDS-tiled transpose fp32[K][N] -> bf16[N][K] (unchanged) ----------------
__global__ __launch_bounds__(256) void prep_kernel(const float* __restrict__ w2,
                                                   const float* __restrict__ w3,
                                                   const float* __restrict__ w4,
                                                   unsigned short* __restrict__ w2t,
                                                   unsigned short* __restrict__ w3t,
                                                   unsigned short* __restrict__ w4t) {
    const int tile = blockIdx.x;
    const float* src;
    unsigned short* dst;
    int K, N, kt, nt;
    if (tile < 8) {
        src = w2; dst = w2t; K = 128; N = 256;
        kt = tile >> 2; nt = tile & 3;
    } else if (tile < 72) {
        int t2 = tile - 8;
        src = w3; dst = w3t; K = 512; N = 512;
        kt = t2 >> 3; nt = t2 & 7;
    } else {
        int t2 = tile - 72;
        src = w4; dst = w4t; K = 512; N = 384;
        kt = t2 / 6; nt = t2 % 6;
    }
    const int k0 = kt * 64, n0 = nt * 64;

    __shared__ unsigned short tl[64][72];

    const int c = threadIdx.x & 63, r0 = threadIdx.x >> 6;
#pragma unroll
    for (int i = 0; i < 16; ++i) {
        int r = 4 * i + r0;
        tl[r][c] = f2bf(src[(size_t)(k0 + r) * N + n0 + c]);
    }
    __syncthreads();

    const int n = threadIdx.x >> 2;
    const int kc = (threadIdx.x & 3) * 16;
    u16x8 v0, v1;
#pragma unroll
    for (int j = 0; j < 8; ++j) {
        v0[j] = tl[kc + j][n];
        v1[j] = tl[kc + 8 + j][n];
    }
    *(u16x8*)(dst + (size_t)(n0 + n) * K + k0 + kc) = v0;
    *(u16x8*)(dst + (size_t)(n0 + n) * K + k0 + kc + 8) = v1;
}

// ---------------- Phase C: M=128 mega-block MFMA MLP (unchanged) ----------------
__global__ __launch_bounds__(512, 2) void mlp_mfma_kernel(
    const float* __restrict__ xin,
    const float* __restrict__ w1, const float* __restrict__ b1,
    const float* __restrict__ g1, const float* __restrict__ be1,
    const float* __restrict__ m1, const float* __restrict__ v1,
    const unsigned short* __restrict__ w2t, const float* __restrict__ b2,
    const unsigned short* __restrict__ w3t, const float* __restrict__ b3,
    const float* __restrict__ g2, const float* __restrict__ be2,
    const float* __restrict__ m2, const float* __restrict__ v2,
    const unsigned short* __restrict__ w4t, const float* __restrict__ b4,
    float* __restrict__ out) {
    const int g0 = blockIdx.x * 4;
    const int t = threadIdx.x;
    const int w = t >> 6;
    const int lane = t & 63;
    const int lr = lane & 15;
    const int lq = lane >> 4;

    __shared__ __align__(16) unsigned short f2s[128 * 264];
    __shared__ __align__(16) unsigned short ubuf[128 * 136];
    __shared__ __align__(16) unsigned short fgs[4 * 256];
    __shared__ float xs[4 * 192];

    unsigned short* f1s = ubuf;
    unsigned short* f3c = ubuf;

    for (int i = t; i < 768; i += 512) xs[i] = xin[(size_t)g0 * 192 + i];
    __syncthreads();

    {
        const int d = t & 127, rq = t >> 7;
        float wv[6];
#pragma unroll
        for (int c = 0; c < 6; ++c) wv[c] = w1[c * 128 + d];
        const float sc = g1[d] * rsqrtf(v1[d] + EPSF);
        const float sh = be1[d] - m1[d] * sc;
        const float bias = b1[d];

        for (int s = 0; s < 2; ++s) {
#pragma unroll
            for (int j = 0; j < 16; ++j) {
                const int rl = rq * 16 + j;
                const int gr = s * 64 + rl;
                const int g = gr >> 5, k = gr & 31;
                float acc = bias;
#pragma unroll
                for (int c = 0; c < 6; ++c) acc += xs[g * 192 + k * 6 + c] * wv[c];
                f1s[rl * 136 + d] = f2bf(fmaxf(acc * sc + sh, 0.0f));
            }
            __syncthreads();
            f32x4 acc[4][2];
#pragma unroll
            for (int nti = 0; nti < 2; ++nti) {
                f32x4 bq = *(const f32x4*)(b2 + w * 32 + nti * 16 + lq * 4);
#pragma unroll
                for (int mtl = 0; mtl < 4; ++mtl) acc[mtl][nti] = bq;
            }
#pragma unroll
            for (int ks = 0; ks < 4; ++ks) {
                bf16x8 xf[4], wf[2];
#pragma unroll
                for (int mtl = 0; mtl < 4; ++mtl)
                    xf[mtl] = *(const bf16x8*)(f1s + (mtl * 16 + lr) * 136 + ks * 32 + lq * 8);
#pragma unroll
                for (int nti = 0; nti < 2; ++nti)
                    wf[nti] = *(const bf16x8*)(w2t + (w * 32 + nti * 16 + lr) * 128 + ks * 32 + lq * 8);
#pragma unroll
                for (int mtl = 0; mtl < 4; ++mtl)
#pragma unroll
                    for (int nti = 0; nti < 2; ++nti)
                        acc[mtl][nti] = __builtin_amdgcn_mfma_f32_16x16x32_bf16(wf[nti], xf[mtl], acc[mtl][nti], 0, 0, 0);
            }
#pragma unroll
            for (int mtl = 0; mtl < 4; ++mtl)
#pragma unroll
                for (int nti = 0; nti < 2; ++nti) {
                    bf16x4 p;
#pragma unroll
                    for (int r = 0; r < 4; ++r) p[r] = (short)f2bf(acc[mtl][nti][r]);
                    *(bf16x4*)(f2s + (size_t)(s * 64 + mtl * 16 + lr) * 264 + w * 32 + nti * 16 + lq * 4) = p;
                }
            __syncthreads();
        }
    }

    for (int idx = t; idx < 1024; idx += 512) {
        int g = idx >> 8, n = idx & 255;
        float m = -3.9e38f;
#pragma unroll
        for (int k = 0; k < 32; ++k) m = fmaxf(m, bf2f(f2s[(size_t)(g * 32 + k) * 264 + n]));
        fgs[g * 256 + n] = f2bf(m);
    }
    __syncthreads();

    auto ldw3 = [&](int cb_, int ks_) -> bf16x8 {
        return *(const bf16x8*)(w3t + (size_t)(cb_ * 128 + w * 16 + lr) * 512 + ks_ * 32 + lq * 8);
    };
    auto ldw4 = [&](int cb_, int kl_, int nti_) -> bf16x8 {
        return *(const bf16x8*)(w4t + (size_t)(w * 48 + nti_ * 16 + lr) * 512 + cb_ * 128 + kl_ * 32 + lq * 8);
    };

    f32x4 acc4[3][8];
#pragma unroll
    for (int nti = 0; nti < 3; ++nti) {
        f32x4 bq = *(const f32x4*)(b4 + w * 48 + nti * 16 + lq * 4);
#pragma unroll
        for (int mt = 0; mt < 8; ++mt) acc4[nti][mt] = bq;
    }

    for (int cb = 0; cb < 4; ++cb) {
        bf16x8 wp[4];
#pragma unroll
        for (int kp = 0; kp < 4; ++kp) wp[kp] = ldw3(cb, kp);

        f32x4 accH = *(const f32x4*)(b3 + cb * 128 + w * 16 + lq * 4);
#pragma unroll
        for (int ks = 0; ks < 8; ++ks) {
            bf16x8 wf = wp[ks & 3];
            wp[ks & 3] = ldw3(cb, ks + 4);
            bf16x8 xfh = *(const bf16x8*)(fgs + (lr & 3) * 256 + ks * 32 + lq * 8);
            accH = __builtin_amdgcn_mfma_f32_16x16x32_bf16(wf, xfh, accH, 0, 0, 0);
        }
        f32x4 acc3[8];
#pragma unroll
        for (int mt = 0; mt < 8; ++mt) {
            const int gg = mt >> 1;
#pragma unroll
            for (int r = 0; r < 4; ++r)
                acc3[mt][r] = __shfl(accH[r], (lane & 48) | gg, 64);
        }
#pragma unroll
        for (int ks = 8; ks < 16; ++ks) {
            bf16x8 wf = wp[ks & 3];
            if (ks + 4 < 16) wp[ks & 3] = ldw3(cb, ks + 4);
#pragma unroll
            for (int mt = 0; mt < 8; ++mt) {
                bf16x8 xf = *(const bf16x8*)(f2s + (size_t)(mt * 16 + lr) * 264 + (ks - 8) * 32 + lq * 8);
                acc3[mt] = __builtin_amdgcn_mfma_f32_16x16x32_bf16(wf, xf, acc3[mt], 0, 0, 0);
            }
        }
        {
            const int nq = cb * 128 + w * 16 + lq * 4;
            f32x4 g2q = *(const f32x4*)(g2 + nq);
            f32x4 v2q = *(const f32x4*)(v2 + nq);
            f32x4 m2q = *(const f32x4*)(m2 + nq);
            f32x4 beq = *(const f32x4*)(be2 + nq);
            f32x4 sc, sh;
#pragma unroll
            for (int r = 0; r < 4; ++r) {
                sc[r] = g2q[r] * rsqrtf(v2q[r] + EPSF);
                sh[r] = beq[r] - m2q[r] * sc[r];
            }
#pragma unroll
            for (int mt = 0; mt < 8; ++mt) {
                bf16x4 p;
#pragma unroll
                for (int r = 0; r < 4; ++r)
                    p[r] = (short)f2bf(fmaxf(acc3[mt][r] * sc[r] + sh[r], 0.0f));
                *(bf16x4*)(f3c + (size_t)(mt * 16 + lr) * 136 + w * 16 + lq * 4) = p;
            }
        }
        bf16x8 w4a[3];
#pragma unroll
        for (int nti = 0; nti < 3; ++nti) w4a[nti] = ldw4(cb, 0, nti);
        __syncthreads();
        for (int kl = 0; kl < 4; ++kl) {
            bf16x8 w4n[3];
            if (kl < 3) {
#pragma unroll
                for (int nti = 0; nti < 3; ++nti) w4n[nti] = ldw4(cb, kl + 1, nti);
            }
            bf16x8 xf8[8];
#pragma unroll
            for (int mt = 0; mt < 8; ++mt)
                xf8[mt] = *(const bf16x8*)(f3c + (size_t)(mt * 16 + lr) * 136 + kl * 32 + lq * 8);
#pragma unroll
            for (int nti = 0; nti < 3; ++nti)
#pragma unroll
                for (int mt = 0; mt < 8; ++mt)
                    acc4[nti][mt] = __builtin_amdgcn_mfma_f32_16x16x32_bf16(w4a[nti], xf8[mt], acc4[nti][mt], 0, 0, 0);
            if (kl < 3) {
#pragma unroll
                for (int nti = 0; nti < 3; ++nti) w4a[nti] = w4n[nti];
            }
        }
        __syncthreads();
    }

#pragma unroll
    for (int nti = 0; nti < 3; ++nti) {
#pragma unroll
        for (int gg = 0; gg < 4; ++gg) {
            f32x4 vv;
#pragma unroll
            for (int r = 0; r < 4; ++r)
                vv[r] = fmaxf(acc4[nti][2 * gg][r], acc4[nti][2 * gg + 1][r]);
#pragma unroll
            for (int mask = 1; mask <= 8; mask <<= 1) {
#pragma unroll
                for (int r = 0; r < 4; ++r)
                    vv[r] = fmaxf(vv[r], __shfl_xor(vv[r], mask, 64));
            }
            if (lr == 0)
                *(f32x4*)(out + (size_t)(g0 + gg) * 384 + w * 48 + nti * 16 + lq * 4) = vv;
        }
    }
}

extern "C" void kernel_launch(void* const* d_in, const int* in_sizes, int n_in,
                              void* d_out, int out_size, void* d_ws, size_t ws_size,
                              hipStream_t stream) {
    const float* pcd = (const float*)d_in[0];
    const float* w1 = (const float*)d_in[2];
    const float* b1 = (const float*)d_in[3];
    const float* g1 = (const float*)d_in[4];
    const float* be1 = (const float*)d_in[5];
    const float* m1 = (const float*)d_in[6];
    const float* v1 = (const float*)d_in[7];
    const float* w2 = (const float*)d_in[8];
    const float* b2 = (const float*)d_in[9];
    const float* w3 = (const float*)d_in[10];
    const float* b3 = (const float*)d_in[11];
    const float* g2 = (const float*)d_in[12];
    const float* be2 = (const float*)d_in[13];
    const float* m2 = (const float*)d_in[14];
    const float* v2 = (const float*)d_in[15];
    const float* w4 = (const float*)d_in[16];
    const float* b4 = (const float*)d_in[17];
    float* out = (float*)d_out;

    char* ws = (char*)d_ws;
    int* cidx = (int*)ws;                                   // 8192 B
    float* xg = (float*)(ws + 8192);                        // 1,572,864 B
    unsigned short* w2t = (unsigned short*)(ws + 1581056);  // 65,536 B
    unsigned short* w3t = (unsigned short*)(ws + 1646592);  // 524,288 B
    unsigned short* w4t = (unsigned short*)(ws + 2170880);  // 393,216 B

    prep_kernel<<<120, 256, 0, stream>>>(w2, w3, w4, w2t, w3t, w4t);
    fps_kernel<<<32, 1024, 0, stream>>>(pcd, cidx);
    knn_kernel<<<2048, 64, 0, stream>>>(pcd, cidx, xg);
    mlp_mfma_kernel<<<512, 512, 0, stream>>>(xg, w1, b1, g1, be1, m1, v1,
                                             w2t, b2, w3t, b3, g2, be2, m2, v2,
                                             w4t, b4, out);
}